// Round 8
// baseline (242.804 us; speedup 1.0000x reference)
//
#include <hip/hip_runtime.h>
#include <hip/hip_fp16.h>
#include <math.h>

constexpr int D = 128;
constexpr int BSH = 9;               // 512 nodes per bucket
constexpr int BNODES = 1 << BSH;
constexpr int NBLK = 256;            // partition pass blocks

typedef __attribute__((ext_vector_type(8))) short bf16x8;
typedef __attribute__((ext_vector_type(4))) float f32x4;

__device__ inline short f2bf(float f) {
    unsigned u = __builtin_bit_cast(unsigned, f);
    u = (u + 0x7FFFu + ((u >> 16) & 1u)) >> 16;   // round-to-nearest-even
    return (short)u;
}

// ===========================================================================
// P1: per-block LDS bucket histogram (bucket = dst>>9). Global atomics: none.
// blkhist layout [blk][b].
// ===========================================================================
__global__ __launch_bounds__(256) void part_hist_kernel(
    const int* __restrict__ dst, int* __restrict__ blkhist,
    int nEdges, int NB)
{
    __shared__ int hist[256];
    int t = threadIdx.x;
    hist[t] = 0;
    __syncthreads();

    int per = (nEdges + gridDim.x - 1) / gridDim.x;
    int i0 = blockIdx.x * per;
    int i1 = min(nEdges, i0 + per);
    for (int i = i0 + t; i < i1; i += 256)
        atomicAdd(&hist[dst[i] >> BSH], 1);
    __syncthreads();
    if (t < NB) blkhist[blockIdx.x * NB + t] = hist[t];
}

// ===========================================================================
// P1.5: single block. For each bucket b (one thread each): serial exclusive
// prefix across blocks (coalesced: lanes read consecutive b at same k), then
// block-scan of bucket totals -> bbase, then add bbase into blkhist cursors.
// ===========================================================================
__global__ __launch_bounds__(256) void part_scan_kernel(
    int* __restrict__ blkhist, int* __restrict__ bbase,
    int nblk, int NB, int nEdges)
{
    __shared__ int s[256];
    int b = threadIdx.x;
    int run = 0;
    if (b < NB) {
        for (int k = 0; k < nblk; ++k) {
            int idx = k * NB + b;
            int v = blkhist[idx];
            blkhist[idx] = run;
            run += v;
        }
    }
    s[b] = (b < NB) ? run : 0;
    __syncthreads();
    for (int off = 1; off < 256; off <<= 1) {
        int xv = (b >= off) ? s[b - off] : 0;
        __syncthreads();
        if (b >= off) s[b] += xv;
        __syncthreads();
    }
    int base = (b > 0) ? s[b - 1] : 0;
    if (b < NB) {
        bbase[b] = base;
        for (int k = 0; k < nblk; ++k) blkhist[k * NB + b] += base;
    }
    if (b == 0) bbase[NB] = nEdges;
}

// ===========================================================================
// P2: scatter edges into bucket-partitioned array. LDS cursors only.
// part[p] = src | dloc<<17  (requires nNodes <= 131072)
// ===========================================================================
__global__ __launch_bounds__(256) void part_scatter_kernel(
    const int* __restrict__ src, const int* __restrict__ dst,
    const int* __restrict__ blkhist, unsigned* __restrict__ part,
    int nEdges, int NB)
{
    __shared__ int cur[256];
    int t = threadIdx.x;
    cur[t] = (t < NB) ? blkhist[blockIdx.x * NB + t] : 0;
    __syncthreads();

    int per = (nEdges + gridDim.x - 1) / gridDim.x;
    int i0 = blockIdx.x * per;
    int i1 = min(nEdges, i0 + per);
    for (int i = i0 + t; i < i1; i += 256) {
        int d = dst[i];
        int b = d >> BSH;
        int p = atomicAdd(&cur[b], 1);
        part[p] = (unsigned)src[i] | ((unsigned)(d & (BNODES - 1)) << 17);
    }
}

// ===========================================================================
// P3: per-bucket CSR build. One block per bucket (<=512 nodes, L2-resident
// edge span). LDS count -> LDS scan -> rowptr/degf -> LDS-cursor scatter.
// ===========================================================================
__global__ __launch_bounds__(256) void bucket_csr_kernel(
    const unsigned* __restrict__ part, const int* __restrict__ bbase,
    int* __restrict__ rowptr, float* __restrict__ degf,
    int* __restrict__ csr_src, int nNodes, int NB, int nEdges)
{
    __shared__ int cnt[BNODES];
    __shared__ int excl[BNODES];
    __shared__ int cur[BNODES];
    __shared__ int s[256];

    int b = blockIdx.x;
    int t = threadIdx.x;
    int bb = bbase[b], be = bbase[b + 1];

    cnt[t] = 0; cnt[t + 256] = 0;
    cur[t] = 0; cur[t + 256] = 0;
    __syncthreads();

    for (int i = bb + t; i < be; i += 256)
        atomicAdd(&cnt[part[i] >> 17], 1);
    __syncthreads();

    // exclusive scan of cnt[512] (2 elems/thread)
    int a0 = cnt[2 * t], a1 = cnt[2 * t + 1];
    s[t] = a0 + a1;
    __syncthreads();
    for (int off = 1; off < 256; off <<= 1) {
        int xv = (t >= off) ? s[t - off] : 0;
        __syncthreads();
        if (t >= off) s[t] += xv;
        __syncthreads();
    }
    int pbase = (t > 0) ? s[t - 1] : 0;
    excl[2 * t]     = pbase;
    excl[2 * t + 1] = pbase + a0;
    __syncthreads();

    int node0 = b << BSH;
#pragma unroll
    for (int q = 0; q < 2; ++q) {
        int j = t + q * 256;
        int d = node0 + j;
        if (d < nNodes) {
            rowptr[d] = bb + excl[j];
            degf[d]   = (float)cnt[j];
        }
    }
    if (b == NB - 1 && t == 0) rowptr[nNodes] = nEdges;

    for (int i = bb + t; i < be; i += 256) {
        unsigned v = part[i];
        int dloc = v >> 17;
        int p = bb + excl[dloc] + atomicAdd(&cur[dloc], 1);
        csr_src[p] = (int)(v & 0x1FFFFu);
    }
}

// ===========================================================================
// mid-tier CSR build (global atomics, windowed) — fallback if ws too small
// ===========================================================================
__global__ __launch_bounds__(256) void hist_win_kernel(
    const int* __restrict__ dst, int* __restrict__ count,
    int nEdges, int winSize)
{
    int pass    = blockIdx.x & 7;
    int slice   = blockIdx.x >> 3;
    int nSlices = gridDim.x >> 3;
    int lo = pass * winSize;
    int hi = lo + winSize;

    int stride = nSlices * blockDim.x;
    for (int i = slice * blockDim.x + threadIdx.x; i < nEdges; i += stride) {
        int d = dst[i];
        if (d >= lo && d < hi) atomicAdd(&count[d], 1);
    }
}

__global__ __launch_bounds__(256) void scan_block_kernel(
    const int* __restrict__ count, int* __restrict__ rowptr,
    int* __restrict__ blksums, int n)
{
    __shared__ int sums[256];
    int t = threadIdx.x;
    int base = blockIdx.x * 1024 + t * 4;
    int v[4];
    int s = 0;
#pragma unroll
    for (int j = 0; j < 4; ++j) { v[j] = (base + j < n) ? count[base + j] : 0; s += v[j]; }
    sums[t] = s;
    __syncthreads();
    for (int off = 1; off < 256; off <<= 1) {
        int xv = (t >= off) ? sums[t - off] : 0;
        __syncthreads();
        if (t >= off) sums[t] += xv;
        __syncthreads();
    }
    int run = (t > 0) ? sums[t - 1] : 0;
#pragma unroll
    for (int j = 0; j < 4; ++j) { if (base + j < n) rowptr[base + j] = run; run += v[j]; }
    if (t == 255) blksums[blockIdx.x] = sums[255];
}

__global__ __launch_bounds__(256) void scan_totals_kernel(
    int* __restrict__ blksums, int* __restrict__ rowptr,
    int numBlocks, int n, int E)
{
    __shared__ int s[256];
    int t = threadIdx.x;
    s[t] = (t < numBlocks) ? blksums[t] : 0;
    __syncthreads();
    for (int off = 1; off < 256; off <<= 1) {
        int xv = (t >= off) ? s[t - off] : 0;
        __syncthreads();
        if (t >= off) s[t] += xv;
        __syncthreads();
    }
    if (t < numBlocks) blksums[t] = (t > 0) ? s[t - 1] : 0;
    if (t == 0) rowptr[n] = E;
}

__global__ __launch_bounds__(256) void add_offsets_kernel(
    int* __restrict__ rowptr, const int* __restrict__ blksums, int n)
{
    int i = blockIdx.x * 256 + threadIdx.x;
    if (i < n) rowptr[i] += blksums[i >> 10];
}

__global__ __launch_bounds__(256) void fill_win_kernel(
    const int* __restrict__ src, const int* __restrict__ dst,
    const int* __restrict__ rowptr, int* __restrict__ count,
    int* __restrict__ csr_src, int nEdges, int winSize)
{
    int pass    = blockIdx.x & 7;
    int slice   = blockIdx.x >> 3;
    int nSlices = gridDim.x >> 3;
    int lo = pass * winSize;
    int hi = lo + winSize;

    int stride = nSlices * blockDim.x;
    for (int i = slice * blockDim.x + threadIdx.x; i < nEdges; i += stride) {
        int d = dst[i];
        if (d >= lo && d < hi) {
            int pos = rowptr[d] + atomicSub(&count[d], 1) - 1;
            csr_src[pos] = src[i];
        }
    }
}

__global__ __launch_bounds__(256) void deg_from_rowptr_kernel(
    const int* __restrict__ rowptr, float* __restrict__ degf, int n)
{
    int i = blockIdx.x * 256 + threadIdx.x;
    if (i < n) degf[i] = (float)(rowptr[i + 1] - rowptr[i]);
}

// ===========================================================================
// tangent_kernel: th[n][:] = fp16( arctanh(clip(||x||))/max(||x||,eps) * x )
// ===========================================================================
__global__ __launch_bounds__(256) void tangent_kernel(
    const float* __restrict__ x, __half* __restrict__ th, int nNodes)
{
    int n    = (blockIdx.x * 256 + threadIdx.x) >> 6;
    int lane = threadIdx.x & 63;
    if (n >= nNodes) return;
    float2 xv = *reinterpret_cast<const float2*>(x + (size_t)n * D + lane * 2);
    float ss = xv.x * xv.x + xv.y * xv.y;
    ss += __shfl_xor(ss, 1);
    ss += __shfl_xor(ss, 2);
    ss += __shfl_xor(ss, 4);
    ss += __shfl_xor(ss, 8);
    ss += __shfl_xor(ss, 16);
    ss += __shfl_xor(ss, 32);
    float norm = sqrtf(ss);
    float ncl  = fminf(norm, 1.0f - 1e-7f);
    float at   = 0.5f * logf((1.0f + ncl) / (1.0f - ncl));
    float sc   = at / fmaxf(norm, 1e-15f);
    __half2 h = __float22half2_rn(make_float2(xv.x * sc, xv.y * sc));
    *(reinterpret_cast<__half2*>(th + (size_t)n * D) + lane) = h;
}

__global__ __launch_bounds__(256) void scale_kernel(
    const float* __restrict__ x, float* __restrict__ scale, int nNodes)
{
    int node = (blockIdx.x * 256 + threadIdx.x) >> 6;
    int lane = threadIdx.x & 63;
    if (node >= nNodes) return;
    float2 xv = *reinterpret_cast<const float2*>(x + (size_t)node * D + lane * 2);
    float ss = xv.x * xv.x + xv.y * xv.y;
    ss += __shfl_xor(ss, 1);
    ss += __shfl_xor(ss, 2);
    ss += __shfl_xor(ss, 4);
    ss += __shfl_xor(ss, 8);
    ss += __shfl_xor(ss, 16);
    ss += __shfl_xor(ss, 32);
    if (lane == 0) {
        float norm = sqrtf(ss);
        float ncl  = fminf(norm, 1.0f - 1e-7f);
        float at   = 0.5f * logf((1.0f + ncl) / (1.0f - ncl));
        scale[node] = at / fmaxf(norm, 1e-15f);
    }
}

// ===========================================================================
// gather (fp16 rows, 16-lane rows): 4 groups/wave, 16B/lane, 8 rows in flight
// ===========================================================================
__global__ __launch_bounds__(256) void gather_h16_kernel(
    const __half* __restrict__ th,
    const int* __restrict__ csr_src, const int* __restrict__ rowptr,
    float* __restrict__ msg, float* __restrict__ degf, int nNodes)
{
    int n    = blockIdx.x * 4 + (threadIdx.x >> 6);
    int lane = threadIdx.x & 63;
    if (n >= nNodes) return;
    int grp = lane >> 4;
    int sl  = lane & 15;

    int beg = rowptr[n];
    int cnt = rowptr[n + 1] - beg;

    float acc[8];
#pragma unroll
    for (int j = 0; j < 8; ++j) acc[j] = 0.0f;

    int k = grp;
    for (; k + 4 < cnt; k += 8) {
        int s0 = csr_src[beg + k];
        int s1 = csr_src[beg + k + 4];
        float4 r0 = *reinterpret_cast<const float4*>(th + (size_t)s0 * D + sl * 8);
        float4 r1 = *reinterpret_cast<const float4*>(th + (size_t)s1 * D + sl * 8);
        const __half2* h0 = reinterpret_cast<const __half2*>(&r0);
        const __half2* h1 = reinterpret_cast<const __half2*>(&r1);
#pragma unroll
        for (int j = 0; j < 4; ++j) {
            float2 f0 = __half22float2(h0[j]);
            float2 f1 = __half22float2(h1[j]);
            acc[2 * j]     += f0.x + f1.x;
            acc[2 * j + 1] += f0.y + f1.y;
        }
    }
    for (; k < cnt; k += 4) {
        int s0 = csr_src[beg + k];
        float4 r0 = *reinterpret_cast<const float4*>(th + (size_t)s0 * D + sl * 8);
        const __half2* h0 = reinterpret_cast<const __half2*>(&r0);
#pragma unroll
        for (int j = 0; j < 4; ++j) {
            float2 f0 = __half22float2(h0[j]);
            acc[2 * j]     += f0.x;
            acc[2 * j + 1] += f0.y;
        }
    }
#pragma unroll
    for (int j = 0; j < 8; ++j) {
        acc[j] += __shfl_xor(acc[j], 16);
        acc[j] += __shfl_xor(acc[j], 32);
    }
    if (grp == 0) {
        float4 o0 = make_float4(acc[0], acc[1], acc[2], acc[3]);
        float4 o1 = make_float4(acc[4], acc[5], acc[6], acc[7]);
        *reinterpret_cast<float4*>(msg + (size_t)n * D + sl * 8)     = o0;
        *reinterpret_cast<float4*>(msg + (size_t)n * D + sl * 8 + 4) = o1;
        if (lane == 0) degf[n] = (float)cnt;
    }
}

// gather (fp32 rows) — mid tier
__global__ __launch_bounds__(256) void gather_kernel(
    const float* __restrict__ x, const float* __restrict__ scale,
    const int* __restrict__ csr_src, const int* __restrict__ rowptr,
    float* __restrict__ msg, float* __restrict__ degf, int nNodes)
{
    int n    = blockIdx.x * 4 + (threadIdx.x >> 6);
    int lane = threadIdx.x & 63;
    if (n >= nNodes) return;

    int beg = rowptr[n], end = rowptr[n + 1];
    float2 acc0 = make_float2(0.0f, 0.0f);
    float2 acc1 = make_float2(0.0f, 0.0f);
    int e = beg;
    for (; e + 3 < end; e += 4) {
        int s0 = csr_src[e],     s1 = csr_src[e + 1];
        int s2 = csr_src[e + 2], s3 = csr_src[e + 3];
        float sc0 = scale[s0], sc1 = scale[s1];
        float sc2 = scale[s2], sc3 = scale[s3];
        float2 a = *reinterpret_cast<const float2*>(x + (size_t)s0 * D + lane * 2);
        float2 b = *reinterpret_cast<const float2*>(x + (size_t)s1 * D + lane * 2);
        float2 c = *reinterpret_cast<const float2*>(x + (size_t)s2 * D + lane * 2);
        float2 d = *reinterpret_cast<const float2*>(x + (size_t)s3 * D + lane * 2);
        acc0.x += sc0 * a.x;  acc0.y += sc0 * a.y;
        acc1.x += sc1 * b.x;  acc1.y += sc1 * b.y;
        acc0.x += sc2 * c.x;  acc0.y += sc2 * c.y;
        acc1.x += sc3 * d.x;  acc1.y += sc3 * d.y;
    }
    for (; e < end; ++e) {
        int s0 = csr_src[e];
        float sc0 = scale[s0];
        float2 a = *reinterpret_cast<const float2*>(x + (size_t)s0 * D + lane * 2);
        acc0.x += sc0 * a.x;  acc0.y += sc0 * a.y;
    }
    acc0.x += acc1.x;  acc0.y += acc1.y;
    *reinterpret_cast<float2*>(msg + (size_t)n * D + lane * 2) = acc0;
    if (lane == 0) degf[n] = (float)(end - beg);
}

// ===========================================================================
// Fallback edge scatter (fp32 hardware atomics) — last resort
// ===========================================================================
__global__ __launch_bounds__(256) void edge_scatter_kernel(
    const float* __restrict__ x,
    const int* __restrict__ src,
    const int* __restrict__ dst,
    float* __restrict__ msg,
    float* __restrict__ deg,
    int nEdges)
{
    long long t = (long long)blockIdx.x * blockDim.x + threadIdx.x;
    int edge = (int)(t >> 5);
    int lane = (int)(t & 31);
    if (edge >= nEdges) return;

    int s = src[edge];
    int d = dst[edge];

    const float4 xv = *reinterpret_cast<const float4*>(x + (size_t)s * D + lane * 4);
    float ss = xv.x * xv.x + xv.y * xv.y + xv.z * xv.z + xv.w * xv.w;
    ss += __shfl_xor(ss, 1);
    ss += __shfl_xor(ss, 2);
    ss += __shfl_xor(ss, 4);
    ss += __shfl_xor(ss, 8);
    ss += __shfl_xor(ss, 16);

    float norm = sqrtf(ss);
    float ncl  = fminf(norm, 1.0f - 1e-7f);
    float at   = 0.5f * logf((1.0f + ncl) / (1.0f - ncl));
    float scale = at / fmaxf(norm, 1e-15f);

    float* mrow = msg + (size_t)d * D + lane * 4;
    unsafeAtomicAdd(mrow + 0, xv.x * scale);
    unsafeAtomicAdd(mrow + 1, xv.y * scale);
    unsafeAtomicAdd(mrow + 2, xv.z * scale);
    unsafeAtomicAdd(mrow + 3, xv.w * scale);
    if (lane == 0) unsafeAtomicAdd(deg + d, 1.0f);
}

// ===========================================================================
// MFMA bf16 GEMM + expmap: out = expmap0( (msg@W^T)/max(deg,1) + b ),
// zeroed where deg==0. In-place safe (each wave reads its rows before store).
// ===========================================================================
__global__ __launch_bounds__(256) void gemm_mfma_kernel(
    const float* msg, const float* __restrict__ deg,
    const float* __restrict__ W, const float* __restrict__ bias,
    float* out, int nNodes)
{
    __shared__ short sW[128][136];

    const int t = threadIdx.x;

#pragma unroll
    for (int p = 0; p < 16; ++p) {
        int chunk = p * 256 + t;
        int row = chunk >> 5;
        int c4  = (chunk & 31) * 4;
        float4 v = *reinterpret_cast<const float4*>(W + row * 128 + c4);
        short4 s;
        s.x = f2bf(v.x); s.y = f2bf(v.y); s.z = f2bf(v.z); s.w = f2bf(v.w);
        *reinterpret_cast<short4*>(&sW[row][c4]) = s;
    }
    __syncthreads();

    const int wave = t >> 6;
    const int lane = t & 63;
    const int l15  = lane & 15;
    const int lhi  = lane >> 4;
    const int m0   = blockIdx.x * 64 + wave * 16;

    int arow = m0 + l15;
    if (arow >= nNodes) arow = nNodes - 1;
    const float* ap = msg + (size_t)arow * D + lhi * 8;
    bf16x8 a[4];
#pragma unroll
    for (int kc = 0; kc < 4; ++kc) {
        float4 v0 = *reinterpret_cast<const float4*>(ap + kc * 32);
        float4 v1 = *reinterpret_cast<const float4*>(ap + kc * 32 + 4);
        bf16x8 f;
        f[0] = f2bf(v0.x); f[1] = f2bf(v0.y); f[2] = f2bf(v0.z); f[3] = f2bf(v0.w);
        f[4] = f2bf(v1.x); f[5] = f2bf(v1.y); f[6] = f2bf(v1.z); f[7] = f2bf(v1.w);
        a[kc] = f;
    }

    f32x4 acc[8];
#pragma unroll
    for (int ct = 0; ct < 8; ++ct) acc[ct] = (f32x4){0.f, 0.f, 0.f, 0.f};

#pragma unroll
    for (int ct = 0; ct < 8; ++ct) {
#pragma unroll
        for (int kc = 0; kc < 4; ++kc) {
            bf16x8 bfrag = *reinterpret_cast<const bf16x8*>(
                &sW[ct * 16 + l15][kc * 32 + lhi * 8]);
            acc[ct] = __builtin_amdgcn_mfma_f32_16x16x32_bf16(a[kc], bfrag, acc[ct], 0, 0, 0);
        }
    }

    float bv[8];
#pragma unroll
    for (int ct = 0; ct < 8; ++ct) bv[ct] = bias[ct * 16 + l15];

#pragma unroll
    for (int r = 0; r < 4; ++r) {
        int row = m0 + lhi * 4 + r;
        int rc  = row < nNodes ? row : nNodes - 1;
        float dg  = deg[rc];
        float inv = 1.0f / fmaxf(dg, 1.0f);
        float v[8];
        float ss = 0.0f;
#pragma unroll
        for (int ct = 0; ct < 8; ++ct) {
            v[ct] = acc[ct][r] * inv + bv[ct];
            ss += v[ct] * v[ct];
        }
        ss += __shfl_xor(ss, 1);
        ss += __shfl_xor(ss, 2);
        ss += __shfl_xor(ss, 4);
        ss += __shfl_xor(ss, 8);
        float norm = sqrtf(ss);
        float sc = (dg > 0.0f) ? (tanhf(norm) / fmaxf(norm, 1e-15f)) : 0.0f;
        if (row < nNodes) {
#pragma unroll
            for (int ct = 0; ct < 8; ++ct)
                out[(size_t)row * D + ct * 16 + l15] = v[ct] * sc;
        }
    }
}

static inline size_t align256(size_t o) { return (o + 255) & ~(size_t)255; }

extern "C" void kernel_launch(void* const* d_in, const int* in_sizes, int n_in,
                              void* d_out, int out_size, void* d_ws, size_t ws_size,
                              hipStream_t stream) {
    const float* x   = (const float*)d_in[0];
    const float* W   = (const float*)d_in[1];
    const float* b   = (const float*)d_in[2];
    const int*   src = (const int*)d_in[3];
    const int*   dst = (const int*)d_in[4];
    float* out = (float*)d_out;

    int nNodes = in_sizes[0] / D;
    int nEdges = in_sizes[3];
    int NB = (nNodes + BNODES - 1) >> BSH;

    // workspace layout (tiered)
    char* ws = (char*)d_ws;
    size_t off = 0;
    float* degf    = (float*)(ws + off); off = align256(off + sizeof(float) * nNodes);
    int*   count   = (int*)  (ws + off); off = align256(off + sizeof(int) * nNodes);
    int*   rowptr  = (int*)  (ws + off); off = align256(off + sizeof(int) * (nNodes + 1));
    float* scl     = (float*)(ws + off); off = align256(off + sizeof(float) * nNodes);
    int*   blksums = (int*)  (ws + off); off = align256(off + sizeof(int) * 256);
    int*   bbase   = (int*)  (ws + off); off = align256(off + sizeof(int) * 257);
    int*   blkhist = (int*)  (ws + off); off = align256(off + sizeof(int) * NBLK * 256);
    int*   csr_src = (int*)  (ws + off); off = align256(off + sizeof(int) * nEdges);
    size_t need_mid = off;
    // region A: part (P1-P3) then th (tangent onward) — sequential stream use
    unsigned* part = (unsigned*)(ws + off);
    __half*   th   = (__half*)  (ws + off);
    size_t szA = sizeof(__half) * (size_t)nNodes * D;
    if (sizeof(unsigned) * (size_t)nEdges > szA) szA = sizeof(unsigned) * (size_t)nEdges;
    off = align256(off + szA);
    size_t need_part = off;

    float* msg = out;  // stage messages directly in d_out (fp32, same rows)

    int numScanBlocks = (nNodes + 1023) / 1024;
    bool part_ok = (ws_size >= need_part) && (nNodes <= 131072) && (NB <= 256);
    bool mid_ok  = (ws_size >= need_mid) && (numScanBlocks <= 256);

    if (part_ok) {
        // ---- LDS-atomic bucket partition -> CSR (no global atomics) ----
        part_hist_kernel<<<NBLK, 256, 0, stream>>>(dst, blkhist, nEdges, NB);
        part_scan_kernel<<<1, 256, 0, stream>>>(blkhist, bbase, NBLK, NB, nEdges);
        part_scatter_kernel<<<NBLK, 256, 0, stream>>>(src, dst, blkhist, part, nEdges, NB);
        bucket_csr_kernel<<<NB, 256, 0, stream>>>(part, bbase, rowptr, degf,
                                                  csr_src, nNodes, NB, nEdges);
        // part no longer needed; th reuses the region
        tangent_kernel<<<(nNodes + 3) / 4, 256, 0, stream>>>(x, th, nNodes);
        gather_h16_kernel<<<(nNodes + 3) / 4, 256, 0, stream>>>(th, csr_src, rowptr, msg, degf, nNodes);
    } else if (mid_ok) {
        // ---- mid tier: windowed atomic hist + down-count fill, fp32 gather ----
        hipMemsetAsync(count, 0, sizeof(int) * nNodes, stream);
        int winSize = (nNodes + 7) / 8;
        hist_win_kernel<<<4096, 256, 0, stream>>>(dst, count, nEdges, winSize);
        scan_block_kernel<<<numScanBlocks, 256, 0, stream>>>(count, rowptr, blksums, nNodes);
        scan_totals_kernel<<<1, 256, 0, stream>>>(blksums, rowptr, numScanBlocks, nNodes, nEdges);
        add_offsets_kernel<<<(nNodes + 255) / 256, 256, 0, stream>>>(rowptr, blksums, nNodes);
        fill_win_kernel<<<4096, 256, 0, stream>>>(src, dst, rowptr, count, csr_src, nEdges, winSize);
        deg_from_rowptr_kernel<<<(nNodes + 255) / 256, 256, 0, stream>>>(rowptr, degf, nNodes);

        scale_kernel<<<(nNodes + 3) / 4, 256, 0, stream>>>(x, scl, nNodes);
        gather_kernel<<<(nNodes + 3) / 4, 256, 0, stream>>>(x, scl, csr_src, rowptr, msg, degf, nNodes);
    } else {
        float* deg = (float*)d_ws;
        hipMemsetAsync(msg, 0, (size_t)nNodes * D * sizeof(float), stream);
        hipMemsetAsync(deg, 0, (size_t)nNodes * sizeof(float), stream);
        long long threads = (long long)nEdges * 32;
        int blocks = (int)((threads + 255) / 256);
        edge_scatter_kernel<<<blocks, 256, 0, stream>>>(x, src, dst, msg, (float*)d_ws, nEdges);
        degf = (float*)d_ws;
    }

    gemm_mfma_kernel<<<(nNodes + 63) / 64, 256, 0, stream>>>(msg, degf, W, b, out, nNodes);
}

// Round 9
// 156.632 us; speedup vs baseline: 1.5502x; 1.5502x over previous
//
#include <hip/hip_runtime.h>
#include <hip/hip_fp16.h>
#include <math.h>

constexpr int D = 128;
constexpr int BSH = 9;               // 512 nodes per bucket
constexpr int BNODES = 1 << BSH;
constexpr int NBLK = 256;            // partition pass blocks

typedef __attribute__((ext_vector_type(8))) short bf16x8;
typedef __attribute__((ext_vector_type(4))) float f32x4;

__device__ inline short f2bf(float f) {
    unsigned u = __builtin_bit_cast(unsigned, f);
    u = (u + 0x7FFFu + ((u >> 16) & 1u)) >> 16;   // round-to-nearest-even
    return (short)u;
}

// ===========================================================================
// P1: per-block LDS bucket histogram (bucket = dst>>9). Global atomics: none.
// blkhist layout TRANSPOSED: [bucket][blk] so the scan reads coalesced.
// ===========================================================================
__global__ __launch_bounds__(256) void part_hist_kernel(
    const int* __restrict__ dst, int* __restrict__ blkhist,
    int nEdges, int NB)
{
    __shared__ int hist[256];
    int t = threadIdx.x;
    hist[t] = 0;
    __syncthreads();

    int per = (nEdges + gridDim.x - 1) / gridDim.x;
    int i0 = blockIdx.x * per;
    int i1 = min(nEdges, i0 + per);
    for (int i = i0 + t; i < i1; i += 256)
        atomicAdd(&hist[dst[i] >> BSH], 1);
    __syncthreads();
    if (t < NB) blkhist[t * NBLK + blockIdx.x] = hist[t];
}

// ===========================================================================
// P1.5a: one block PER BUCKET: 256-wide LDS scan of that bucket's per-block
// counts -> exclusive prefix in place, bucket total to btot[b].
// ===========================================================================
__global__ __launch_bounds__(256) void part_scan1_kernel(
    int* __restrict__ blkhist, int* __restrict__ btot)
{
    __shared__ int s[256];
    int b = blockIdx.x;
    int t = threadIdx.x;
    int v = blkhist[b * NBLK + t];
    s[t] = v;
    __syncthreads();
    for (int off = 1; off < 256; off <<= 1) {
        int xv = (t >= off) ? s[t - off] : 0;
        __syncthreads();
        if (t >= off) s[t] += xv;
        __syncthreads();
    }
    blkhist[b * NBLK + t] = s[t] - v;   // exclusive
    if (t == 255) btot[b] = s[255];
}

// P1.5b: single tiny block: exclusive scan of bucket totals -> bbase
__global__ __launch_bounds__(256) void part_scan2_kernel(
    const int* __restrict__ btot, int* __restrict__ bbase,
    int NB, int nEdges)
{
    __shared__ int s[256];
    int t = threadIdx.x;
    int v = (t < NB) ? btot[t] : 0;
    s[t] = v;
    __syncthreads();
    for (int off = 1; off < 256; off <<= 1) {
        int xv = (t >= off) ? s[t - off] : 0;
        __syncthreads();
        if (t >= off) s[t] += xv;
        __syncthreads();
    }
    if (t < NB) bbase[t] = s[t] - v;
    if (t == 0) bbase[NB] = nEdges;
}

// ===========================================================================
// P2: scatter edges into bucket-partitioned array. LDS cursors only; bucket
// base (bbase) folded into cursor init. part[p] = src | dloc<<17.
// ===========================================================================
__global__ __launch_bounds__(256) void part_scatter_kernel(
    const int* __restrict__ src, const int* __restrict__ dst,
    const int* __restrict__ blkhist, const int* __restrict__ bbase,
    unsigned* __restrict__ part, int nEdges, int NB)
{
    __shared__ int cur[256];
    int t = threadIdx.x;
    cur[t] = (t < NB) ? (blkhist[t * NBLK + blockIdx.x] + bbase[t]) : 0;
    __syncthreads();

    int per = (nEdges + gridDim.x - 1) / gridDim.x;
    int i0 = blockIdx.x * per;
    int i1 = min(nEdges, i0 + per);
    for (int i = i0 + t; i < i1; i += 256) {
        int d = dst[i];
        int b = d >> BSH;
        int p = atomicAdd(&cur[b], 1);
        part[p] = (unsigned)src[i] | ((unsigned)(d & (BNODES - 1)) << 17);
    }
}

// ===========================================================================
// P3: per-bucket CSR build. One block per bucket (<=512 nodes, L2-resident
// edge span). LDS count -> LDS scan -> rowptr/degf -> LDS-cursor scatter.
// ===========================================================================
__global__ __launch_bounds__(256) void bucket_csr_kernel(
    const unsigned* __restrict__ part, const int* __restrict__ bbase,
    int* __restrict__ rowptr, float* __restrict__ degf,
    int* __restrict__ csr_src, int nNodes, int NB, int nEdges)
{
    __shared__ int cnt[BNODES];
    __shared__ int excl[BNODES];
    __shared__ int cur[BNODES];
    __shared__ int s[256];

    int b = blockIdx.x;
    int t = threadIdx.x;
    int bb = bbase[b], be = bbase[b + 1];

    cnt[t] = 0; cnt[t + 256] = 0;
    cur[t] = 0; cur[t + 256] = 0;
    __syncthreads();

    for (int i = bb + t; i < be; i += 256)
        atomicAdd(&cnt[part[i] >> 17], 1);
    __syncthreads();

    int a0 = cnt[2 * t], a1 = cnt[2 * t + 1];
    s[t] = a0 + a1;
    __syncthreads();
    for (int off = 1; off < 256; off <<= 1) {
        int xv = (t >= off) ? s[t - off] : 0;
        __syncthreads();
        if (t >= off) s[t] += xv;
        __syncthreads();
    }
    int pbase = (t > 0) ? s[t - 1] : 0;
    excl[2 * t]     = pbase;
    excl[2 * t + 1] = pbase + a0;
    __syncthreads();

    int node0 = b << BSH;
#pragma unroll
    for (int q = 0; q < 2; ++q) {
        int j = t + q * 256;
        int d = node0 + j;
        if (d < nNodes) {
            rowptr[d] = bb + excl[j];
            degf[d]   = (float)cnt[j];
        }
    }
    if (b == NB - 1 && t == 0) rowptr[nNodes] = nEdges;

    for (int i = bb + t; i < be; i += 256) {
        unsigned v = part[i];
        int dloc = v >> 17;
        int p = bb + excl[dloc] + atomicAdd(&cur[dloc], 1);
        csr_src[p] = (int)(v & 0x1FFFFu);
    }
}

// ===========================================================================
// mid-tier CSR build (global atomics, windowed) — fallback if ws too small
// ===========================================================================
__global__ __launch_bounds__(256) void hist_win_kernel(
    const int* __restrict__ dst, int* __restrict__ count,
    int nEdges, int winSize)
{
    int pass    = blockIdx.x & 7;
    int slice   = blockIdx.x >> 3;
    int nSlices = gridDim.x >> 3;
    int lo = pass * winSize;
    int hi = lo + winSize;

    int stride = nSlices * blockDim.x;
    for (int i = slice * blockDim.x + threadIdx.x; i < nEdges; i += stride) {
        int d = dst[i];
        if (d >= lo && d < hi) atomicAdd(&count[d], 1);
    }
}

__global__ __launch_bounds__(256) void scan_block_kernel(
    const int* __restrict__ count, int* __restrict__ rowptr,
    int* __restrict__ blksums, int n)
{
    __shared__ int sums[256];
    int t = threadIdx.x;
    int base = blockIdx.x * 1024 + t * 4;
    int v[4];
    int s = 0;
#pragma unroll
    for (int j = 0; j < 4; ++j) { v[j] = (base + j < n) ? count[base + j] : 0; s += v[j]; }
    sums[t] = s;
    __syncthreads();
    for (int off = 1; off < 256; off <<= 1) {
        int xv = (t >= off) ? sums[t - off] : 0;
        __syncthreads();
        if (t >= off) sums[t] += xv;
        __syncthreads();
    }
    int run = (t > 0) ? sums[t - 1] : 0;
#pragma unroll
    for (int j = 0; j < 4; ++j) { if (base + j < n) rowptr[base + j] = run; run += v[j]; }
    if (t == 255) blksums[blockIdx.x] = sums[255];
}

__global__ __launch_bounds__(256) void scan_totals_kernel(
    int* __restrict__ blksums, int* __restrict__ rowptr,
    int numBlocks, int n, int E)
{
    __shared__ int s[256];
    int t = threadIdx.x;
    s[t] = (t < numBlocks) ? blksums[t] : 0;
    __syncthreads();
    for (int off = 1; off < 256; off <<= 1) {
        int xv = (t >= off) ? s[t - off] : 0;
        __syncthreads();
        if (t >= off) s[t] += xv;
        __syncthreads();
    }
    if (t < numBlocks) blksums[t] = (t > 0) ? s[t - 1] : 0;
    if (t == 0) rowptr[n] = E;
}

__global__ __launch_bounds__(256) void add_offsets_kernel(
    int* __restrict__ rowptr, const int* __restrict__ blksums, int n)
{
    int i = blockIdx.x * 256 + threadIdx.x;
    if (i < n) rowptr[i] += blksums[i >> 10];
}

__global__ __launch_bounds__(256) void fill_win_kernel(
    const int* __restrict__ src, const int* __restrict__ dst,
    const int* __restrict__ rowptr, int* __restrict__ count,
    int* __restrict__ csr_src, int nEdges, int winSize)
{
    int pass    = blockIdx.x & 7;
    int slice   = blockIdx.x >> 3;
    int nSlices = gridDim.x >> 3;
    int lo = pass * winSize;
    int hi = lo + winSize;

    int stride = nSlices * blockDim.x;
    for (int i = slice * blockDim.x + threadIdx.x; i < nEdges; i += stride) {
        int d = dst[i];
        if (d >= lo && d < hi) {
            int pos = rowptr[d] + atomicSub(&count[d], 1) - 1;
            csr_src[pos] = src[i];
        }
    }
}

__global__ __launch_bounds__(256) void deg_from_rowptr_kernel(
    const int* __restrict__ rowptr, float* __restrict__ degf, int n)
{
    int i = blockIdx.x * 256 + threadIdx.x;
    if (i < n) degf[i] = (float)(rowptr[i + 1] - rowptr[i]);
}

// ===========================================================================
// tangent_kernel: th[n][:] = fp16( arctanh(clip(||x||))/max(||x||,eps) * x )
// ===========================================================================
__global__ __launch_bounds__(256) void tangent_kernel(
    const float* __restrict__ x, __half* __restrict__ th, int nNodes)
{
    int n    = (blockIdx.x * 256 + threadIdx.x) >> 6;
    int lane = threadIdx.x & 63;
    if (n >= nNodes) return;
    float2 xv = *reinterpret_cast<const float2*>(x + (size_t)n * D + lane * 2);
    float ss = xv.x * xv.x + xv.y * xv.y;
    ss += __shfl_xor(ss, 1);
    ss += __shfl_xor(ss, 2);
    ss += __shfl_xor(ss, 4);
    ss += __shfl_xor(ss, 8);
    ss += __shfl_xor(ss, 16);
    ss += __shfl_xor(ss, 32);
    float norm = sqrtf(ss);
    float ncl  = fminf(norm, 1.0f - 1e-7f);
    float at   = 0.5f * logf((1.0f + ncl) / (1.0f - ncl));
    float sc   = at / fmaxf(norm, 1e-15f);
    __half2 h = __float22half2_rn(make_float2(xv.x * sc, xv.y * sc));
    *(reinterpret_cast<__half2*>(th + (size_t)n * D) + lane) = h;
}

__global__ __launch_bounds__(256) void scale_kernel(
    const float* __restrict__ x, float* __restrict__ scale, int nNodes)
{
    int node = (blockIdx.x * 256 + threadIdx.x) >> 6;
    int lane = threadIdx.x & 63;
    if (node >= nNodes) return;
    float2 xv = *reinterpret_cast<const float2*>(x + (size_t)node * D + lane * 2);
    float ss = xv.x * xv.x + xv.y * xv.y;
    ss += __shfl_xor(ss, 1);
    ss += __shfl_xor(ss, 2);
    ss += __shfl_xor(ss, 4);
    ss += __shfl_xor(ss, 8);
    ss += __shfl_xor(ss, 16);
    ss += __shfl_xor(ss, 32);
    if (lane == 0) {
        float norm = sqrtf(ss);
        float ncl  = fminf(norm, 1.0f - 1e-7f);
        float at   = 0.5f * logf((1.0f + ncl) / (1.0f - ncl));
        scale[node] = at / fmaxf(norm, 1e-15f);
    }
}

// ===========================================================================
// gather (fp16 rows, 16-lane rows): 4 groups/wave, 16B/lane, 8 rows in flight
// ===========================================================================
__global__ __launch_bounds__(256) void gather_h16_kernel(
    const __half* __restrict__ th,
    const int* __restrict__ csr_src, const int* __restrict__ rowptr,
    float* __restrict__ msg, float* __restrict__ degf, int nNodes)
{
    int n    = blockIdx.x * 4 + (threadIdx.x >> 6);
    int lane = threadIdx.x & 63;
    if (n >= nNodes) return;
    int grp = lane >> 4;
    int sl  = lane & 15;

    int beg = rowptr[n];
    int cnt = rowptr[n + 1] - beg;

    float acc[8];
#pragma unroll
    for (int j = 0; j < 8; ++j) acc[j] = 0.0f;

    int k = grp;
    for (; k + 4 < cnt; k += 8) {
        int s0 = csr_src[beg + k];
        int s1 = csr_src[beg + k + 4];
        float4 r0 = *reinterpret_cast<const float4*>(th + (size_t)s0 * D + sl * 8);
        float4 r1 = *reinterpret_cast<const float4*>(th + (size_t)s1 * D + sl * 8);
        const __half2* h0 = reinterpret_cast<const __half2*>(&r0);
        const __half2* h1 = reinterpret_cast<const __half2*>(&r1);
#pragma unroll
        for (int j = 0; j < 4; ++j) {
            float2 f0 = __half22float2(h0[j]);
            float2 f1 = __half22float2(h1[j]);
            acc[2 * j]     += f0.x + f1.x;
            acc[2 * j + 1] += f0.y + f1.y;
        }
    }
    for (; k < cnt; k += 4) {
        int s0 = csr_src[beg + k];
        float4 r0 = *reinterpret_cast<const float4*>(th + (size_t)s0 * D + sl * 8);
        const __half2* h0 = reinterpret_cast<const __half2*>(&r0);
#pragma unroll
        for (int j = 0; j < 4; ++j) {
            float2 f0 = __half22float2(h0[j]);
            acc[2 * j]     += f0.x;
            acc[2 * j + 1] += f0.y;
        }
    }
#pragma unroll
    for (int j = 0; j < 8; ++j) {
        acc[j] += __shfl_xor(acc[j], 16);
        acc[j] += __shfl_xor(acc[j], 32);
    }
    if (grp == 0) {
        float4 o0 = make_float4(acc[0], acc[1], acc[2], acc[3]);
        float4 o1 = make_float4(acc[4], acc[5], acc[6], acc[7]);
        *reinterpret_cast<float4*>(msg + (size_t)n * D + sl * 8)     = o0;
        *reinterpret_cast<float4*>(msg + (size_t)n * D + sl * 8 + 4) = o1;
        if (lane == 0) degf[n] = (float)cnt;
    }
}

// gather (fp32 rows) — mid tier
__global__ __launch_bounds__(256) void gather_kernel(
    const float* __restrict__ x, const float* __restrict__ scale,
    const int* __restrict__ csr_src, const int* __restrict__ rowptr,
    float* __restrict__ msg, float* __restrict__ degf, int nNodes)
{
    int n    = blockIdx.x * 4 + (threadIdx.x >> 6);
    int lane = threadIdx.x & 63;
    if (n >= nNodes) return;

    int beg = rowptr[n], end = rowptr[n + 1];
    float2 acc0 = make_float2(0.0f, 0.0f);
    float2 acc1 = make_float2(0.0f, 0.0f);
    int e = beg;
    for (; e + 3 < end; e += 4) {
        int s0 = csr_src[e],     s1 = csr_src[e + 1];
        int s2 = csr_src[e + 2], s3 = csr_src[e + 3];
        float sc0 = scale[s0], sc1 = scale[s1];
        float sc2 = scale[s2], sc3 = scale[s3];
        float2 a = *reinterpret_cast<const float2*>(x + (size_t)s0 * D + lane * 2);
        float2 b = *reinterpret_cast<const float2*>(x + (size_t)s1 * D + lane * 2);
        float2 c = *reinterpret_cast<const float2*>(x + (size_t)s2 * D + lane * 2);
        float2 d = *reinterpret_cast<const float2*>(x + (size_t)s3 * D + lane * 2);
        acc0.x += sc0 * a.x;  acc0.y += sc0 * a.y;
        acc1.x += sc1 * b.x;  acc1.y += sc1 * b.y;
        acc0.x += sc2 * c.x;  acc0.y += sc2 * c.y;
        acc1.x += sc3 * d.x;  acc1.y += sc3 * d.y;
    }
    for (; e < end; ++e) {
        int s0 = csr_src[e];
        float sc0 = scale[s0];
        float2 a = *reinterpret_cast<const float2*>(x + (size_t)s0 * D + lane * 2);
        acc0.x += sc0 * a.x;  acc0.y += sc0 * a.y;
    }
    acc0.x += acc1.x;  acc0.y += acc1.y;
    *reinterpret_cast<float2*>(msg + (size_t)n * D + lane * 2) = acc0;
    if (lane == 0) degf[n] = (float)(end - beg);
}

// ===========================================================================
// Fallback edge scatter (fp32 hardware atomics) — last resort
// ===========================================================================
__global__ __launch_bounds__(256) void edge_scatter_kernel(
    const float* __restrict__ x,
    const int* __restrict__ src,
    const int* __restrict__ dst,
    float* __restrict__ msg,
    float* __restrict__ deg,
    int nEdges)
{
    long long t = (long long)blockIdx.x * blockDim.x + threadIdx.x;
    int edge = (int)(t >> 5);
    int lane = (int)(t & 31);
    if (edge >= nEdges) return;

    int s = src[edge];
    int d = dst[edge];

    const float4 xv = *reinterpret_cast<const float4*>(x + (size_t)s * D + lane * 4);
    float ss = xv.x * xv.x + xv.y * xv.y + xv.z * xv.z + xv.w * xv.w;
    ss += __shfl_xor(ss, 1);
    ss += __shfl_xor(ss, 2);
    ss += __shfl_xor(ss, 4);
    ss += __shfl_xor(ss, 8);
    ss += __shfl_xor(ss, 16);

    float norm = sqrtf(ss);
    float ncl  = fminf(norm, 1.0f - 1e-7f);
    float at   = 0.5f * logf((1.0f + ncl) / (1.0f - ncl));
    float scale = at / fmaxf(norm, 1e-15f);

    float* mrow = msg + (size_t)d * D + lane * 4;
    unsafeAtomicAdd(mrow + 0, xv.x * scale);
    unsafeAtomicAdd(mrow + 1, xv.y * scale);
    unsafeAtomicAdd(mrow + 2, xv.z * scale);
    unsafeAtomicAdd(mrow + 3, xv.w * scale);
    if (lane == 0) unsafeAtomicAdd(deg + d, 1.0f);
}

// ===========================================================================
// MFMA bf16 GEMM + expmap: out = expmap0( (msg@W^T)/max(deg,1) + b ),
// zeroed where deg==0. In-place safe (each wave reads its rows before store).
// ===========================================================================
__global__ __launch_bounds__(256) void gemm_mfma_kernel(
    const float* msg, const float* __restrict__ deg,
    const float* __restrict__ W, const float* __restrict__ bias,
    float* out, int nNodes)
{
    __shared__ short sW[128][136];

    const int t = threadIdx.x;

#pragma unroll
    for (int p = 0; p < 16; ++p) {
        int chunk = p * 256 + t;
        int row = chunk >> 5;
        int c4  = (chunk & 31) * 4;
        float4 v = *reinterpret_cast<const float4*>(W + row * 128 + c4);
        short4 s;
        s.x = f2bf(v.x); s.y = f2bf(v.y); s.z = f2bf(v.z); s.w = f2bf(v.w);
        *reinterpret_cast<short4*>(&sW[row][c4]) = s;
    }
    __syncthreads();

    const int wave = t >> 6;
    const int lane = t & 63;
    const int l15  = lane & 15;
    const int lhi  = lane >> 4;
    const int m0   = blockIdx.x * 64 + wave * 16;

    int arow = m0 + l15;
    if (arow >= nNodes) arow = nNodes - 1;
    const float* ap = msg + (size_t)arow * D + lhi * 8;
    bf16x8 a[4];
#pragma unroll
    for (int kc = 0; kc < 4; ++kc) {
        float4 v0 = *reinterpret_cast<const float4*>(ap + kc * 32);
        float4 v1 = *reinterpret_cast<const float4*>(ap + kc * 32 + 4);
        bf16x8 f;
        f[0] = f2bf(v0.x); f[1] = f2bf(v0.y); f[2] = f2bf(v0.z); f[3] = f2bf(v0.w);
        f[4] = f2bf(v1.x); f[5] = f2bf(v1.y); f[6] = f2bf(v1.z); f[7] = f2bf(v1.w);
        a[kc] = f;
    }

    f32x4 acc[8];
#pragma unroll
    for (int ct = 0; ct < 8; ++ct) acc[ct] = (f32x4){0.f, 0.f, 0.f, 0.f};

#pragma unroll
    for (int ct = 0; ct < 8; ++ct) {
#pragma unroll
        for (int kc = 0; kc < 4; ++kc) {
            bf16x8 bfrag = *reinterpret_cast<const bf16x8*>(
                &sW[ct * 16 + l15][kc * 32 + lhi * 8]);
            acc[ct] = __builtin_amdgcn_mfma_f32_16x16x32_bf16(a[kc], bfrag, acc[ct], 0, 0, 0);
        }
    }

    float bv[8];
#pragma unroll
    for (int ct = 0; ct < 8; ++ct) bv[ct] = bias[ct * 16 + l15];

#pragma unroll
    for (int r = 0; r < 4; ++r) {
        int row = m0 + lhi * 4 + r;
        int rc  = row < nNodes ? row : nNodes - 1;
        float dg  = deg[rc];
        float inv = 1.0f / fmaxf(dg, 1.0f);
        float v[8];
        float ss = 0.0f;
#pragma unroll
        for (int ct = 0; ct < 8; ++ct) {
            v[ct] = acc[ct][r] * inv + bv[ct];
            ss += v[ct] * v[ct];
        }
        ss += __shfl_xor(ss, 1);
        ss += __shfl_xor(ss, 2);
        ss += __shfl_xor(ss, 4);
        ss += __shfl_xor(ss, 8);
        float norm = sqrtf(ss);
        float sc = (dg > 0.0f) ? (tanhf(norm) / fmaxf(norm, 1e-15f)) : 0.0f;
        if (row < nNodes) {
#pragma unroll
            for (int ct = 0; ct < 8; ++ct)
                out[(size_t)row * D + ct * 16 + l15] = v[ct] * sc;
        }
    }
}

static inline size_t align256(size_t o) { return (o + 255) & ~(size_t)255; }

extern "C" void kernel_launch(void* const* d_in, const int* in_sizes, int n_in,
                              void* d_out, int out_size, void* d_ws, size_t ws_size,
                              hipStream_t stream) {
    const float* x   = (const float*)d_in[0];
    const float* W   = (const float*)d_in[1];
    const float* b   = (const float*)d_in[2];
    const int*   src = (const int*)d_in[3];
    const int*   dst = (const int*)d_in[4];
    float* out = (float*)d_out;

    int nNodes = in_sizes[0] / D;
    int nEdges = in_sizes[3];
    int NB = (nNodes + BNODES - 1) >> BSH;

    // workspace layout (tiered)
    char* ws = (char*)d_ws;
    size_t off = 0;
    float* degf    = (float*)(ws + off); off = align256(off + sizeof(float) * nNodes);
    int*   count   = (int*)  (ws + off); off = align256(off + sizeof(int) * nNodes);
    int*   rowptr  = (int*)  (ws + off); off = align256(off + sizeof(int) * (nNodes + 1));
    float* scl     = (float*)(ws + off); off = align256(off + sizeof(float) * nNodes);
    int*   blksums = (int*)  (ws + off); off = align256(off + sizeof(int) * 256);
    int*   bbase   = (int*)  (ws + off); off = align256(off + sizeof(int) * 257);
    int*   btot    = (int*)  (ws + off); off = align256(off + sizeof(int) * 256);
    int*   blkhist = (int*)  (ws + off); off = align256(off + sizeof(int) * NBLK * 256);
    int*   csr_src = (int*)  (ws + off); off = align256(off + sizeof(int) * nEdges);
    size_t need_mid = off;
    // region A: part (P1-P3) then th (tangent onward) — sequential stream use
    unsigned* part = (unsigned*)(ws + off);
    __half*   th   = (__half*)  (ws + off);
    size_t szA = sizeof(__half) * (size_t)nNodes * D;
    if (sizeof(unsigned) * (size_t)nEdges > szA) szA = sizeof(unsigned) * (size_t)nEdges;
    off = align256(off + szA);
    size_t need_part = off;

    float* msg = out;  // stage messages directly in d_out (fp32, same rows)

    int numScanBlocks = (nNodes + 1023) / 1024;
    bool part_ok = (ws_size >= need_part) && (nNodes <= 131072) && (NB <= 256);
    bool mid_ok  = (ws_size >= need_mid) && (numScanBlocks <= 256);

    if (part_ok) {
        // ---- LDS-atomic bucket partition -> CSR (no global atomics) ----
        part_hist_kernel<<<NBLK, 256, 0, stream>>>(dst, blkhist, nEdges, NB);
        part_scan1_kernel<<<NB, 256, 0, stream>>>(blkhist, btot);
        part_scan2_kernel<<<1, 256, 0, stream>>>(btot, bbase, NB, nEdges);
        part_scatter_kernel<<<NBLK, 256, 0, stream>>>(src, dst, blkhist, bbase, part, nEdges, NB);
        bucket_csr_kernel<<<NB, 256, 0, stream>>>(part, bbase, rowptr, degf,
                                                  csr_src, nNodes, NB, nEdges);
        // part no longer needed; th reuses the region
        tangent_kernel<<<(nNodes + 3) / 4, 256, 0, stream>>>(x, th, nNodes);
        gather_h16_kernel<<<(nNodes + 3) / 4, 256, 0, stream>>>(th, csr_src, rowptr, msg, degf, nNodes);
    } else if (mid_ok) {
        // ---- mid tier: windowed atomic hist + down-count fill, fp32 gather ----
        hipMemsetAsync(count, 0, sizeof(int) * nNodes, stream);
        int winSize = (nNodes + 7) / 8;
        hist_win_kernel<<<4096, 256, 0, stream>>>(dst, count, nEdges, winSize);
        scan_block_kernel<<<numScanBlocks, 256, 0, stream>>>(count, rowptr, blksums, nNodes);
        scan_totals_kernel<<<1, 256, 0, stream>>>(blksums, rowptr, numScanBlocks, nNodes, nEdges);
        add_offsets_kernel<<<(nNodes + 255) / 256, 256, 0, stream>>>(rowptr, blksums, nNodes);
        fill_win_kernel<<<4096, 256, 0, stream>>>(src, dst, rowptr, count, csr_src, nEdges, winSize);
        deg_from_rowptr_kernel<<<(nNodes + 255) / 256, 256, 0, stream>>>(rowptr, degf, nNodes);

        scale_kernel<<<(nNodes + 3) / 4, 256, 0, stream>>>(x, scl, nNodes);
        gather_kernel<<<(nNodes + 3) / 4, 256, 0, stream>>>(x, scl, csr_src, rowptr, msg, degf, nNodes);
    } else {
        float* deg = (float*)d_ws;
        hipMemsetAsync(msg, 0, (size_t)nNodes * D * sizeof(float), stream);
        hipMemsetAsync(deg, 0, (size_t)nNodes * sizeof(float), stream);
        long long threads = (long long)nEdges * 32;
        int blocks = (int)((threads + 255) / 256);
        edge_scatter_kernel<<<blocks, 256, 0, stream>>>(x, src, dst, msg, (float*)d_ws, nEdges);
        degf = (float*)d_ws;
    }

    gemm_mfma_kernel<<<(nNodes + 63) / 64, 256, 0, stream>>>(msg, degf, W, b, out, nNodes);
}

// Round 10
// 149.476 us; speedup vs baseline: 1.6244x; 1.0479x over previous
//
#include <hip/hip_runtime.h>
#include <hip/hip_fp16.h>
#include <math.h>

constexpr int D = 128;
constexpr int BSH = 9;               // 512 nodes per bucket
constexpr int BNODES = 1 << BSH;
constexpr int NBLK = 256;            // partition pass blocks

typedef __attribute__((ext_vector_type(8))) short bf16x8;
typedef __attribute__((ext_vector_type(4))) float f32x4;

__device__ inline short f2bf(float f) {
    unsigned u = __builtin_bit_cast(unsigned, f);
    u = (u + 0x7FFFu + ((u >> 16) & 1u)) >> 16;   // round-to-nearest-even
    return (short)u;
}

// ===========================================================================
// P1: per-block LDS bucket histogram (bucket = dst>>9). Global atomics: none.
// blkhist layout TRANSPOSED: [bucket][blk] so the scan reads coalesced.
// ===========================================================================
__global__ __launch_bounds__(256) void part_hist_kernel(
    const int* __restrict__ dst, int* __restrict__ blkhist,
    int nEdges, int NB)
{
    __shared__ int hist[256];
    int t = threadIdx.x;
    hist[t] = 0;
    __syncthreads();

    int per = (nEdges + gridDim.x - 1) / gridDim.x;
    int i0 = blockIdx.x * per;
    int i1 = min(nEdges, i0 + per);
    for (int i = i0 + t; i < i1; i += 256)
        atomicAdd(&hist[dst[i] >> BSH], 1);
    __syncthreads();
    if (t < NB) blkhist[t * NBLK + blockIdx.x] = hist[t];
}

// P1.5a: one block per bucket: scan per-block counts -> exclusive, total out
__global__ __launch_bounds__(256) void part_scan1_kernel(
    int* __restrict__ blkhist, int* __restrict__ btot)
{
    __shared__ int s[256];
    int b = blockIdx.x;
    int t = threadIdx.x;
    int v = blkhist[b * NBLK + t];
    s[t] = v;
    __syncthreads();
    for (int off = 1; off < 256; off <<= 1) {
        int xv = (t >= off) ? s[t - off] : 0;
        __syncthreads();
        if (t >= off) s[t] += xv;
        __syncthreads();
    }
    blkhist[b * NBLK + t] = s[t] - v;   // exclusive
    if (t == 255) btot[b] = s[255];
}

// P1.5b: single tiny block: exclusive scan of bucket totals -> bbase
__global__ __launch_bounds__(256) void part_scan2_kernel(
    const int* __restrict__ btot, int* __restrict__ bbase,
    int NB, int nEdges)
{
    __shared__ int s[256];
    int t = threadIdx.x;
    int v = (t < NB) ? btot[t] : 0;
    s[t] = v;
    __syncthreads();
    for (int off = 1; off < 256; off <<= 1) {
        int xv = (t >= off) ? s[t - off] : 0;
        __syncthreads();
        if (t >= off) s[t] += xv;
        __syncthreads();
    }
    if (t < NB) bbase[t] = s[t] - v;
    if (t == 0) bbase[NB] = nEdges;
}

// ===========================================================================
// P2: scatter edges into bucket-partitioned array. LDS cursors only.
// part[p] = src | dloc<<17  (requires nNodes <= 131072)
// ===========================================================================
__global__ __launch_bounds__(256) void part_scatter_kernel(
    const int* __restrict__ src, const int* __restrict__ dst,
    const int* __restrict__ blkhist, const int* __restrict__ bbase,
    unsigned* __restrict__ part, int nEdges, int NB)
{
    __shared__ int cur[256];
    int t = threadIdx.x;
    cur[t] = (t < NB) ? (blkhist[t * NBLK + blockIdx.x] + bbase[t]) : 0;
    __syncthreads();

    int per = (nEdges + gridDim.x - 1) / gridDim.x;
    int i0 = blockIdx.x * per;
    int i1 = min(nEdges, i0 + per);
    for (int i = i0 + t; i < i1; i += 256) {
        int d = dst[i];
        int b = d >> BSH;
        int p = atomicAdd(&cur[b], 1);
        part[p] = (unsigned)src[i] | ((unsigned)(d & (BNODES - 1)) << 17);
    }
}

// ===========================================================================
// P3: per-bucket CSR build. One block per bucket (<=512 nodes, L2-resident
// edge span). LDS count -> LDS scan -> rowptr/degf -> LDS-cursor scatter.
// ===========================================================================
__global__ __launch_bounds__(256) void bucket_csr_kernel(
    const unsigned* __restrict__ part, const int* __restrict__ bbase,
    int* __restrict__ rowptr, float* __restrict__ degf,
    int* __restrict__ csr_src, int nNodes, int NB, int nEdges)
{
    __shared__ int cnt[BNODES];
    __shared__ int excl[BNODES];
    __shared__ int cur[BNODES];
    __shared__ int s[256];

    int b = blockIdx.x;
    int t = threadIdx.x;
    int bb = bbase[b], be = bbase[b + 1];

    cnt[t] = 0; cnt[t + 256] = 0;
    cur[t] = 0; cur[t + 256] = 0;
    __syncthreads();

    for (int i = bb + t; i < be; i += 256)
        atomicAdd(&cnt[part[i] >> 17], 1);
    __syncthreads();

    int a0 = cnt[2 * t], a1 = cnt[2 * t + 1];
    s[t] = a0 + a1;
    __syncthreads();
    for (int off = 1; off < 256; off <<= 1) {
        int xv = (t >= off) ? s[t - off] : 0;
        __syncthreads();
        if (t >= off) s[t] += xv;
        __syncthreads();
    }
    int pbase = (t > 0) ? s[t - 1] : 0;
    excl[2 * t]     = pbase;
    excl[2 * t + 1] = pbase + a0;
    __syncthreads();

    int node0 = b << BSH;
#pragma unroll
    for (int q = 0; q < 2; ++q) {
        int j = t + q * 256;
        int d = node0 + j;
        if (d < nNodes) {
            rowptr[d] = bb + excl[j];
            degf[d]   = (float)cnt[j];
        }
    }
    if (b == NB - 1 && t == 0) rowptr[nNodes] = nEdges;

    for (int i = bb + t; i < be; i += 256) {
        unsigned v = part[i];
        int dloc = v >> 17;
        int p = bb + excl[dloc] + atomicAdd(&cur[dloc], 1);
        csr_src[p] = (int)(v & 0x1FFFFu);
    }
}

// ===========================================================================
// mid-tier CSR build (global atomics, windowed) — fallback if ws too small
// ===========================================================================
__global__ __launch_bounds__(256) void hist_win_kernel(
    const int* __restrict__ dst, int* __restrict__ count,
    int nEdges, int winSize)
{
    int pass    = blockIdx.x & 7;
    int slice   = blockIdx.x >> 3;
    int nSlices = gridDim.x >> 3;
    int lo = pass * winSize;
    int hi = lo + winSize;

    int stride = nSlices * blockDim.x;
    for (int i = slice * blockDim.x + threadIdx.x; i < nEdges; i += stride) {
        int d = dst[i];
        if (d >= lo && d < hi) atomicAdd(&count[d], 1);
    }
}

__global__ __launch_bounds__(256) void scan_block_kernel(
    const int* __restrict__ count, int* __restrict__ rowptr,
    int* __restrict__ blksums, int n)
{
    __shared__ int sums[256];
    int t = threadIdx.x;
    int base = blockIdx.x * 1024 + t * 4;
    int v[4];
    int s = 0;
#pragma unroll
    for (int j = 0; j < 4; ++j) { v[j] = (base + j < n) ? count[base + j] : 0; s += v[j]; }
    sums[t] = s;
    __syncthreads();
    for (int off = 1; off < 256; off <<= 1) {
        int xv = (t >= off) ? sums[t - off] : 0;
        __syncthreads();
        if (t >= off) sums[t] += xv;
        __syncthreads();
    }
    int run = (t > 0) ? sums[t - 1] : 0;
#pragma unroll
    for (int j = 0; j < 4; ++j) { if (base + j < n) rowptr[base + j] = run; run += v[j]; }
    if (t == 255) blksums[blockIdx.x] = sums[255];
}

__global__ __launch_bounds__(256) void scan_totals_kernel(
    int* __restrict__ blksums, int* __restrict__ rowptr,
    int numBlocks, int n, int E)
{
    __shared__ int s[256];
    int t = threadIdx.x;
    s[t] = (t < numBlocks) ? blksums[t] : 0;
    __syncthreads();
    for (int off = 1; off < 256; off <<= 1) {
        int xv = (t >= off) ? s[t - off] : 0;
        __syncthreads();
        if (t >= off) s[t] += xv;
        __syncthreads();
    }
    if (t < numBlocks) blksums[t] = (t > 0) ? s[t - 1] : 0;
    if (t == 0) rowptr[n] = E;
}

__global__ __launch_bounds__(256) void add_offsets_kernel(
    int* __restrict__ rowptr, const int* __restrict__ blksums, int n)
{
    int i = blockIdx.x * 256 + threadIdx.x;
    if (i < n) rowptr[i] += blksums[i >> 10];
}

__global__ __launch_bounds__(256) void fill_win_kernel(
    const int* __restrict__ src, const int* __restrict__ dst,
    const int* __restrict__ rowptr, int* __restrict__ count,
    int* __restrict__ csr_src, int nEdges, int winSize)
{
    int pass    = blockIdx.x & 7;
    int slice   = blockIdx.x >> 3;
    int nSlices = gridDim.x >> 3;
    int lo = pass * winSize;
    int hi = lo + winSize;

    int stride = nSlices * blockDim.x;
    for (int i = slice * blockDim.x + threadIdx.x; i < nEdges; i += stride) {
        int d = dst[i];
        if (d >= lo && d < hi) {
            int pos = rowptr[d] + atomicSub(&count[d], 1) - 1;
            csr_src[pos] = src[i];
        }
    }
}

__global__ __launch_bounds__(256) void deg_from_rowptr_kernel(
    const int* __restrict__ rowptr, float* __restrict__ degf, int n)
{
    int i = blockIdx.x * 256 + threadIdx.x;
    if (i < n) degf[i] = (float)(rowptr[i + 1] - rowptr[i]);
}

// ===========================================================================
// tangent_kernel: th[n][:] = fp16( arctanh(clip(||x||))/max(||x||,eps) * x )
// ===========================================================================
__global__ __launch_bounds__(256) void tangent_kernel(
    const float* __restrict__ x, __half* __restrict__ th, int nNodes)
{
    int n    = (blockIdx.x * 256 + threadIdx.x) >> 6;
    int lane = threadIdx.x & 63;
    if (n >= nNodes) return;
    float2 xv = *reinterpret_cast<const float2*>(x + (size_t)n * D + lane * 2);
    float ss = xv.x * xv.x + xv.y * xv.y;
    ss += __shfl_xor(ss, 1);
    ss += __shfl_xor(ss, 2);
    ss += __shfl_xor(ss, 4);
    ss += __shfl_xor(ss, 8);
    ss += __shfl_xor(ss, 16);
    ss += __shfl_xor(ss, 32);
    float norm = sqrtf(ss);
    float ncl  = fminf(norm, 1.0f - 1e-7f);
    float at   = 0.5f * logf((1.0f + ncl) / (1.0f - ncl));
    float sc   = at / fmaxf(norm, 1e-15f);
    __half2 h = __float22half2_rn(make_float2(xv.x * sc, xv.y * sc));
    *(reinterpret_cast<__half2*>(th + (size_t)n * D) + lane) = h;
}

__global__ __launch_bounds__(256) void scale_kernel(
    const float* __restrict__ x, float* __restrict__ scale, int nNodes)
{
    int node = (blockIdx.x * 256 + threadIdx.x) >> 6;
    int lane = threadIdx.x & 63;
    if (node >= nNodes) return;
    float2 xv = *reinterpret_cast<const float2*>(x + (size_t)node * D + lane * 2);
    float ss = xv.x * xv.x + xv.y * xv.y;
    ss += __shfl_xor(ss, 1);
    ss += __shfl_xor(ss, 2);
    ss += __shfl_xor(ss, 4);
    ss += __shfl_xor(ss, 8);
    ss += __shfl_xor(ss, 16);
    ss += __shfl_xor(ss, 32);
    if (lane == 0) {
        float norm = sqrtf(ss);
        float ncl  = fminf(norm, 1.0f - 1e-7f);
        float at   = 0.5f * logf((1.0f + ncl) / (1.0f - ncl));
        scale[node] = at / fmaxf(norm, 1e-15f);
    }
}

// ===========================================================================
// gather, bf16 output: msgb[n] = bf16( sum th[src_e] )  (fp16 pk accumulate)
// 4 nodes/block (1 wave each); 4 groups x 16 lanes; 16 rows in flight/wave.
// ===========================================================================
__global__ __launch_bounds__(256) void gather_h16b_kernel(
    const __half* __restrict__ th,
    const int* __restrict__ csr_src, const int* __restrict__ rowptr,
    short* __restrict__ msgb, int nNodes)
{
    int n    = blockIdx.x * 4 + (threadIdx.x >> 6);
    int lane = threadIdx.x & 63;
    if (n >= nNodes) return;
    int grp = lane >> 4;
    int sl  = lane & 15;

    int beg = rowptr[n];
    int cnt = rowptr[n + 1] - beg;

    __half2 z = __float2half2_rn(0.0f);
    __half2 acc0[4] = {z, z, z, z};
    __half2 acc1[4] = {z, z, z, z};

    int k = grp;
    for (; k + 12 < cnt; k += 16) {
        int s0 = csr_src[beg + k];
        int s1 = csr_src[beg + k + 4];
        int s2 = csr_src[beg + k + 8];
        int s3 = csr_src[beg + k + 12];
        float4 r0 = *reinterpret_cast<const float4*>(th + (size_t)s0 * D + sl * 8);
        float4 r1 = *reinterpret_cast<const float4*>(th + (size_t)s1 * D + sl * 8);
        float4 r2 = *reinterpret_cast<const float4*>(th + (size_t)s2 * D + sl * 8);
        float4 r3 = *reinterpret_cast<const float4*>(th + (size_t)s3 * D + sl * 8);
        const __half2* h0 = reinterpret_cast<const __half2*>(&r0);
        const __half2* h1 = reinterpret_cast<const __half2*>(&r1);
        const __half2* h2 = reinterpret_cast<const __half2*>(&r2);
        const __half2* h3 = reinterpret_cast<const __half2*>(&r3);
#pragma unroll
        for (int j = 0; j < 4; ++j) {
            acc0[j] = __hadd2(acc0[j], h0[j]);
            acc1[j] = __hadd2(acc1[j], h1[j]);
            acc0[j] = __hadd2(acc0[j], h2[j]);
            acc1[j] = __hadd2(acc1[j], h3[j]);
        }
    }
    for (; k < cnt; k += 4) {
        int s0 = csr_src[beg + k];
        float4 r0 = *reinterpret_cast<const float4*>(th + (size_t)s0 * D + sl * 8);
        const __half2* h0 = reinterpret_cast<const __half2*>(&r0);
#pragma unroll
        for (int j = 0; j < 4; ++j) acc0[j] = __hadd2(acc0[j], h0[j]);
    }
#pragma unroll
    for (int j = 0; j < 4; ++j) {
        acc0[j] = __hadd2(acc0[j], acc1[j]);
        float f16 = __shfl_xor(__builtin_bit_cast(float, acc0[j]), 16);
        acc0[j] = __hadd2(acc0[j], __builtin_bit_cast(__half2, f16));
        float f32v = __shfl_xor(__builtin_bit_cast(float, acc0[j]), 32);
        acc0[j] = __hadd2(acc0[j], __builtin_bit_cast(__half2, f32v));
    }
    if (grp == 0) {
        short s8[8];
#pragma unroll
        for (int j = 0; j < 4; ++j) {
            float2 f = __half22float2(acc0[j]);
            s8[2 * j]     = f2bf(f.x);
            s8[2 * j + 1] = f2bf(f.y);
        }
        *reinterpret_cast<float4*>(msgb + (size_t)n * D + sl * 8) =
            *reinterpret_cast<float4*>(s8);
    }
}

// gather, fp32 output (msg aliases d_out) — used when ws can't hold msgb
__global__ __launch_bounds__(256) void gather_h16_kernel(
    const __half* __restrict__ th,
    const int* __restrict__ csr_src, const int* __restrict__ rowptr,
    float* __restrict__ msg, int nNodes)
{
    int n    = blockIdx.x * 4 + (threadIdx.x >> 6);
    int lane = threadIdx.x & 63;
    if (n >= nNodes) return;
    int grp = lane >> 4;
    int sl  = lane & 15;

    int beg = rowptr[n];
    int cnt = rowptr[n + 1] - beg;

    __half2 z = __float2half2_rn(0.0f);
    __half2 acc0[4] = {z, z, z, z};
    __half2 acc1[4] = {z, z, z, z};

    int k = grp;
    for (; k + 12 < cnt; k += 16) {
        int s0 = csr_src[beg + k];
        int s1 = csr_src[beg + k + 4];
        int s2 = csr_src[beg + k + 8];
        int s3 = csr_src[beg + k + 12];
        float4 r0 = *reinterpret_cast<const float4*>(th + (size_t)s0 * D + sl * 8);
        float4 r1 = *reinterpret_cast<const float4*>(th + (size_t)s1 * D + sl * 8);
        float4 r2 = *reinterpret_cast<const float4*>(th + (size_t)s2 * D + sl * 8);
        float4 r3 = *reinterpret_cast<const float4*>(th + (size_t)s3 * D + sl * 8);
        const __half2* h0 = reinterpret_cast<const __half2*>(&r0);
        const __half2* h1 = reinterpret_cast<const __half2*>(&r1);
        const __half2* h2 = reinterpret_cast<const __half2*>(&r2);
        const __half2* h3 = reinterpret_cast<const __half2*>(&r3);
#pragma unroll
        for (int j = 0; j < 4; ++j) {
            acc0[j] = __hadd2(acc0[j], h0[j]);
            acc1[j] = __hadd2(acc1[j], h1[j]);
            acc0[j] = __hadd2(acc0[j], h2[j]);
            acc1[j] = __hadd2(acc1[j], h3[j]);
        }
    }
    for (; k < cnt; k += 4) {
        int s0 = csr_src[beg + k];
        float4 r0 = *reinterpret_cast<const float4*>(th + (size_t)s0 * D + sl * 8);
        const __half2* h0 = reinterpret_cast<const __half2*>(&r0);
#pragma unroll
        for (int j = 0; j < 4; ++j) acc0[j] = __hadd2(acc0[j], h0[j]);
    }
#pragma unroll
    for (int j = 0; j < 4; ++j) {
        acc0[j] = __hadd2(acc0[j], acc1[j]);
        float f16 = __shfl_xor(__builtin_bit_cast(float, acc0[j]), 16);
        acc0[j] = __hadd2(acc0[j], __builtin_bit_cast(__half2, f16));
        float f32v = __shfl_xor(__builtin_bit_cast(float, acc0[j]), 32);
        acc0[j] = __hadd2(acc0[j], __builtin_bit_cast(__half2, f32v));
    }
    if (grp == 0) {
        float2 f0 = __half22float2(acc0[0]);
        float2 f1 = __half22float2(acc0[1]);
        float2 f2 = __half22float2(acc0[2]);
        float2 f3 = __half22float2(acc0[3]);
        float4 o0 = make_float4(f0.x, f0.y, f1.x, f1.y);
        float4 o1 = make_float4(f2.x, f2.y, f3.x, f3.y);
        *reinterpret_cast<float4*>(msg + (size_t)n * D + sl * 8)     = o0;
        *reinterpret_cast<float4*>(msg + (size_t)n * D + sl * 8 + 4) = o1;
    }
}

// gather (fp32 rows) — mid tier
__global__ __launch_bounds__(256) void gather_kernel(
    const float* __restrict__ x, const float* __restrict__ scale,
    const int* __restrict__ csr_src, const int* __restrict__ rowptr,
    float* __restrict__ msg, float* __restrict__ degf, int nNodes)
{
    int n    = blockIdx.x * 4 + (threadIdx.x >> 6);
    int lane = threadIdx.x & 63;
    if (n >= nNodes) return;

    int beg = rowptr[n], end = rowptr[n + 1];
    float2 acc0 = make_float2(0.0f, 0.0f);
    float2 acc1 = make_float2(0.0f, 0.0f);
    int e = beg;
    for (; e + 3 < end; e += 4) {
        int s0 = csr_src[e],     s1 = csr_src[e + 1];
        int s2 = csr_src[e + 2], s3 = csr_src[e + 3];
        float sc0 = scale[s0], sc1 = scale[s1];
        float sc2 = scale[s2], sc3 = scale[s3];
        float2 a = *reinterpret_cast<const float2*>(x + (size_t)s0 * D + lane * 2);
        float2 b = *reinterpret_cast<const float2*>(x + (size_t)s1 * D + lane * 2);
        float2 c = *reinterpret_cast<const float2*>(x + (size_t)s2 * D + lane * 2);
        float2 d = *reinterpret_cast<const float2*>(x + (size_t)s3 * D + lane * 2);
        acc0.x += sc0 * a.x;  acc0.y += sc0 * a.y;
        acc1.x += sc1 * b.x;  acc1.y += sc1 * b.y;
        acc0.x += sc2 * c.x;  acc0.y += sc2 * c.y;
        acc1.x += sc3 * d.x;  acc1.y += sc3 * d.y;
    }
    for (; e < end; ++e) {
        int s0 = csr_src[e];
        float sc0 = scale[s0];
        float2 a = *reinterpret_cast<const float2*>(x + (size_t)s0 * D + lane * 2);
        acc0.x += sc0 * a.x;  acc0.y += sc0 * a.y;
    }
    acc0.x += acc1.x;  acc0.y += acc1.y;
    *reinterpret_cast<float2*>(msg + (size_t)n * D + lane * 2) = acc0;
    if (lane == 0) degf[n] = (float)(end - beg);
}

// ===========================================================================
// Fallback edge scatter (fp32 hardware atomics) — last resort
// ===========================================================================
__global__ __launch_bounds__(256) void edge_scatter_kernel(
    const float* __restrict__ x,
    const int* __restrict__ src,
    const int* __restrict__ dst,
    float* __restrict__ msg,
    float* __restrict__ deg,
    int nEdges)
{
    long long t = (long long)blockIdx.x * blockDim.x + threadIdx.x;
    int edge = (int)(t >> 5);
    int lane = (int)(t & 31);
    if (edge >= nEdges) return;

    int s = src[edge];
    int d = dst[edge];

    const float4 xv = *reinterpret_cast<const float4*>(x + (size_t)s * D + lane * 4);
    float ss = xv.x * xv.x + xv.y * xv.y + xv.z * xv.z + xv.w * xv.w;
    ss += __shfl_xor(ss, 1);
    ss += __shfl_xor(ss, 2);
    ss += __shfl_xor(ss, 4);
    ss += __shfl_xor(ss, 8);
    ss += __shfl_xor(ss, 16);

    float norm = sqrtf(ss);
    float ncl  = fminf(norm, 1.0f - 1e-7f);
    float at   = 0.5f * logf((1.0f + ncl) / (1.0f - ncl));
    float scale = at / fmaxf(norm, 1e-15f);

    float* mrow = msg + (size_t)d * D + lane * 4;
    unsafeAtomicAdd(mrow + 0, xv.x * scale);
    unsafeAtomicAdd(mrow + 1, xv.y * scale);
    unsafeAtomicAdd(mrow + 2, xv.z * scale);
    unsafeAtomicAdd(mrow + 3, xv.w * scale);
    if (lane == 0) unsafeAtomicAdd(deg + d, 1.0f);
}

// ===========================================================================
// MFMA bf16 GEMM + expmap, bf16 A: out = expmap0( (msgb@W^T)/max(deg,1)+b ),
// zeroed where deg==0. msgb in ws — no aliasing with out.
// ===========================================================================
__global__ __launch_bounds__(256) void gemm_mfma_b_kernel(
    const short* __restrict__ msgb, const float* __restrict__ deg,
    const float* __restrict__ W, const float* __restrict__ bias,
    float* __restrict__ out, int nNodes)
{
    __shared__ short sW[128][136];

    const int t = threadIdx.x;

#pragma unroll
    for (int p = 0; p < 16; ++p) {
        int chunk = p * 256 + t;
        int row = chunk >> 5;
        int c4  = (chunk & 31) * 4;
        float4 v = *reinterpret_cast<const float4*>(W + row * 128 + c4);
        short4 s;
        s.x = f2bf(v.x); s.y = f2bf(v.y); s.z = f2bf(v.z); s.w = f2bf(v.w);
        *reinterpret_cast<short4*>(&sW[row][c4]) = s;
    }
    __syncthreads();

    const int wave = t >> 6;
    const int lane = t & 63;
    const int l15  = lane & 15;
    const int lhi  = lane >> 4;
    const int m0   = blockIdx.x * 64 + wave * 16;

    int arow = m0 + l15;
    if (arow >= nNodes) arow = nNodes - 1;
    const short* ap = msgb + (size_t)arow * D + lhi * 8;
    bf16x8 a[4];
#pragma unroll
    for (int kc = 0; kc < 4; ++kc)
        a[kc] = *reinterpret_cast<const bf16x8*>(ap + kc * 32);

    f32x4 acc[8];
#pragma unroll
    for (int ct = 0; ct < 8; ++ct) acc[ct] = (f32x4){0.f, 0.f, 0.f, 0.f};

#pragma unroll
    for (int ct = 0; ct < 8; ++ct) {
#pragma unroll
        for (int kc = 0; kc < 4; ++kc) {
            bf16x8 bfrag = *reinterpret_cast<const bf16x8*>(
                &sW[ct * 16 + l15][kc * 32 + lhi * 8]);
            acc[ct] = __builtin_amdgcn_mfma_f32_16x16x32_bf16(a[kc], bfrag, acc[ct], 0, 0, 0);
        }
    }

    float bv[8];
#pragma unroll
    for (int ct = 0; ct < 8; ++ct) bv[ct] = bias[ct * 16 + l15];

#pragma unroll
    for (int r = 0; r < 4; ++r) {
        int row = m0 + lhi * 4 + r;
        int rc  = row < nNodes ? row : nNodes - 1;
        float dg  = deg[rc];
        float inv = 1.0f / fmaxf(dg, 1.0f);
        float v[8];
        float ss = 0.0f;
#pragma unroll
        for (int ct = 0; ct < 8; ++ct) {
            v[ct] = acc[ct][r] * inv + bv[ct];
            ss += v[ct] * v[ct];
        }
        ss += __shfl_xor(ss, 1);
        ss += __shfl_xor(ss, 2);
        ss += __shfl_xor(ss, 4);
        ss += __shfl_xor(ss, 8);
        float norm = sqrtf(ss);
        float sc = (dg > 0.0f) ? (tanhf(norm) / fmaxf(norm, 1e-15f)) : 0.0f;
        if (row < nNodes) {
#pragma unroll
            for (int ct = 0; ct < 8; ++ct)
                out[(size_t)row * D + ct * 16 + l15] = v[ct] * sc;
        }
    }
}

// fp32-A variant (msg may alias out; in-place safe — reads precede stores)
__global__ __launch_bounds__(256) void gemm_mfma_kernel(
    const float* msg, const float* __restrict__ deg,
    const float* __restrict__ W, const float* __restrict__ bias,
    float* out, int nNodes)
{
    __shared__ short sW[128][136];

    const int t = threadIdx.x;

#pragma unroll
    for (int p = 0; p < 16; ++p) {
        int chunk = p * 256 + t;
        int row = chunk >> 5;
        int c4  = (chunk & 31) * 4;
        float4 v = *reinterpret_cast<const float4*>(W + row * 128 + c4);
        short4 s;
        s.x = f2bf(v.x); s.y = f2bf(v.y); s.z = f2bf(v.z); s.w = f2bf(v.w);
        *reinterpret_cast<short4*>(&sW[row][c4]) = s;
    }
    __syncthreads();

    const int wave = t >> 6;
    const int lane = t & 63;
    const int l15  = lane & 15;
    const int lhi  = lane >> 4;
    const int m0   = blockIdx.x * 64 + wave * 16;

    int arow = m0 + l15;
    if (arow >= nNodes) arow = nNodes - 1;
    const float* ap = msg + (size_t)arow * D + lhi * 8;
    bf16x8 a[4];
#pragma unroll
    for (int kc = 0; kc < 4; ++kc) {
        float4 v0 = *reinterpret_cast<const float4*>(ap + kc * 32);
        float4 v1 = *reinterpret_cast<const float4*>(ap + kc * 32 + 4);
        bf16x8 f;
        f[0] = f2bf(v0.x); f[1] = f2bf(v0.y); f[2] = f2bf(v0.z); f[3] = f2bf(v0.w);
        f[4] = f2bf(v1.x); f[5] = f2bf(v1.y); f[6] = f2bf(v1.z); f[7] = f2bf(v1.w);
        a[kc] = f;
    }

    f32x4 acc[8];
#pragma unroll
    for (int ct = 0; ct < 8; ++ct) acc[ct] = (f32x4){0.f, 0.f, 0.f, 0.f};

#pragma unroll
    for (int ct = 0; ct < 8; ++ct) {
#pragma unroll
        for (int kc = 0; kc < 4; ++kc) {
            bf16x8 bfrag = *reinterpret_cast<const bf16x8*>(
                &sW[ct * 16 + l15][kc * 32 + lhi * 8]);
            acc[ct] = __builtin_amdgcn_mfma_f32_16x16x32_bf16(a[kc], bfrag, acc[ct], 0, 0, 0);
        }
    }

    float bv[8];
#pragma unroll
    for (int ct = 0; ct < 8; ++ct) bv[ct] = bias[ct * 16 + l15];

#pragma unroll
    for (int r = 0; r < 4; ++r) {
        int row = m0 + lhi * 4 + r;
        int rc  = row < nNodes ? row : nNodes - 1;
        float dg  = deg[rc];
        float inv = 1.0f / fmaxf(dg, 1.0f);
        float v[8];
        float ss = 0.0f;
#pragma unroll
        for (int ct = 0; ct < 8; ++ct) {
            v[ct] = acc[ct][r] * inv + bv[ct];
            ss += v[ct] * v[ct];
        }
        ss += __shfl_xor(ss, 1);
        ss += __shfl_xor(ss, 2);
        ss += __shfl_xor(ss, 4);
        ss += __shfl_xor(ss, 8);
        float norm = sqrtf(ss);
        float sc = (dg > 0.0f) ? (tanhf(norm) / fmaxf(norm, 1e-15f)) : 0.0f;
        if (row < nNodes) {
#pragma unroll
            for (int ct = 0; ct < 8; ++ct)
                out[(size_t)row * D + ct * 16 + l15] = v[ct] * sc;
        }
    }
}

static inline size_t align256(size_t o) { return (o + 255) & ~(size_t)255; }

extern "C" void kernel_launch(void* const* d_in, const int* in_sizes, int n_in,
                              void* d_out, int out_size, void* d_ws, size_t ws_size,
                              hipStream_t stream) {
    const float* x   = (const float*)d_in[0];
    const float* W   = (const float*)d_in[1];
    const float* b   = (const float*)d_in[2];
    const int*   src = (const int*)d_in[3];
    const int*   dst = (const int*)d_in[4];
    float* out = (float*)d_out;

    int nNodes = in_sizes[0] / D;
    int nEdges = in_sizes[3];
    int NB = (nNodes + BNODES - 1) >> BSH;

    // workspace layout (tiered)
    char* ws = (char*)d_ws;
    size_t off = 0;
    float* degf    = (float*)(ws + off); off = align256(off + sizeof(float) * nNodes);
    int*   count   = (int*)  (ws + off); off = align256(off + sizeof(int) * nNodes);
    int*   rowptr  = (int*)  (ws + off); off = align256(off + sizeof(int) * (nNodes + 1));
    float* scl     = (float*)(ws + off); off = align256(off + sizeof(float) * nNodes);
    int*   blksums = (int*)  (ws + off); off = align256(off + sizeof(int) * 256);
    int*   bbase   = (int*)  (ws + off); off = align256(off + sizeof(int) * 257);
    int*   btot    = (int*)  (ws + off); off = align256(off + sizeof(int) * 256);
    int*   blkhist = (int*)  (ws + off); off = align256(off + sizeof(int) * NBLK * 256);
    int*   csr_src = (int*)  (ws + off); off = align256(off + sizeof(int) * nEdges);
    size_t need_mid = off;
    // region A: part (P1-P3) then th (tangent onward) — sequential stream use
    unsigned* part = (unsigned*)(ws + off);
    __half*   th   = (__half*)  (ws + off);
    size_t szA = sizeof(__half) * (size_t)nNodes * D;
    if (sizeof(unsigned) * (size_t)nEdges > szA) szA = sizeof(unsigned) * (size_t)nEdges;
    off = align256(off + szA);
    size_t need_part = off;
    short* msgb = (short*)(ws + off); off = align256(off + sizeof(short) * (size_t)nNodes * D);
    size_t need_msgb = off;

    float* msg = out;  // fp32 msg staging (aliases out) for non-msgb tiers

    int numScanBlocks = (nNodes + 1023) / 1024;
    bool part_ok = (ws_size >= need_part) && (nNodes <= 131072) && (NB <= 256);
    bool bf16msg = part_ok && (ws_size >= need_msgb);
    bool mid_ok  = (ws_size >= need_mid) && (numScanBlocks <= 256);

    if (part_ok) {
        // ---- LDS-atomic bucket partition -> CSR (no global atomics) ----
        part_hist_kernel<<<NBLK, 256, 0, stream>>>(dst, blkhist, nEdges, NB);
        part_scan1_kernel<<<NB, 256, 0, stream>>>(blkhist, btot);
        part_scan2_kernel<<<1, 256, 0, stream>>>(btot, bbase, NB, nEdges);
        part_scatter_kernel<<<NBLK, 256, 0, stream>>>(src, dst, blkhist, bbase, part, nEdges, NB);
        bucket_csr_kernel<<<NB, 256, 0, stream>>>(part, bbase, rowptr, degf,
                                                  csr_src, nNodes, NB, nEdges);
        // part no longer needed; th reuses the region
        tangent_kernel<<<(nNodes + 3) / 4, 256, 0, stream>>>(x, th, nNodes);
        if (bf16msg) {
            gather_h16b_kernel<<<(nNodes + 3) / 4, 256, 0, stream>>>(th, csr_src, rowptr, msgb, nNodes);
            gemm_mfma_b_kernel<<<(nNodes + 63) / 64, 256, 0, stream>>>(msgb, degf, W, b, out, nNodes);
        } else {
            gather_h16_kernel<<<(nNodes + 3) / 4, 256, 0, stream>>>(th, csr_src, rowptr, msg, nNodes);
            gemm_mfma_kernel<<<(nNodes + 63) / 64, 256, 0, stream>>>(msg, degf, W, b, out, nNodes);
        }
        return;
    }

    if (mid_ok) {
        // ---- mid tier: windowed atomic hist + down-count fill, fp32 gather ----
        hipMemsetAsync(count, 0, sizeof(int) * nNodes, stream);
        int winSize = (nNodes + 7) / 8;
        hist_win_kernel<<<4096, 256, 0, stream>>>(dst, count, nEdges, winSize);
        scan_block_kernel<<<numScanBlocks, 256, 0, stream>>>(count, rowptr, blksums, nNodes);
        scan_totals_kernel<<<1, 256, 0, stream>>>(blksums, rowptr, numScanBlocks, nNodes, nEdges);
        add_offsets_kernel<<<(nNodes + 255) / 256, 256, 0, stream>>>(rowptr, blksums, nNodes);
        fill_win_kernel<<<4096, 256, 0, stream>>>(src, dst, rowptr, count, csr_src, nEdges, winSize);
        deg_from_rowptr_kernel<<<(nNodes + 255) / 256, 256, 0, stream>>>(rowptr, degf, nNodes);

        scale_kernel<<<(nNodes + 3) / 4, 256, 0, stream>>>(x, scl, nNodes);
        gather_kernel<<<(nNodes + 3) / 4, 256, 0, stream>>>(x, scl, csr_src, rowptr, msg, degf, nNodes);
        gemm_mfma_kernel<<<(nNodes + 63) / 64, 256, 0, stream>>>(msg, degf, W, b, out, nNodes);
        return;
    }

    {
        float* deg = (float*)d_ws;
        hipMemsetAsync(msg, 0, (size_t)nNodes * D * sizeof(float), stream);
        hipMemsetAsync(deg, 0, (size_t)nNodes * sizeof(float), stream);
        long long threads = (long long)nEdges * 32;
        int blocks = (int)((threads + 255) / 256);
        edge_scatter_kernel<<<blocks, 256, 0, stream>>>(x, src, dst, msg, (float*)d_ws, nEdges);
        gemm_mfma_kernel<<<(nNodes + 63) / 64, 256, 0, stream>>>(msg, (float*)d_ws, W, b, out, nNodes);
    }
}

// Round 11
// 140.788 us; speedup vs baseline: 1.7246x; 1.0617x over previous
//
#include <hip/hip_runtime.h>
#include <hip/hip_fp16.h>
#include <math.h>

constexpr int D = 128;
constexpr int BSH = 9;               // 512 nodes per bucket
constexpr int BNODES = 1 << BSH;
constexpr int NBLK = 256;            // partition pass blocks

typedef __attribute__((ext_vector_type(8))) short bf16x8;
typedef __attribute__((ext_vector_type(4))) float f32x4;

__device__ inline short f2bf(float f) {
    unsigned u = __builtin_bit_cast(unsigned, f);
    u = (u + 0x7FFFu + ((u >> 16) & 1u)) >> 16;   // round-to-nearest-even
    return (short)u;
}

// ===========================================================================
// Combo: blocks [0,NBLK) do the per-block LDS bucket histogram; the rest do
// tangent (th = fp16 logmap0 rows). Independent work, runs concurrently.
// blkhist TRANSPOSED [bucket][blk] for coalesced scans.
// ===========================================================================
__global__ __launch_bounds__(256) void hist_tangent_kernel(
    const int* __restrict__ dst, int* __restrict__ blkhist,
    int nEdges, int NB,
    const float* __restrict__ x, __half* __restrict__ th, int nNodes)
{
    __shared__ int hist[256];
    int t = threadIdx.x;

    if (blockIdx.x < NBLK) {
        hist[t] = 0;
        __syncthreads();
        int per = (nEdges + NBLK - 1) / NBLK;
        int i0 = blockIdx.x * per;
        int i1 = min(nEdges, i0 + per);
        for (int i = i0 + t; i < i1; i += 256)
            atomicAdd(&hist[dst[i] >> BSH], 1);
        __syncthreads();
        if (t < NB) blkhist[t * NBLK + blockIdx.x] = hist[t];
        return;
    }

    // tangent: 4 nodes per block, one wave each
    int nb = blockIdx.x - NBLK;
    int n    = (nb * 256 + t) >> 6;
    int lane = t & 63;
    if (n >= nNodes) return;
    float2 xv = *reinterpret_cast<const float2*>(x + (size_t)n * D + lane * 2);
    float ss = xv.x * xv.x + xv.y * xv.y;
    ss += __shfl_xor(ss, 1);
    ss += __shfl_xor(ss, 2);
    ss += __shfl_xor(ss, 4);
    ss += __shfl_xor(ss, 8);
    ss += __shfl_xor(ss, 16);
    ss += __shfl_xor(ss, 32);
    float norm = sqrtf(ss);
    float ncl  = fminf(norm, 1.0f - 1e-7f);
    float at   = 0.5f * logf((1.0f + ncl) / (1.0f - ncl));
    float sc   = at / fmaxf(norm, 1e-15f);
    __half2 h = __float22half2_rn(make_float2(xv.x * sc, xv.y * sc));
    *(reinterpret_cast<__half2*>(th + (size_t)n * D) + lane) = h;
}

// P1.5: one block per bucket: scan per-block counts -> exclusive, total out
__global__ __launch_bounds__(256) void part_scan1_kernel(
    int* __restrict__ blkhist, int* __restrict__ btot)
{
    __shared__ int s[256];
    int b = blockIdx.x;
    int t = threadIdx.x;
    int v = blkhist[b * NBLK + t];
    s[t] = v;
    __syncthreads();
    for (int off = 1; off < 256; off <<= 1) {
        int xv = (t >= off) ? s[t - off] : 0;
        __syncthreads();
        if (t >= off) s[t] += xv;
        __syncthreads();
    }
    blkhist[b * NBLK + t] = s[t] - v;   // exclusive
    if (t == 255) btot[b] = s[255];
}

// ===========================================================================
// P2: scatter edges into bucket-partitioned array. LDS cursors only; bucket
// bases recomputed per-block from btot (folds old scan2 away).
// part[p] = src | dloc<<17  (requires nNodes <= 131072)
// ===========================================================================
__global__ __launch_bounds__(256) void part_scatter_kernel(
    const int* __restrict__ src, const int* __restrict__ dst,
    const int* __restrict__ blkhist, const int* __restrict__ btot,
    unsigned* __restrict__ part, int nEdges, int NB)
{
    __shared__ int sb[256];
    __shared__ int cur[256];
    int t = threadIdx.x;
    int v = (t < NB) ? btot[t] : 0;
    sb[t] = v;
    __syncthreads();
    for (int off = 1; off < 256; off <<= 1) {
        int xv = (t >= off) ? sb[t - off] : 0;
        __syncthreads();
        if (t >= off) sb[t] += xv;
        __syncthreads();
    }
    int bbase_t = sb[t] - v;   // exclusive prefix of bucket totals
    cur[t] = (t < NB) ? (blkhist[t * NBLK + blockIdx.x] + bbase_t) : 0;
    __syncthreads();

    int per = (nEdges + gridDim.x - 1) / gridDim.x;
    int i0 = blockIdx.x * per;
    int i1 = min(nEdges, i0 + per);
    for (int i = i0 + t; i < i1; i += 256) {
        int d = dst[i];
        int b = d >> BSH;
        int p = atomicAdd(&cur[b], 1);
        part[p] = (unsigned)src[i] | ((unsigned)(d & (BNODES - 1)) << 17);
    }
}

// ===========================================================================
// P3: per-bucket CSR build. Bucket bases recomputed from btot in LDS.
// ===========================================================================
__global__ __launch_bounds__(256) void bucket_csr_kernel(
    const unsigned* __restrict__ part, const int* __restrict__ btot,
    int* __restrict__ rowptr, float* __restrict__ degf,
    int* __restrict__ csr_src, int nNodes, int NB, int nEdges)
{
    __shared__ int cnt[BNODES];
    __shared__ int excl[BNODES];
    __shared__ int cur[BNODES];
    __shared__ int s[256];
    __shared__ int sBB[2];

    int b = blockIdx.x;
    int t = threadIdx.x;

    // bucket base from btot prefix
    int v = (t < NB) ? btot[t] : 0;
    s[t] = v;
    __syncthreads();
    for (int off = 1; off < 256; off <<= 1) {
        int xv = (t >= off) ? s[t - off] : 0;
        __syncthreads();
        if (t >= off) s[t] += xv;
        __syncthreads();
    }
    if (t == b) { sBB[0] = s[t] - v; sBB[1] = s[t]; }
    __syncthreads();
    int bb = sBB[0], be = sBB[1];

    cnt[t] = 0; cnt[t + 256] = 0;
    cur[t] = 0; cur[t + 256] = 0;
    __syncthreads();

    for (int i = bb + t; i < be; i += 256)
        atomicAdd(&cnt[part[i] >> 17], 1);
    __syncthreads();

    int a0 = cnt[2 * t], a1 = cnt[2 * t + 1];
    s[t] = a0 + a1;
    __syncthreads();
    for (int off = 1; off < 256; off <<= 1) {
        int xv = (t >= off) ? s[t - off] : 0;
        __syncthreads();
        if (t >= off) s[t] += xv;
        __syncthreads();
    }
    int pbase = (t > 0) ? s[t - 1] : 0;
    excl[2 * t]     = pbase;
    excl[2 * t + 1] = pbase + a0;
    __syncthreads();

    int node0 = b << BSH;
#pragma unroll
    for (int q = 0; q < 2; ++q) {
        int j = t + q * 256;
        int d = node0 + j;
        if (d < nNodes) {
            rowptr[d] = bb + excl[j];
            degf[d]   = (float)cnt[j];
        }
    }
    if (b == NB - 1 && t == 0) rowptr[nNodes] = nEdges;

    for (int i = bb + t; i < be; i += 256) {
        unsigned vv = part[i];
        int dloc = vv >> 17;
        int p = bb + excl[dloc] + atomicAdd(&cur[dloc], 1);
        csr_src[p] = (int)(vv & 0x1FFFFu);
    }
}

// ===========================================================================
// mid-tier CSR build (global atomics, windowed) — fallback if ws too small
// ===========================================================================
__global__ __launch_bounds__(256) void hist_win_kernel(
    const int* __restrict__ dst, int* __restrict__ count,
    int nEdges, int winSize)
{
    int pass    = blockIdx.x & 7;
    int slice   = blockIdx.x >> 3;
    int nSlices = gridDim.x >> 3;
    int lo = pass * winSize;
    int hi = lo + winSize;

    int stride = nSlices * blockDim.x;
    for (int i = slice * blockDim.x + threadIdx.x; i < nEdges; i += stride) {
        int d = dst[i];
        if (d >= lo && d < hi) atomicAdd(&count[d], 1);
    }
}

__global__ __launch_bounds__(256) void scan_block_kernel(
    const int* __restrict__ count, int* __restrict__ rowptr,
    int* __restrict__ blksums, int n)
{
    __shared__ int sums[256];
    int t = threadIdx.x;
    int base = blockIdx.x * 1024 + t * 4;
    int v[4];
    int s = 0;
#pragma unroll
    for (int j = 0; j < 4; ++j) { v[j] = (base + j < n) ? count[base + j] : 0; s += v[j]; }
    sums[t] = s;
    __syncthreads();
    for (int off = 1; off < 256; off <<= 1) {
        int xv = (t >= off) ? sums[t - off] : 0;
        __syncthreads();
        if (t >= off) sums[t] += xv;
        __syncthreads();
    }
    int run = (t > 0) ? sums[t - 1] : 0;
#pragma unroll
    for (int j = 0; j < 4; ++j) { if (base + j < n) rowptr[base + j] = run; run += v[j]; }
    if (t == 255) blksums[blockIdx.x] = sums[255];
}

__global__ __launch_bounds__(256) void scan_totals_kernel(
    int* __restrict__ blksums, int* __restrict__ rowptr,
    int numBlocks, int n, int E)
{
    __shared__ int s[256];
    int t = threadIdx.x;
    s[t] = (t < numBlocks) ? blksums[t] : 0;
    __syncthreads();
    for (int off = 1; off < 256; off <<= 1) {
        int xv = (t >= off) ? s[t - off] : 0;
        __syncthreads();
        if (t >= off) s[t] += xv;
        __syncthreads();
    }
    if (t < numBlocks) blksums[t] = (t > 0) ? s[t - 1] : 0;
    if (t == 0) rowptr[n] = E;
}

__global__ __launch_bounds__(256) void add_offsets_kernel(
    int* __restrict__ rowptr, const int* __restrict__ blksums, int n)
{
    int i = blockIdx.x * 256 + threadIdx.x;
    if (i < n) rowptr[i] += blksums[i >> 10];
}

__global__ __launch_bounds__(256) void fill_win_kernel(
    const int* __restrict__ src, const int* __restrict__ dst,
    const int* __restrict__ rowptr, int* __restrict__ count,
    int* __restrict__ csr_src, int nEdges, int winSize)
{
    int pass    = blockIdx.x & 7;
    int slice   = blockIdx.x >> 3;
    int nSlices = gridDim.x >> 3;
    int lo = pass * winSize;
    int hi = lo + winSize;

    int stride = nSlices * blockDim.x;
    for (int i = slice * blockDim.x + threadIdx.x; i < nEdges; i += stride) {
        int d = dst[i];
        if (d >= lo && d < hi) {
            int pos = rowptr[d] + atomicSub(&count[d], 1) - 1;
            csr_src[pos] = src[i];
        }
    }
}

__global__ __launch_bounds__(256) void deg_from_rowptr_kernel(
    const int* __restrict__ rowptr, float* __restrict__ degf, int n)
{
    int i = blockIdx.x * 256 + threadIdx.x;
    if (i < n) degf[i] = (float)(rowptr[i + 1] - rowptr[i]);
}

__global__ __launch_bounds__(256) void scale_kernel(
    const float* __restrict__ x, float* __restrict__ scale, int nNodes)
{
    int node = (blockIdx.x * 256 + threadIdx.x) >> 6;
    int lane = threadIdx.x & 63;
    if (node >= nNodes) return;
    float2 xv = *reinterpret_cast<const float2*>(x + (size_t)node * D + lane * 2);
    float ss = xv.x * xv.x + xv.y * xv.y;
    ss += __shfl_xor(ss, 1);
    ss += __shfl_xor(ss, 2);
    ss += __shfl_xor(ss, 4);
    ss += __shfl_xor(ss, 8);
    ss += __shfl_xor(ss, 16);
    ss += __shfl_xor(ss, 32);
    if (lane == 0) {
        float norm = sqrtf(ss);
        float ncl  = fminf(norm, 1.0f - 1e-7f);
        float at   = 0.5f * logf((1.0f + ncl) / (1.0f - ncl));
        scale[node] = at / fmaxf(norm, 1e-15f);
    }
}

// ===========================================================================
// gather, bf16 out, 2 nodes per wave (8/block): groups {0,1}->node0,
// {2,3}->node1; per node 2 groups at slot stride 2, 4-deep unroll =
// 16 rows in flight/wave across 2 independent nodes (overlaps per-node
// reduce/write serialization).
// ===========================================================================
__global__ __launch_bounds__(256) void gather2_h16b_kernel(
    const __half* __restrict__ th,
    const int* __restrict__ csr_src, const int* __restrict__ rowptr,
    short* __restrict__ msgb, int nNodes)
{
    int t    = threadIdx.x;
    int lane = t & 63;
    int wave = t >> 6;
    int grp  = lane >> 4;
    int np   = grp >> 1;      // node select 0/1
    int g2   = grp & 1;       // slot parity
    int sl   = lane & 15;     // owns elements [8*sl, 8*sl+8)

    int n  = blockIdx.x * 8 + wave * 2 + np;
    int nn = n < nNodes ? n : nNodes - 1;
    int beg = rowptr[nn];
    int cnt = rowptr[nn + 1] - beg;

    __half2 z = __float2half2_rn(0.0f);
    __half2 acc0[4] = {z, z, z, z};
    __half2 acc1[4] = {z, z, z, z};

    int k = g2;
    for (; k + 6 < cnt; k += 8) {
        int s0 = csr_src[beg + k];
        int s1 = csr_src[beg + k + 2];
        int s2 = csr_src[beg + k + 4];
        int s3 = csr_src[beg + k + 6];
        float4 r0 = *reinterpret_cast<const float4*>(th + (size_t)s0 * D + sl * 8);
        float4 r1 = *reinterpret_cast<const float4*>(th + (size_t)s1 * D + sl * 8);
        float4 r2 = *reinterpret_cast<const float4*>(th + (size_t)s2 * D + sl * 8);
        float4 r3 = *reinterpret_cast<const float4*>(th + (size_t)s3 * D + sl * 8);
        const __half2* h0 = reinterpret_cast<const __half2*>(&r0);
        const __half2* h1 = reinterpret_cast<const __half2*>(&r1);
        const __half2* h2 = reinterpret_cast<const __half2*>(&r2);
        const __half2* h3 = reinterpret_cast<const __half2*>(&r3);
#pragma unroll
        for (int j = 0; j < 4; ++j) {
            acc0[j] = __hadd2(acc0[j], h0[j]);
            acc1[j] = __hadd2(acc1[j], h1[j]);
            acc0[j] = __hadd2(acc0[j], h2[j]);
            acc1[j] = __hadd2(acc1[j], h3[j]);
        }
    }
    for (; k < cnt; k += 2) {
        int s0 = csr_src[beg + k];
        float4 r0 = *reinterpret_cast<const float4*>(th + (size_t)s0 * D + sl * 8);
        const __half2* h0 = reinterpret_cast<const __half2*>(&r0);
#pragma unroll
        for (int j = 0; j < 4; ++j) acc0[j] = __hadd2(acc0[j], h0[j]);
    }
#pragma unroll
    for (int j = 0; j < 4; ++j) {
        acc0[j] = __hadd2(acc0[j], acc1[j]);
        // combine the two slot-parity groups of this node (lanes ^16)
        float fx = __shfl_xor(__builtin_bit_cast(float, acc0[j]), 16);
        acc0[j] = __hadd2(acc0[j], __builtin_bit_cast(__half2, fx));
    }
    if (g2 == 0 && n < nNodes) {
        short s8[8];
#pragma unroll
        for (int j = 0; j < 4; ++j) {
            float2 f = __half22float2(acc0[j]);
            s8[2 * j]     = f2bf(f.x);
            s8[2 * j + 1] = f2bf(f.y);
        }
        *reinterpret_cast<float4*>(msgb + (size_t)n * D + sl * 8) =
            *reinterpret_cast<float4*>(s8);
    }
}

// gather, fp32 out (msg aliases d_out) — used when ws can't hold msgb
__global__ __launch_bounds__(256) void gather_h16_kernel(
    const __half* __restrict__ th,
    const int* __restrict__ csr_src, const int* __restrict__ rowptr,
    float* __restrict__ msg, int nNodes)
{
    int n    = blockIdx.x * 4 + (threadIdx.x >> 6);
    int lane = threadIdx.x & 63;
    if (n >= nNodes) return;
    int grp = lane >> 4;
    int sl  = lane & 15;

    int beg = rowptr[n];
    int cnt = rowptr[n + 1] - beg;

    __half2 z = __float2half2_rn(0.0f);
    __half2 acc0[4] = {z, z, z, z};
    __half2 acc1[4] = {z, z, z, z};

    int k = grp;
    for (; k + 12 < cnt; k += 16) {
        int s0 = csr_src[beg + k];
        int s1 = csr_src[beg + k + 4];
        int s2 = csr_src[beg + k + 8];
        int s3 = csr_src[beg + k + 12];
        float4 r0 = *reinterpret_cast<const float4*>(th + (size_t)s0 * D + sl * 8);
        float4 r1 = *reinterpret_cast<const float4*>(th + (size_t)s1 * D + sl * 8);
        float4 r2 = *reinterpret_cast<const float4*>(th + (size_t)s2 * D + sl * 8);
        float4 r3 = *reinterpret_cast<const float4*>(th + (size_t)s3 * D + sl * 8);
        const __half2* h0 = reinterpret_cast<const __half2*>(&r0);
        const __half2* h1 = reinterpret_cast<const __half2*>(&r1);
        const __half2* h2 = reinterpret_cast<const __half2*>(&r2);
        const __half2* h3 = reinterpret_cast<const __half2*>(&r3);
#pragma unroll
        for (int j = 0; j < 4; ++j) {
            acc0[j] = __hadd2(acc0[j], h0[j]);
            acc1[j] = __hadd2(acc1[j], h1[j]);
            acc0[j] = __hadd2(acc0[j], h2[j]);
            acc1[j] = __hadd2(acc1[j], h3[j]);
        }
    }
    for (; k < cnt; k += 4) {
        int s0 = csr_src[beg + k];
        float4 r0 = *reinterpret_cast<const float4*>(th + (size_t)s0 * D + sl * 8);
        const __half2* h0 = reinterpret_cast<const __half2*>(&r0);
#pragma unroll
        for (int j = 0; j < 4; ++j) acc0[j] = __hadd2(acc0[j], h0[j]);
    }
#pragma unroll
    for (int j = 0; j < 4; ++j) {
        acc0[j] = __hadd2(acc0[j], acc1[j]);
        float f16 = __shfl_xor(__builtin_bit_cast(float, acc0[j]), 16);
        acc0[j] = __hadd2(acc0[j], __builtin_bit_cast(__half2, f16));
        float f32v = __shfl_xor(__builtin_bit_cast(float, acc0[j]), 32);
        acc0[j] = __hadd2(acc0[j], __builtin_bit_cast(__half2, f32v));
    }
    if (grp == 0) {
        float2 f0 = __half22float2(acc0[0]);
        float2 f1 = __half22float2(acc0[1]);
        float2 f2 = __half22float2(acc0[2]);
        float2 f3 = __half22float2(acc0[3]);
        float4 o0 = make_float4(f0.x, f0.y, f1.x, f1.y);
        float4 o1 = make_float4(f2.x, f2.y, f3.x, f3.y);
        *reinterpret_cast<float4*>(msg + (size_t)n * D + sl * 8)     = o0;
        *reinterpret_cast<float4*>(msg + (size_t)n * D + sl * 8 + 4) = o1;
    }
}

// gather (fp32 rows) — mid tier
__global__ __launch_bounds__(256) void gather_kernel(
    const float* __restrict__ x, const float* __restrict__ scale,
    const int* __restrict__ csr_src, const int* __restrict__ rowptr,
    float* __restrict__ msg, float* __restrict__ degf, int nNodes)
{
    int n    = blockIdx.x * 4 + (threadIdx.x >> 6);
    int lane = threadIdx.x & 63;
    if (n >= nNodes) return;

    int beg = rowptr[n], end = rowptr[n + 1];
    float2 acc0 = make_float2(0.0f, 0.0f);
    float2 acc1 = make_float2(0.0f, 0.0f);
    int e = beg;
    for (; e + 3 < end; e += 4) {
        int s0 = csr_src[e],     s1 = csr_src[e + 1];
        int s2 = csr_src[e + 2], s3 = csr_src[e + 3];
        float sc0 = scale[s0], sc1 = scale[s1];
        float sc2 = scale[s2], sc3 = scale[s3];
        float2 a = *reinterpret_cast<const float2*>(x + (size_t)s0 * D + lane * 2);
        float2 b = *reinterpret_cast<const float2*>(x + (size_t)s1 * D + lane * 2);
        float2 c = *reinterpret_cast<const float2*>(x + (size_t)s2 * D + lane * 2);
        float2 d = *reinterpret_cast<const float2*>(x + (size_t)s3 * D + lane * 2);
        acc0.x += sc0 * a.x;  acc0.y += sc0 * a.y;
        acc1.x += sc1 * b.x;  acc1.y += sc1 * b.y;
        acc0.x += sc2 * c.x;  acc0.y += sc2 * c.y;
        acc1.x += sc3 * d.x;  acc1.y += sc3 * d.y;
    }
    for (; e < end; ++e) {
        int s0 = csr_src[e];
        float sc0 = scale[s0];
        float2 a = *reinterpret_cast<const float2*>(x + (size_t)s0 * D + lane * 2);
        acc0.x += sc0 * a.x;  acc0.y += sc0 * a.y;
    }
    acc0.x += acc1.x;  acc0.y += acc1.y;
    *reinterpret_cast<float2*>(msg + (size_t)n * D + lane * 2) = acc0;
    if (lane == 0) degf[n] = (float)(end - beg);
}

// ===========================================================================
// Fallback edge scatter (fp32 hardware atomics) — last resort
// ===========================================================================
__global__ __launch_bounds__(256) void edge_scatter_kernel(
    const float* __restrict__ x,
    const int* __restrict__ src,
    const int* __restrict__ dst,
    float* __restrict__ msg,
    float* __restrict__ deg,
    int nEdges)
{
    long long t = (long long)blockIdx.x * blockDim.x + threadIdx.x;
    int edge = (int)(t >> 5);
    int lane = (int)(t & 31);
    if (edge >= nEdges) return;

    int s = src[edge];
    int d = dst[edge];

    const float4 xv = *reinterpret_cast<const float4*>(x + (size_t)s * D + lane * 4);
    float ss = xv.x * xv.x + xv.y * xv.y + xv.z * xv.z + xv.w * xv.w;
    ss += __shfl_xor(ss, 1);
    ss += __shfl_xor(ss, 2);
    ss += __shfl_xor(ss, 4);
    ss += __shfl_xor(ss, 8);
    ss += __shfl_xor(ss, 16);

    float norm = sqrtf(ss);
    float ncl  = fminf(norm, 1.0f - 1e-7f);
    float at   = 0.5f * logf((1.0f + ncl) / (1.0f - ncl));
    float scale = at / fmaxf(norm, 1e-15f);

    float* mrow = msg + (size_t)d * D + lane * 4;
    unsafeAtomicAdd(mrow + 0, xv.x * scale);
    unsafeAtomicAdd(mrow + 1, xv.y * scale);
    unsafeAtomicAdd(mrow + 2, xv.z * scale);
    unsafeAtomicAdd(mrow + 3, xv.w * scale);
    if (lane == 0) unsafeAtomicAdd(deg + d, 1.0f);
}

// ===========================================================================
// MFMA bf16 GEMM + expmap, bf16 A: out = expmap0( (msgb@W^T)/max(deg,1)+b )
// ===========================================================================
__global__ __launch_bounds__(256) void gemm_mfma_b_kernel(
    const short* __restrict__ msgb, const float* __restrict__ deg,
    const float* __restrict__ W, const float* __restrict__ bias,
    float* __restrict__ out, int nNodes)
{
    __shared__ short sW[128][136];

    const int t = threadIdx.x;

#pragma unroll
    for (int p = 0; p < 16; ++p) {
        int chunk = p * 256 + t;
        int row = chunk >> 5;
        int c4  = (chunk & 31) * 4;
        float4 v = *reinterpret_cast<const float4*>(W + row * 128 + c4);
        short4 s;
        s.x = f2bf(v.x); s.y = f2bf(v.y); s.z = f2bf(v.z); s.w = f2bf(v.w);
        *reinterpret_cast<short4*>(&sW[row][c4]) = s;
    }
    __syncthreads();

    const int wave = t >> 6;
    const int lane = t & 63;
    const int l15  = lane & 15;
    const int lhi  = lane >> 4;
    const int m0   = blockIdx.x * 64 + wave * 16;

    int arow = m0 + l15;
    if (arow >= nNodes) arow = nNodes - 1;
    const short* ap = msgb + (size_t)arow * D + lhi * 8;
    bf16x8 a[4];
#pragma unroll
    for (int kc = 0; kc < 4; ++kc)
        a[kc] = *reinterpret_cast<const bf16x8*>(ap + kc * 32);

    f32x4 acc[8];
#pragma unroll
    for (int ct = 0; ct < 8; ++ct) acc[ct] = (f32x4){0.f, 0.f, 0.f, 0.f};

#pragma unroll
    for (int ct = 0; ct < 8; ++ct) {
#pragma unroll
        for (int kc = 0; kc < 4; ++kc) {
            bf16x8 bfrag = *reinterpret_cast<const bf16x8*>(
                &sW[ct * 16 + l15][kc * 32 + lhi * 8]);
            acc[ct] = __builtin_amdgcn_mfma_f32_16x16x32_bf16(a[kc], bfrag, acc[ct], 0, 0, 0);
        }
    }

    float bv[8];
#pragma unroll
    for (int ct = 0; ct < 8; ++ct) bv[ct] = bias[ct * 16 + l15];

#pragma unroll
    for (int r = 0; r < 4; ++r) {
        int row = m0 + lhi * 4 + r;
        int rc  = row < nNodes ? row : nNodes - 1;
        float dg  = deg[rc];
        float inv = 1.0f / fmaxf(dg, 1.0f);
        float v[8];
        float ss = 0.0f;
#pragma unroll
        for (int ct = 0; ct < 8; ++ct) {
            v[ct] = acc[ct][r] * inv + bv[ct];
            ss += v[ct] * v[ct];
        }
        ss += __shfl_xor(ss, 1);
        ss += __shfl_xor(ss, 2);
        ss += __shfl_xor(ss, 4);
        ss += __shfl_xor(ss, 8);
        float norm = sqrtf(ss);
        float sc = (dg > 0.0f) ? (tanhf(norm) / fmaxf(norm, 1e-15f)) : 0.0f;
        if (row < nNodes) {
#pragma unroll
            for (int ct = 0; ct < 8; ++ct)
                out[(size_t)row * D + ct * 16 + l15] = v[ct] * sc;
        }
    }
}

// fp32-A variant (msg may alias out; in-place safe — reads precede stores)
__global__ __launch_bounds__(256) void gemm_mfma_kernel(
    const float* msg, const float* __restrict__ deg,
    const float* __restrict__ W, const float* __restrict__ bias,
    float* out, int nNodes)
{
    __shared__ short sW[128][136];

    const int t = threadIdx.x;

#pragma unroll
    for (int p = 0; p < 16; ++p) {
        int chunk = p * 256 + t;
        int row = chunk >> 5;
        int c4  = (chunk & 31) * 4;
        float4 v = *reinterpret_cast<const float4*>(W + row * 128 + c4);
        short4 s;
        s.x = f2bf(v.x); s.y = f2bf(v.y); s.z = f2bf(v.z); s.w = f2bf(v.w);
        *reinterpret_cast<short4*>(&sW[row][c4]) = s;
    }
    __syncthreads();

    const int wave = t >> 6;
    const int lane = t & 63;
    const int l15  = lane & 15;
    const int lhi  = lane >> 4;
    const int m0   = blockIdx.x * 64 + wave * 16;

    int arow = m0 + l15;
    if (arow >= nNodes) arow = nNodes - 1;
    const float* ap = msg + (size_t)arow * D + lhi * 8;
    bf16x8 a[4];
#pragma unroll
    for (int kc = 0; kc < 4; ++kc) {
        float4 v0 = *reinterpret_cast<const float4*>(ap + kc * 32);
        float4 v1 = *reinterpret_cast<const float4*>(ap + kc * 32 + 4);
        bf16x8 f;
        f[0] = f2bf(v0.x); f[1] = f2bf(v0.y); f[2] = f2bf(v0.z); f[3] = f2bf(v0.w);
        f[4] = f2bf(v1.x); f[5] = f2bf(v1.y); f[6] = f2bf(v1.z); f[7] = f2bf(v1.w);
        a[kc] = f;
    }

    f32x4 acc[8];
#pragma unroll
    for (int ct = 0; ct < 8; ++ct) acc[ct] = (f32x4){0.f, 0.f, 0.f, 0.f};

#pragma unroll
    for (int ct = 0; ct < 8; ++ct) {
#pragma unroll
        for (int kc = 0; kc < 4; ++kc) {
            bf16x8 bfrag = *reinterpret_cast<const bf16x8*>(
                &sW[ct * 16 + l15][kc * 32 + lhi * 8]);
            acc[ct] = __builtin_amdgcn_mfma_f32_16x16x32_bf16(a[kc], bfrag, acc[ct], 0, 0, 0);
        }
    }

    float bv[8];
#pragma unroll
    for (int ct = 0; ct < 8; ++ct) bv[ct] = bias[ct * 16 + l15];

#pragma unroll
    for (int r = 0; r < 4; ++r) {
        int row = m0 + lhi * 4 + r;
        int rc  = row < nNodes ? row : nNodes - 1;
        float dg  = deg[rc];
        float inv = 1.0f / fmaxf(dg, 1.0f);
        float v[8];
        float ss = 0.0f;
#pragma unroll
        for (int ct = 0; ct < 8; ++ct) {
            v[ct] = acc[ct][r] * inv + bv[ct];
            ss += v[ct] * v[ct];
        }
        ss += __shfl_xor(ss, 1);
        ss += __shfl_xor(ss, 2);
        ss += __shfl_xor(ss, 4);
        ss += __shfl_xor(ss, 8);
        float norm = sqrtf(ss);
        float sc = (dg > 0.0f) ? (tanhf(norm) / fmaxf(norm, 1e-15f)) : 0.0f;
        if (row < nNodes) {
#pragma unroll
            for (int ct = 0; ct < 8; ++ct)
                out[(size_t)row * D + ct * 16 + l15] = v[ct] * sc;
        }
    }
}

static inline size_t align256(size_t o) { return (o + 255) & ~(size_t)255; }

extern "C" void kernel_launch(void* const* d_in, const int* in_sizes, int n_in,
                              void* d_out, int out_size, void* d_ws, size_t ws_size,
                              hipStream_t stream) {
    const float* x   = (const float*)d_in[0];
    const float* W   = (const float*)d_in[1];
    const float* b   = (const float*)d_in[2];
    const int*   src = (const int*)d_in[3];
    const int*   dst = (const int*)d_in[4];
    float* out = (float*)d_out;

    int nNodes = in_sizes[0] / D;
    int nEdges = in_sizes[3];
    int NB = (nNodes + BNODES - 1) >> BSH;

    // workspace layout (tiered)
    char* ws = (char*)d_ws;
    size_t off = 0;
    float* degf    = (float*)(ws + off); off = align256(off + sizeof(float) * nNodes);
    int*   count   = (int*)  (ws + off); off = align256(off + sizeof(int) * nNodes);
    int*   rowptr  = (int*)  (ws + off); off = align256(off + sizeof(int) * (nNodes + 1));
    float* scl     = (float*)(ws + off); off = align256(off + sizeof(float) * nNodes);
    int*   blksums = (int*)  (ws + off); off = align256(off + sizeof(int) * 256);
    int*   btot    = (int*)  (ws + off); off = align256(off + sizeof(int) * 256);
    int*   blkhist = (int*)  (ws + off); off = align256(off + sizeof(int) * NBLK * 256);
    int*   csr_src = (int*)  (ws + off); off = align256(off + sizeof(int) * nEdges);
    size_t need_mid = off;

    // region1: part (P2/P3) then msgb (gather onward) — part dead before
    // msgb is written. th lives separately (written first, read last).
    size_t part_sz = sizeof(unsigned) * (size_t)nEdges;
    size_t msgb_sz = sizeof(short) * (size_t)nNodes * D;
    size_t th_sz   = sizeof(__half) * (size_t)nNodes * D;

    unsigned* part = (unsigned*)(ws + off);
    short*    msgb = (short*)   (ws + off);
    size_t off_lo = align256(off + part_sz);                               // region1 = part only
    size_t off_hi = align256(off + (part_sz > msgb_sz ? part_sz : msgb_sz)); // region1 = max
    __half* th_lo = (__half*)(ws + off_lo);
    __half* th_hi = (__half*)(ws + off_hi);
    size_t need_lo = align256(off_lo + th_sz);
    size_t need_hi = align256(off_hi + th_sz);

    float* msg = out;  // fp32 msg staging (aliases out) for non-msgb tiers

    int numScanBlocks = (nNodes + 1023) / 1024;
    bool part_ok = (ws_size >= need_lo) && (nNodes <= 131072) && (NB <= 256);
    bool bf16msg = (ws_size >= need_hi) && (nNodes <= 131072) && (NB <= 256);
    bool mid_ok  = (ws_size >= need_mid) && (numScanBlocks <= 256);

    if (part_ok || bf16msg) {
        __half* th = bf16msg ? th_hi : th_lo;
        int TB = (nNodes + 3) / 4;
        // hist + tangent concurrently (independent inputs)
        hist_tangent_kernel<<<NBLK + TB, 256, 0, stream>>>(
            dst, blkhist, nEdges, NB, x, th, nNodes);
        part_scan1_kernel<<<NB, 256, 0, stream>>>(blkhist, btot);
        part_scatter_kernel<<<NBLK, 256, 0, stream>>>(src, dst, blkhist, btot, part, nEdges, NB);
        bucket_csr_kernel<<<NB, 256, 0, stream>>>(part, btot, rowptr, degf,
                                                  csr_src, nNodes, NB, nEdges);
        if (bf16msg) {
            gather2_h16b_kernel<<<(nNodes + 7) / 8, 256, 0, stream>>>(th, csr_src, rowptr, msgb, nNodes);
            gemm_mfma_b_kernel<<<(nNodes + 63) / 64, 256, 0, stream>>>(msgb, degf, W, b, out, nNodes);
        } else {
            gather_h16_kernel<<<(nNodes + 3) / 4, 256, 0, stream>>>(th, csr_src, rowptr, msg, nNodes);
            gemm_mfma_kernel<<<(nNodes + 63) / 64, 256, 0, stream>>>(msg, degf, W, b, out, nNodes);
        }
        return;
    }

    if (mid_ok) {
        hipMemsetAsync(count, 0, sizeof(int) * nNodes, stream);
        int winSize = (nNodes + 7) / 8;
        hist_win_kernel<<<4096, 256, 0, stream>>>(dst, count, nEdges, winSize);
        scan_block_kernel<<<numScanBlocks, 256, 0, stream>>>(count, rowptr, blksums, nNodes);
        scan_totals_kernel<<<1, 256, 0, stream>>>(blksums, rowptr, numScanBlocks, nNodes, nEdges);
        add_offsets_kernel<<<(nNodes + 255) / 256, 256, 0, stream>>>(rowptr, blksums, nNodes);
        fill_win_kernel<<<4096, 256, 0, stream>>>(src, dst, rowptr, count, csr_src, nEdges, winSize);
        deg_from_rowptr_kernel<<<(nNodes + 255) / 256, 256, 0, stream>>>(rowptr, degf, nNodes);

        scale_kernel<<<(nNodes + 3) / 4, 256, 0, stream>>>(x, scl, nNodes);
        gather_kernel<<<(nNodes + 3) / 4, 256, 0, stream>>>(x, scl, csr_src, rowptr, msg, degf, nNodes);
        gemm_mfma_kernel<<<(nNodes + 63) / 64, 256, 0, stream>>>(msg, degf, W, b, out, nNodes);
        return;
    }

    {
        float* deg = (float*)d_ws;
        hipMemsetAsync(msg, 0, (size_t)nNodes * D * sizeof(float), stream);
        hipMemsetAsync(deg, 0, (size_t)nNodes * sizeof(float), stream);
        long long threads = (long long)nEdges * 32;
        int blocks = (int)((threads + 255) / 256);
        edge_scatter_kernel<<<blocks, 256, 0, stream>>>(x, src, dst, msg, (float*)d_ws, nEdges);
        gemm_mfma_kernel<<<(nNodes + 63) / 64, 256, 0, stream>>>(msg, (float*)d_ws, W, b, out, nNodes);
    }
}

// Round 12
// 140.598 us; speedup vs baseline: 1.7269x; 1.0014x over previous
//
#include <hip/hip_runtime.h>
#include <hip/hip_fp16.h>
#include <math.h>

constexpr int D = 128;
constexpr int BSH = 9;               // 512 nodes per bucket
constexpr int BNODES = 1 << BSH;
constexpr int NBLK = 256;            // partition pass blocks

typedef __attribute__((ext_vector_type(8))) short bf16x8;
typedef __attribute__((ext_vector_type(4))) float f32x4;

__device__ inline short f2bf(float f) {
    unsigned u = __builtin_bit_cast(unsigned, f);
    u = (u + 0x7FFFu + ((u >> 16) & 1u)) >> 16;   // round-to-nearest-even
    return (short)u;
}

// ===========================================================================
// Combo: blocks [0,NBLK) do the per-block LDS bucket histogram; the rest do
// tangent (th = fp16 logmap0 rows). Independent work, runs concurrently.
// blkhist TRANSPOSED [bucket][blk] for coalesced scans.
// ===========================================================================
__global__ __launch_bounds__(256) void hist_tangent_kernel(
    const int* __restrict__ dst, int* __restrict__ blkhist,
    int nEdges, int NB,
    const float* __restrict__ x, __half* __restrict__ th, int nNodes)
{
    __shared__ int hist[256];
    int t = threadIdx.x;

    if (blockIdx.x < NBLK) {
        hist[t] = 0;
        __syncthreads();
        int per = (nEdges + NBLK - 1) / NBLK;
        int i0 = blockIdx.x * per;
        int i1 = min(nEdges, i0 + per);
        for (int i = i0 + t; i < i1; i += 256)
            atomicAdd(&hist[dst[i] >> BSH], 1);
        __syncthreads();
        if (t < NB) blkhist[t * NBLK + blockIdx.x] = hist[t];
        return;
    }

    // tangent: 4 nodes per block, one wave each
    int nb = blockIdx.x - NBLK;
    int n    = (nb * 256 + t) >> 6;
    int lane = t & 63;
    if (n >= nNodes) return;
    float2 xv = *reinterpret_cast<const float2*>(x + (size_t)n * D + lane * 2);
    float ss = xv.x * xv.x + xv.y * xv.y;
    ss += __shfl_xor(ss, 1);
    ss += __shfl_xor(ss, 2);
    ss += __shfl_xor(ss, 4);
    ss += __shfl_xor(ss, 8);
    ss += __shfl_xor(ss, 16);
    ss += __shfl_xor(ss, 32);
    float norm = sqrtf(ss);
    float ncl  = fminf(norm, 1.0f - 1e-7f);
    float at   = 0.5f * logf((1.0f + ncl) / (1.0f - ncl));
    float sc   = at / fmaxf(norm, 1e-15f);
    __half2 h = __float22half2_rn(make_float2(xv.x * sc, xv.y * sc));
    *(reinterpret_cast<__half2*>(th + (size_t)n * D) + lane) = h;
}

// P1.5: one block per bucket: scan per-block counts -> exclusive, total out
__global__ __launch_bounds__(256) void part_scan1_kernel(
    int* __restrict__ blkhist, int* __restrict__ btot)
{
    __shared__ int s[256];
    int b = blockIdx.x;
    int t = threadIdx.x;
    int v = blkhist[b * NBLK + t];
    s[t] = v;
    __syncthreads();
    for (int off = 1; off < 256; off <<= 1) {
        int xv = (t >= off) ? s[t - off] : 0;
        __syncthreads();
        if (t >= off) s[t] += xv;
        __syncthreads();
    }
    blkhist[b * NBLK + t] = s[t] - v;   // exclusive
    if (t == 255) btot[b] = s[255];
}

// ===========================================================================
// P2: scatter edges into bucket-partitioned array. LDS cursors only; bucket
// bases recomputed per-block from btot (folds old scan2 away).
// part[p] = src | dloc<<17  (requires nNodes <= 131072)
// ===========================================================================
__global__ __launch_bounds__(256) void part_scatter_kernel(
    const int* __restrict__ src, const int* __restrict__ dst,
    const int* __restrict__ blkhist, const int* __restrict__ btot,
    unsigned* __restrict__ part, int nEdges, int NB)
{
    __shared__ int sb[256];
    __shared__ int cur[256];
    int t = threadIdx.x;
    int v = (t < NB) ? btot[t] : 0;
    sb[t] = v;
    __syncthreads();
    for (int off = 1; off < 256; off <<= 1) {
        int xv = (t >= off) ? sb[t - off] : 0;
        __syncthreads();
        if (t >= off) sb[t] += xv;
        __syncthreads();
    }
    int bbase_t = sb[t] - v;   // exclusive prefix of bucket totals
    cur[t] = (t < NB) ? (blkhist[t * NBLK + blockIdx.x] + bbase_t) : 0;
    __syncthreads();

    int per = (nEdges + gridDim.x - 1) / gridDim.x;
    int i0 = blockIdx.x * per;
    int i1 = min(nEdges, i0 + per);
    for (int i = i0 + t; i < i1; i += 256) {
        int d = dst[i];
        int b = d >> BSH;
        int p = atomicAdd(&cur[b], 1);
        part[p] = (unsigned)src[i] | ((unsigned)(d & (BNODES - 1)) << 17);
    }
}

// ===========================================================================
// P3: per-bucket CSR build. Bucket bases recomputed from btot in LDS.
// ===========================================================================
__global__ __launch_bounds__(256) void bucket_csr_kernel(
    const unsigned* __restrict__ part, const int* __restrict__ btot,
    int* __restrict__ rowptr, float* __restrict__ degf,
    int* __restrict__ csr_src, int nNodes, int NB, int nEdges)
{
    __shared__ int cnt[BNODES];
    __shared__ int excl[BNODES];
    __shared__ int cur[BNODES];
    __shared__ int s[256];
    __shared__ int sBB[2];

    int b = blockIdx.x;
    int t = threadIdx.x;

    // bucket base from btot prefix
    int v = (t < NB) ? btot[t] : 0;
    s[t] = v;
    __syncthreads();
    for (int off = 1; off < 256; off <<= 1) {
        int xv = (t >= off) ? s[t - off] : 0;
        __syncthreads();
        if (t >= off) s[t] += xv;
        __syncthreads();
    }
    if (t == b) { sBB[0] = s[t] - v; sBB[1] = s[t]; }
    __syncthreads();
    int bb = sBB[0], be = sBB[1];

    cnt[t] = 0; cnt[t + 256] = 0;
    cur[t] = 0; cur[t + 256] = 0;
    __syncthreads();

    for (int i = bb + t; i < be; i += 256)
        atomicAdd(&cnt[part[i] >> 17], 1);
    __syncthreads();

    int a0 = cnt[2 * t], a1 = cnt[2 * t + 1];
    s[t] = a0 + a1;
    __syncthreads();
    for (int off = 1; off < 256; off <<= 1) {
        int xv = (t >= off) ? s[t - off] : 0;
        __syncthreads();
        if (t >= off) s[t] += xv;
        __syncthreads();
    }
    int pbase = (t > 0) ? s[t - 1] : 0;
    excl[2 * t]     = pbase;
    excl[2 * t + 1] = pbase + a0;
    __syncthreads();

    int node0 = b << BSH;
#pragma unroll
    for (int q = 0; q < 2; ++q) {
        int j = t + q * 256;
        int d = node0 + j;
        if (d < nNodes) {
            rowptr[d] = bb + excl[j];
            degf[d]   = (float)cnt[j];
        }
    }
    if (b == NB - 1 && t == 0) rowptr[nNodes] = nEdges;

    for (int i = bb + t; i < be; i += 256) {
        unsigned vv = part[i];
        int dloc = vv >> 17;
        int p = bb + excl[dloc] + atomicAdd(&cur[dloc], 1);
        csr_src[p] = (int)(vv & 0x1FFFFu);
    }
}

// ===========================================================================
// mid-tier CSR build (global atomics, windowed) — fallback if ws too small
// ===========================================================================
__global__ __launch_bounds__(256) void hist_win_kernel(
    const int* __restrict__ dst, int* __restrict__ count,
    int nEdges, int winSize)
{
    int pass    = blockIdx.x & 7;
    int slice   = blockIdx.x >> 3;
    int nSlices = gridDim.x >> 3;
    int lo = pass * winSize;
    int hi = lo + winSize;

    int stride = nSlices * blockDim.x;
    for (int i = slice * blockDim.x + threadIdx.x; i < nEdges; i += stride) {
        int d = dst[i];
        if (d >= lo && d < hi) atomicAdd(&count[d], 1);
    }
}

__global__ __launch_bounds__(256) void scan_block_kernel(
    const int* __restrict__ count, int* __restrict__ rowptr,
    int* __restrict__ blksums, int n)
{
    __shared__ int sums[256];
    int t = threadIdx.x;
    int base = blockIdx.x * 1024 + t * 4;
    int v[4];
    int s = 0;
#pragma unroll
    for (int j = 0; j < 4; ++j) { v[j] = (base + j < n) ? count[base + j] : 0; s += v[j]; }
    sums[t] = s;
    __syncthreads();
    for (int off = 1; off < 256; off <<= 1) {
        int xv = (t >= off) ? sums[t - off] : 0;
        __syncthreads();
        if (t >= off) sums[t] += xv;
        __syncthreads();
    }
    int run = (t > 0) ? sums[t - 1] : 0;
#pragma unroll
    for (int j = 0; j < 4; ++j) { if (base + j < n) rowptr[base + j] = run; run += v[j]; }
    if (t == 255) blksums[blockIdx.x] = sums[255];
}

__global__ __launch_bounds__(256) void scan_totals_kernel(
    int* __restrict__ blksums, int* __restrict__ rowptr,
    int numBlocks, int n, int E)
{
    __shared__ int s[256];
    int t = threadIdx.x;
    s[t] = (t < numBlocks) ? blksums[t] : 0;
    __syncthreads();
    for (int off = 1; off < 256; off <<= 1) {
        int xv = (t >= off) ? s[t - off] : 0;
        __syncthreads();
        if (t >= off) s[t] += xv;
        __syncthreads();
    }
    if (t < numBlocks) blksums[t] = (t > 0) ? s[t - 1] : 0;
    if (t == 0) rowptr[n] = E;
}

__global__ __launch_bounds__(256) void add_offsets_kernel(
    int* __restrict__ rowptr, const int* __restrict__ blksums, int n)
{
    int i = blockIdx.x * 256 + threadIdx.x;
    if (i < n) rowptr[i] += blksums[i >> 10];
}

__global__ __launch_bounds__(256) void fill_win_kernel(
    const int* __restrict__ src, const int* __restrict__ dst,
    const int* __restrict__ rowptr, int* __restrict__ count,
    int* __restrict__ csr_src, int nEdges, int winSize)
{
    int pass    = blockIdx.x & 7;
    int slice   = blockIdx.x >> 3;
    int nSlices = gridDim.x >> 3;
    int lo = pass * winSize;
    int hi = lo + winSize;

    int stride = nSlices * blockDim.x;
    for (int i = slice * blockDim.x + threadIdx.x; i < nEdges; i += stride) {
        int d = dst[i];
        if (d >= lo && d < hi) {
            int pos = rowptr[d] + atomicSub(&count[d], 1) - 1;
            csr_src[pos] = src[i];
        }
    }
}

__global__ __launch_bounds__(256) void deg_from_rowptr_kernel(
    const int* __restrict__ rowptr, float* __restrict__ degf, int n)
{
    int i = blockIdx.x * 256 + threadIdx.x;
    if (i < n) degf[i] = (float)(rowptr[i + 1] - rowptr[i]);
}

__global__ __launch_bounds__(256) void scale_kernel(
    const float* __restrict__ x, float* __restrict__ scale, int nNodes)
{
    int node = (blockIdx.x * 256 + threadIdx.x) >> 6;
    int lane = threadIdx.x & 63;
    if (node >= nNodes) return;
    float2 xv = *reinterpret_cast<const float2*>(x + (size_t)node * D + lane * 2);
    float ss = xv.x * xv.x + xv.y * xv.y;
    ss += __shfl_xor(ss, 1);
    ss += __shfl_xor(ss, 2);
    ss += __shfl_xor(ss, 4);
    ss += __shfl_xor(ss, 8);
    ss += __shfl_xor(ss, 16);
    ss += __shfl_xor(ss, 32);
    if (lane == 0) {
        float norm = sqrtf(ss);
        float ncl  = fminf(norm, 1.0f - 1e-7f);
        float at   = 0.5f * logf((1.0f + ncl) / (1.0f - ncl));
        scale[node] = at / fmaxf(norm, 1e-15f);
    }
}

// ===========================================================================
// gather, bf16 out, 2 nodes per wave (8/block): groups {0,1}->node0,
// {2,3}->node1; per node 2 groups at slot stride 2, 4-deep unroll =
// 16 rows in flight/wave across 2 independent nodes (overlaps per-node
// reduce/write serialization).
// ===========================================================================
__global__ __launch_bounds__(256) void gather2_h16b_kernel(
    const __half* __restrict__ th,
    const int* __restrict__ csr_src, const int* __restrict__ rowptr,
    short* __restrict__ msgb, int nNodes)
{
    int t    = threadIdx.x;
    int lane = t & 63;
    int wave = t >> 6;
    int grp  = lane >> 4;
    int np   = grp >> 1;      // node select 0/1
    int g2   = grp & 1;       // slot parity
    int sl   = lane & 15;     // owns elements [8*sl, 8*sl+8)

    int n  = blockIdx.x * 8 + wave * 2 + np;
    int nn = n < nNodes ? n : nNodes - 1;
    int beg = rowptr[nn];
    int cnt = rowptr[nn + 1] - beg;

    __half2 z = __float2half2_rn(0.0f);
    __half2 acc0[4] = {z, z, z, z};
    __half2 acc1[4] = {z, z, z, z};

    int k = g2;
    for (; k + 6 < cnt; k += 8) {
        int s0 = csr_src[beg + k];
        int s1 = csr_src[beg + k + 2];
        int s2 = csr_src[beg + k + 4];
        int s3 = csr_src[beg + k + 6];
        float4 r0 = *reinterpret_cast<const float4*>(th + (size_t)s0 * D + sl * 8);
        float4 r1 = *reinterpret_cast<const float4*>(th + (size_t)s1 * D + sl * 8);
        float4 r2 = *reinterpret_cast<const float4*>(th + (size_t)s2 * D + sl * 8);
        float4 r3 = *reinterpret_cast<const float4*>(th + (size_t)s3 * D + sl * 8);
        const __half2* h0 = reinterpret_cast<const __half2*>(&r0);
        const __half2* h1 = reinterpret_cast<const __half2*>(&r1);
        const __half2* h2 = reinterpret_cast<const __half2*>(&r2);
        const __half2* h3 = reinterpret_cast<const __half2*>(&r3);
#pragma unroll
        for (int j = 0; j < 4; ++j) {
            acc0[j] = __hadd2(acc0[j], h0[j]);
            acc1[j] = __hadd2(acc1[j], h1[j]);
            acc0[j] = __hadd2(acc0[j], h2[j]);
            acc1[j] = __hadd2(acc1[j], h3[j]);
        }
    }
    for (; k < cnt; k += 2) {
        int s0 = csr_src[beg + k];
        float4 r0 = *reinterpret_cast<const float4*>(th + (size_t)s0 * D + sl * 8);
        const __half2* h0 = reinterpret_cast<const __half2*>(&r0);
#pragma unroll
        for (int j = 0; j < 4; ++j) acc0[j] = __hadd2(acc0[j], h0[j]);
    }
#pragma unroll
    for (int j = 0; j < 4; ++j) {
        acc0[j] = __hadd2(acc0[j], acc1[j]);
        // combine the two slot-parity groups of this node (lanes ^16)
        float fx = __shfl_xor(__builtin_bit_cast(float, acc0[j]), 16);
        acc0[j] = __hadd2(acc0[j], __builtin_bit_cast(__half2, fx));
    }
    if (g2 == 0 && n < nNodes) {
        short s8[8];
#pragma unroll
        for (int j = 0; j < 4; ++j) {
            float2 f = __half22float2(acc0[j]);
            s8[2 * j]     = f2bf(f.x);
            s8[2 * j + 1] = f2bf(f.y);
        }
        *reinterpret_cast<float4*>(msgb + (size_t)n * D + sl * 8) =
            *reinterpret_cast<float4*>(s8);
    }
}

// gather, fp32 out (msg aliases d_out) — used when ws can't hold msgb
__global__ __launch_bounds__(256) void gather_h16_kernel(
    const __half* __restrict__ th,
    const int* __restrict__ csr_src, const int* __restrict__ rowptr,
    float* __restrict__ msg, int nNodes)
{
    int n    = blockIdx.x * 4 + (threadIdx.x >> 6);
    int lane = threadIdx.x & 63;
    if (n >= nNodes) return;
    int grp = lane >> 4;
    int sl  = lane & 15;

    int beg = rowptr[n];
    int cnt = rowptr[n + 1] - beg;

    __half2 z = __float2half2_rn(0.0f);
    __half2 acc0[4] = {z, z, z, z};
    __half2 acc1[4] = {z, z, z, z};

    int k = grp;
    for (; k + 12 < cnt; k += 16) {
        int s0 = csr_src[beg + k];
        int s1 = csr_src[beg + k + 4];
        int s2 = csr_src[beg + k + 8];
        int s3 = csr_src[beg + k + 12];
        float4 r0 = *reinterpret_cast<const float4*>(th + (size_t)s0 * D + sl * 8);
        float4 r1 = *reinterpret_cast<const float4*>(th + (size_t)s1 * D + sl * 8);
        float4 r2 = *reinterpret_cast<const float4*>(th + (size_t)s2 * D + sl * 8);
        float4 r3 = *reinterpret_cast<const float4*>(th + (size_t)s3 * D + sl * 8);
        const __half2* h0 = reinterpret_cast<const __half2*>(&r0);
        const __half2* h1 = reinterpret_cast<const __half2*>(&r1);
        const __half2* h2 = reinterpret_cast<const __half2*>(&r2);
        const __half2* h3 = reinterpret_cast<const __half2*>(&r3);
#pragma unroll
        for (int j = 0; j < 4; ++j) {
            acc0[j] = __hadd2(acc0[j], h0[j]);
            acc1[j] = __hadd2(acc1[j], h1[j]);
            acc0[j] = __hadd2(acc0[j], h2[j]);
            acc1[j] = __hadd2(acc1[j], h3[j]);
        }
    }
    for (; k < cnt; k += 4) {
        int s0 = csr_src[beg + k];
        float4 r0 = *reinterpret_cast<const float4*>(th + (size_t)s0 * D + sl * 8);
        const __half2* h0 = reinterpret_cast<const __half2*>(&r0);
#pragma unroll
        for (int j = 0; j < 4; ++j) acc0[j] = __hadd2(acc0[j], h0[j]);
    }
#pragma unroll
    for (int j = 0; j < 4; ++j) {
        acc0[j] = __hadd2(acc0[j], acc1[j]);
        float f16 = __shfl_xor(__builtin_bit_cast(float, acc0[j]), 16);
        acc0[j] = __hadd2(acc0[j], __builtin_bit_cast(__half2, f16));
        float f32v = __shfl_xor(__builtin_bit_cast(float, acc0[j]), 32);
        acc0[j] = __hadd2(acc0[j], __builtin_bit_cast(__half2, f32v));
    }
    if (grp == 0) {
        float2 f0 = __half22float2(acc0[0]);
        float2 f1 = __half22float2(acc0[1]);
        float2 f2 = __half22float2(acc0[2]);
        float2 f3 = __half22float2(acc0[3]);
        float4 o0 = make_float4(f0.x, f0.y, f1.x, f1.y);
        float4 o1 = make_float4(f2.x, f2.y, f3.x, f3.y);
        *reinterpret_cast<float4*>(msg + (size_t)n * D + sl * 8)     = o0;
        *reinterpret_cast<float4*>(msg + (size_t)n * D + sl * 8 + 4) = o1;
    }
}

// gather (fp32 rows) — mid tier
__global__ __launch_bounds__(256) void gather_kernel(
    const float* __restrict__ x, const float* __restrict__ scale,
    const int* __restrict__ csr_src, const int* __restrict__ rowptr,
    float* __restrict__ msg, float* __restrict__ degf, int nNodes)
{
    int n    = blockIdx.x * 4 + (threadIdx.x >> 6);
    int lane = threadIdx.x & 63;
    if (n >= nNodes) return;

    int beg = rowptr[n], end = rowptr[n + 1];
    float2 acc0 = make_float2(0.0f, 0.0f);
    float2 acc1 = make_float2(0.0f, 0.0f);
    int e = beg;
    for (; e + 3 < end; e += 4) {
        int s0 = csr_src[e],     s1 = csr_src[e + 1];
        int s2 = csr_src[e + 2], s3 = csr_src[e + 3];
        float sc0 = scale[s0], sc1 = scale[s1];
        float sc2 = scale[s2], sc3 = scale[s3];
        float2 a = *reinterpret_cast<const float2*>(x + (size_t)s0 * D + lane * 2);
        float2 b = *reinterpret_cast<const float2*>(x + (size_t)s1 * D + lane * 2);
        float2 c = *reinterpret_cast<const float2*>(x + (size_t)s2 * D + lane * 2);
        float2 d = *reinterpret_cast<const float2*>(x + (size_t)s3 * D + lane * 2);
        acc0.x += sc0 * a.x;  acc0.y += sc0 * a.y;
        acc1.x += sc1 * b.x;  acc1.y += sc1 * b.y;
        acc0.x += sc2 * c.x;  acc0.y += sc2 * c.y;
        acc1.x += sc3 * d.x;  acc1.y += sc3 * d.y;
    }
    for (; e < end; ++e) {
        int s0 = csr_src[e];
        float sc0 = scale[s0];
        float2 a = *reinterpret_cast<const float2*>(x + (size_t)s0 * D + lane * 2);
        acc0.x += sc0 * a.x;  acc0.y += sc0 * a.y;
    }
    acc0.x += acc1.x;  acc0.y += acc1.y;
    *reinterpret_cast<float2*>(msg + (size_t)n * D + lane * 2) = acc0;
    if (lane == 0) degf[n] = (float)(end - beg);
}

// ===========================================================================
// Fallback edge scatter (fp32 hardware atomics) — last resort
// ===========================================================================
__global__ __launch_bounds__(256) void edge_scatter_kernel(
    const float* __restrict__ x,
    const int* __restrict__ src,
    const int* __restrict__ dst,
    float* __restrict__ msg,
    float* __restrict__ deg,
    int nEdges)
{
    long long t = (long long)blockIdx.x * blockDim.x + threadIdx.x;
    int edge = (int)(t >> 5);
    int lane = (int)(t & 31);
    if (edge >= nEdges) return;

    int s = src[edge];
    int d = dst[edge];

    const float4 xv = *reinterpret_cast<const float4*>(x + (size_t)s * D + lane * 4);
    float ss = xv.x * xv.x + xv.y * xv.y + xv.z * xv.z + xv.w * xv.w;
    ss += __shfl_xor(ss, 1);
    ss += __shfl_xor(ss, 2);
    ss += __shfl_xor(ss, 4);
    ss += __shfl_xor(ss, 8);
    ss += __shfl_xor(ss, 16);

    float norm = sqrtf(ss);
    float ncl  = fminf(norm, 1.0f - 1e-7f);
    float at   = 0.5f * logf((1.0f + ncl) / (1.0f - ncl));
    float scale = at / fmaxf(norm, 1e-15f);

    float* mrow = msg + (size_t)d * D + lane * 4;
    unsafeAtomicAdd(mrow + 0, xv.x * scale);
    unsafeAtomicAdd(mrow + 1, xv.y * scale);
    unsafeAtomicAdd(mrow + 2, xv.z * scale);
    unsafeAtomicAdd(mrow + 3, xv.w * scale);
    if (lane == 0) unsafeAtomicAdd(deg + d, 1.0f);
}

// ===========================================================================
// MFMA bf16 GEMM + expmap, bf16 A: out = expmap0( (msgb@W^T)/max(deg,1)+b )
// ===========================================================================
__global__ __launch_bounds__(256) void gemm_mfma_b_kernel(
    const short* __restrict__ msgb, const float* __restrict__ deg,
    const float* __restrict__ W, const float* __restrict__ bias,
    float* __restrict__ out, int nNodes)
{
    __shared__ short sW[128][136];

    const int t = threadIdx.x;

#pragma unroll
    for (int p = 0; p < 16; ++p) {
        int chunk = p * 256 + t;
        int row = chunk >> 5;
        int c4  = (chunk & 31) * 4;
        float4 v = *reinterpret_cast<const float4*>(W + row * 128 + c4);
        short4 s;
        s.x = f2bf(v.x); s.y = f2bf(v.y); s.z = f2bf(v.z); s.w = f2bf(v.w);
        *reinterpret_cast<short4*>(&sW[row][c4]) = s;
    }
    __syncthreads();

    const int wave = t >> 6;
    const int lane = t & 63;
    const int l15  = lane & 15;
    const int lhi  = lane >> 4;
    const int m0   = blockIdx.x * 64 + wave * 16;

    int arow = m0 + l15;
    if (arow >= nNodes) arow = nNodes - 1;
    const short* ap = msgb + (size_t)arow * D + lhi * 8;
    bf16x8 a[4];
#pragma unroll
    for (int kc = 0; kc < 4; ++kc)
        a[kc] = *reinterpret_cast<const bf16x8*>(ap + kc * 32);

    f32x4 acc[8];
#pragma unroll
    for (int ct = 0; ct < 8; ++ct) acc[ct] = (f32x4){0.f, 0.f, 0.f, 0.f};

#pragma unroll
    for (int ct = 0; ct < 8; ++ct) {
#pragma unroll
        for (int kc = 0; kc < 4; ++kc) {
            bf16x8 bfrag = *reinterpret_cast<const bf16x8*>(
                &sW[ct * 16 + l15][kc * 32 + lhi * 8]);
            acc[ct] = __builtin_amdgcn_mfma_f32_16x16x32_bf16(a[kc], bfrag, acc[ct], 0, 0, 0);
        }
    }

    float bv[8];
#pragma unroll
    for (int ct = 0; ct < 8; ++ct) bv[ct] = bias[ct * 16 + l15];

#pragma unroll
    for (int r = 0; r < 4; ++r) {
        int row = m0 + lhi * 4 + r;
        int rc  = row < nNodes ? row : nNodes - 1;
        float dg  = deg[rc];
        float inv = 1.0f / fmaxf(dg, 1.0f);
        float v[8];
        float ss = 0.0f;
#pragma unroll
        for (int ct = 0; ct < 8; ++ct) {
            v[ct] = acc[ct][r] * inv + bv[ct];
            ss += v[ct] * v[ct];
        }
        ss += __shfl_xor(ss, 1);
        ss += __shfl_xor(ss, 2);
        ss += __shfl_xor(ss, 4);
        ss += __shfl_xor(ss, 8);
        float norm = sqrtf(ss);
        float sc = (dg > 0.0f) ? (tanhf(norm) / fmaxf(norm, 1e-15f)) : 0.0f;
        if (row < nNodes) {
#pragma unroll
            for (int ct = 0; ct < 8; ++ct)
                out[(size_t)row * D + ct * 16 + l15] = v[ct] * sc;
        }
    }
}

// fp32-A variant (msg may alias out; in-place safe — reads precede stores)
__global__ __launch_bounds__(256) void gemm_mfma_kernel(
    const float* msg, const float* __restrict__ deg,
    const float* __restrict__ W, const float* __restrict__ bias,
    float* out, int nNodes)
{
    __shared__ short sW[128][136];

    const int t = threadIdx.x;

#pragma unroll
    for (int p = 0; p < 16; ++p) {
        int chunk = p * 256 + t;
        int row = chunk >> 5;
        int c4  = (chunk & 31) * 4;
        float4 v = *reinterpret_cast<const float4*>(W + row * 128 + c4);
        short4 s;
        s.x = f2bf(v.x); s.y = f2bf(v.y); s.z = f2bf(v.z); s.w = f2bf(v.w);
        *reinterpret_cast<short4*>(&sW[row][c4]) = s;
    }
    __syncthreads();

    const int wave = t >> 6;
    const int lane = t & 63;
    const int l15  = lane & 15;
    const int lhi  = lane >> 4;
    const int m0   = blockIdx.x * 64 + wave * 16;

    int arow = m0 + l15;
    if (arow >= nNodes) arow = nNodes - 1;
    const float* ap = msg + (size_t)arow * D + lhi * 8;
    bf16x8 a[4];
#pragma unroll
    for (int kc = 0; kc < 4; ++kc) {
        float4 v0 = *reinterpret_cast<const float4*>(ap + kc * 32);
        float4 v1 = *reinterpret_cast<const float4*>(ap + kc * 32 + 4);
        bf16x8 f;
        f[0] = f2bf(v0.x); f[1] = f2bf(v0.y); f[2] = f2bf(v0.z); f[3] = f2bf(v0.w);
        f[4] = f2bf(v1.x); f[5] = f2bf(v1.y); f[6] = f2bf(v1.z); f[7] = f2bf(v1.w);
        a[kc] = f;
    }

    f32x4 acc[8];
#pragma unroll
    for (int ct = 0; ct < 8; ++ct) acc[ct] = (f32x4){0.f, 0.f, 0.f, 0.f};

#pragma unroll
    for (int ct = 0; ct < 8; ++ct) {
#pragma unroll
        for (int kc = 0; kc < 4; ++kc) {
            bf16x8 bfrag = *reinterpret_cast<const bf16x8*>(
                &sW[ct * 16 + l15][kc * 32 + lhi * 8]);
            acc[ct] = __builtin_amdgcn_mfma_f32_16x16x32_bf16(a[kc], bfrag, acc[ct], 0, 0, 0);
        }
    }

    float bv[8];
#pragma unroll
    for (int ct = 0; ct < 8; ++ct) bv[ct] = bias[ct * 16 + l15];

#pragma unroll
    for (int r = 0; r < 4; ++r) {
        int row = m0 + lhi * 4 + r;
        int rc  = row < nNodes ? row : nNodes - 1;
        float dg  = deg[rc];
        float inv = 1.0f / fmaxf(dg, 1.0f);
        float v[8];
        float ss = 0.0f;
#pragma unroll
        for (int ct = 0; ct < 8; ++ct) {
            v[ct] = acc[ct][r] * inv + bv[ct];
            ss += v[ct] * v[ct];
        }
        ss += __shfl_xor(ss, 1);
        ss += __shfl_xor(ss, 2);
        ss += __shfl_xor(ss, 4);
        ss += __shfl_xor(ss, 8);
        float norm = sqrtf(ss);
        float sc = (dg > 0.0f) ? (tanhf(norm) / fmaxf(norm, 1e-15f)) : 0.0f;
        if (row < nNodes) {
#pragma unroll
            for (int ct = 0; ct < 8; ++ct)
                out[(size_t)row * D + ct * 16 + l15] = v[ct] * sc;
        }
    }
}

static inline size_t align256(size_t o) { return (o + 255) & ~(size_t)255; }

extern "C" void kernel_launch(void* const* d_in, const int* in_sizes, int n_in,
                              void* d_out, int out_size, void* d_ws, size_t ws_size,
                              hipStream_t stream) {
    const float* x   = (const float*)d_in[0];
    const float* W   = (const float*)d_in[1];
    const float* b   = (const float*)d_in[2];
    const int*   src = (const int*)d_in[3];
    const int*   dst = (const int*)d_in[4];
    float* out = (float*)d_out;

    int nNodes = in_sizes[0] / D;
    int nEdges = in_sizes[3];
    int NB = (nNodes + BNODES - 1) >> BSH;

    // workspace layout (tiered)
    char* ws = (char*)d_ws;
    size_t off = 0;
    float* degf    = (float*)(ws + off); off = align256(off + sizeof(float) * nNodes);
    int*   count   = (int*)  (ws + off); off = align256(off + sizeof(int) * nNodes);
    int*   rowptr  = (int*)  (ws + off); off = align256(off + sizeof(int) * (nNodes + 1));
    float* scl     = (float*)(ws + off); off = align256(off + sizeof(float) * nNodes);
    int*   blksums = (int*)  (ws + off); off = align256(off + sizeof(int) * 256);
    int*   btot    = (int*)  (ws + off); off = align256(off + sizeof(int) * 256);
    int*   blkhist = (int*)  (ws + off); off = align256(off + sizeof(int) * NBLK * 256);
    int*   csr_src = (int*)  (ws + off); off = align256(off + sizeof(int) * nEdges);
    size_t need_mid = off;

    // region1: part (P2/P3) then msgb (gather onward) — part dead before
    // msgb is written. th lives separately (written first, read last).
    size_t part_sz = sizeof(unsigned) * (size_t)nEdges;
    size_t msgb_sz = sizeof(short) * (size_t)nNodes * D;
    size_t th_sz   = sizeof(__half) * (size_t)nNodes * D;

    unsigned* part = (unsigned*)(ws + off);
    short*    msgb = (short*)   (ws + off);
    size_t off_lo = align256(off + part_sz);                               // region1 = part only
    size_t off_hi = align256(off + (part_sz > msgb_sz ? part_sz : msgb_sz)); // region1 = max
    __half* th_lo = (__half*)(ws + off_lo);
    __half* th_hi = (__half*)(ws + off_hi);
    size_t need_lo = align256(off_lo + th_sz);
    size_t need_hi = align256(off_hi + th_sz);

    float* msg = out;  // fp32 msg staging (aliases out) for non-msgb tiers

    int numScanBlocks = (nNodes + 1023) / 1024;
    bool part_ok = (ws_size >= need_lo) && (nNodes <= 131072) && (NB <= 256);
    bool bf16msg = (ws_size >= need_hi) && (nNodes <= 131072) && (NB <= 256);
    bool mid_ok  = (ws_size >= need_mid) && (numScanBlocks <= 256);

    if (part_ok || bf16msg) {
        __half* th = bf16msg ? th_hi : th_lo;
        int TB = (nNodes + 3) / 4;
        // hist + tangent concurrently (independent inputs)
        hist_tangent_kernel<<<NBLK + TB, 256, 0, stream>>>(
            dst, blkhist, nEdges, NB, x, th, nNodes);
        part_scan1_kernel<<<NB, 256, 0, stream>>>(blkhist, btot);
        part_scatter_kernel<<<NBLK, 256, 0, stream>>>(src, dst, blkhist, btot, part, nEdges, NB);
        bucket_csr_kernel<<<NB, 256, 0, stream>>>(part, btot, rowptr, degf,
                                                  csr_src, nNodes, NB, nEdges);
        if (bf16msg) {
            gather2_h16b_kernel<<<(nNodes + 7) / 8, 256, 0, stream>>>(th, csr_src, rowptr, msgb, nNodes);
            gemm_mfma_b_kernel<<<(nNodes + 63) / 64, 256, 0, stream>>>(msgb, degf, W, b, out, nNodes);
        } else {
            gather_h16_kernel<<<(nNodes + 3) / 4, 256, 0, stream>>>(th, csr_src, rowptr, msg, nNodes);
            gemm_mfma_kernel<<<(nNodes + 63) / 64, 256, 0, stream>>>(msg, degf, W, b, out, nNodes);
        }
        return;
    }

    if (mid_ok) {
        hipMemsetAsync(count, 0, sizeof(int) * nNodes, stream);
        int winSize = (nNodes + 7) / 8;
        hist_win_kernel<<<4096, 256, 0, stream>>>(dst, count, nEdges, winSize);
        scan_block_kernel<<<numScanBlocks, 256, 0, stream>>>(count, rowptr, blksums, nNodes);
        scan_totals_kernel<<<1, 256, 0, stream>>>(blksums, rowptr, numScanBlocks, nNodes, nEdges);
        add_offsets_kernel<<<(nNodes + 255) / 256, 256, 0, stream>>>(rowptr, blksums, nNodes);
        fill_win_kernel<<<4096, 256, 0, stream>>>(src, dst, rowptr, count, csr_src, nEdges, winSize);
        deg_from_rowptr_kernel<<<(nNodes + 255) / 256, 256, 0, stream>>>(rowptr, degf, nNodes);

        scale_kernel<<<(nNodes + 3) / 4, 256, 0, stream>>>(x, scl, nNodes);
        gather_kernel<<<(nNodes + 3) / 4, 256, 0, stream>>>(x, scl, csr_src, rowptr, msg, degf, nNodes);
        gemm_mfma_kernel<<<(nNodes + 63) / 64, 256, 0, stream>>>(msg, degf, W, b, out, nNodes);
        return;
    }

    {
        float* deg = (float*)d_ws;
        hipMemsetAsync(msg, 0, (size_t)nNodes * D * sizeof(float), stream);
        hipMemsetAsync(deg, 0, (size_t)nNodes * sizeof(float), stream);
        long long threads = (long long)nEdges * 32;
        int blocks = (int)((threads + 255) / 256);
        edge_scatter_kernel<<<blocks, 256, 0, stream>>>(x, src, dst, msg, (float*)d_ws, nEdges);
        gemm_mfma_kernel<<<(nNodes + 63) / 64, 256, 0, stream>>>(msg, (float*)d_ws, W, b, out, nNodes);
    }
}

// Round 13
// 124.805 us; speedup vs baseline: 1.9455x; 1.1265x over previous
//
#include <hip/hip_runtime.h>
#include <hip/hip_fp16.h>
#include <math.h>

constexpr int D = 128;
constexpr int BSH = 9;               // 512 nodes per bucket
constexpr int BNODES = 1 << BSH;
constexpr int NBLK = 256;            // partition pass blocks

typedef __attribute__((ext_vector_type(8))) short bf16x8;
typedef __attribute__((ext_vector_type(4))) float f32x4;
typedef __attribute__((ext_vector_type(2))) float f32x2;

__device__ inline short f2bf(float f) {
    unsigned u = __builtin_bit_cast(unsigned, f);
    u = (u + 0x7FFFu + ((u >> 16) & 1u)) >> 16;   // round-to-nearest-even
    return (short)u;
}

// ===========================================================================
// Combo (fp8 tier): blocks [0,NBLK) build the per-block LDS bucket histogram;
// remaining blocks compute th8 = fp8_e4m3(64 * logmap0(x)) rows (half-wave
// per node, 4 elem/lane, packed u32 stores). Independent work, concurrent.
// ===========================================================================
__global__ __launch_bounds__(256) void hist_tangent8_kernel(
    const int* __restrict__ dst, int* __restrict__ blkhist,
    int nEdges, int NB,
    const float* __restrict__ x, unsigned char* __restrict__ th8, int nNodes)
{
    __shared__ int hist[256];
    int t = threadIdx.x;

    if (blockIdx.x < NBLK) {
        hist[t] = 0;
        __syncthreads();
        int per = (nEdges + NBLK - 1) / NBLK;
        int i0 = blockIdx.x * per;
        int i1 = min(nEdges, i0 + per);
        for (int i = i0 + t; i < i1; i += 256)
            atomicAdd(&hist[dst[i] >> BSH], 1);
        __syncthreads();
        if (t < NB) blkhist[t * NBLK + blockIdx.x] = hist[t];
        return;
    }

    // tangent: 8 nodes per block (half-wave per node, lane owns 4 elements)
    int nb = blockIdx.x - NBLK;
    int hw = t >> 5;
    int l  = t & 31;
    int n  = nb * 8 + hw;
    if (n >= nNodes) return;
    float4 xv = *reinterpret_cast<const float4*>(x + (size_t)n * D + l * 4);
    float ss = xv.x * xv.x + xv.y * xv.y + xv.z * xv.z + xv.w * xv.w;
    ss += __shfl_xor(ss, 1);
    ss += __shfl_xor(ss, 2);
    ss += __shfl_xor(ss, 4);
    ss += __shfl_xor(ss, 8);
    ss += __shfl_xor(ss, 16);
    float norm = sqrtf(ss);
    float ncl  = fminf(norm, 1.0f - 1e-7f);
    float at   = 0.5f * logf((1.0f + ncl) / (1.0f - ncl));
    float sc64 = 64.0f * at / fmaxf(norm, 1e-15f);   // x64 keeps e4m3 normal
    int u = __builtin_amdgcn_cvt_pk_fp8_f32(xv.x * sc64, xv.y * sc64, 0, false);
    u     = __builtin_amdgcn_cvt_pk_fp8_f32(xv.z * sc64, xv.w * sc64, u, true);
    reinterpret_cast<unsigned*>(th8 + (size_t)n * D)[l] = (unsigned)u;
}

// Combo (fp16 tier) — fallback when ws can't hold msgb
__global__ __launch_bounds__(256) void hist_tangent_kernel(
    const int* __restrict__ dst, int* __restrict__ blkhist,
    int nEdges, int NB,
    const float* __restrict__ x, __half* __restrict__ th, int nNodes)
{
    __shared__ int hist[256];
    int t = threadIdx.x;

    if (blockIdx.x < NBLK) {
        hist[t] = 0;
        __syncthreads();
        int per = (nEdges + NBLK - 1) / NBLK;
        int i0 = blockIdx.x * per;
        int i1 = min(nEdges, i0 + per);
        for (int i = i0 + t; i < i1; i += 256)
            atomicAdd(&hist[dst[i] >> BSH], 1);
        __syncthreads();
        if (t < NB) blkhist[t * NBLK + blockIdx.x] = hist[t];
        return;
    }

    int nb = blockIdx.x - NBLK;
    int n    = (nb * 256 + t) >> 6;
    int lane = t & 63;
    if (n >= nNodes) return;
    float2 xv = *reinterpret_cast<const float2*>(x + (size_t)n * D + lane * 2);
    float ss = xv.x * xv.x + xv.y * xv.y;
    ss += __shfl_xor(ss, 1);
    ss += __shfl_xor(ss, 2);
    ss += __shfl_xor(ss, 4);
    ss += __shfl_xor(ss, 8);
    ss += __shfl_xor(ss, 16);
    ss += __shfl_xor(ss, 32);
    float norm = sqrtf(ss);
    float ncl  = fminf(norm, 1.0f - 1e-7f);
    float at   = 0.5f * logf((1.0f + ncl) / (1.0f - ncl));
    float sc   = at / fmaxf(norm, 1e-15f);
    __half2 h = __float22half2_rn(make_float2(xv.x * sc, xv.y * sc));
    *(reinterpret_cast<__half2*>(th + (size_t)n * D) + lane) = h;
}

// P1.5: one block per bucket: scan per-block counts -> exclusive, total out
__global__ __launch_bounds__(256) void part_scan1_kernel(
    int* __restrict__ blkhist, int* __restrict__ btot)
{
    __shared__ int s[256];
    int b = blockIdx.x;
    int t = threadIdx.x;
    int v = blkhist[b * NBLK + t];
    s[t] = v;
    __syncthreads();
    for (int off = 1; off < 256; off <<= 1) {
        int xv = (t >= off) ? s[t - off] : 0;
        __syncthreads();
        if (t >= off) s[t] += xv;
        __syncthreads();
    }
    blkhist[b * NBLK + t] = s[t] - v;   // exclusive
    if (t == 255) btot[b] = s[255];
}

// ===========================================================================
// P2: scatter edges into bucket-partitioned array. LDS cursors only; bucket
// bases recomputed per-block from btot. part[p] = src | dloc<<17.
// ===========================================================================
__global__ __launch_bounds__(256) void part_scatter_kernel(
    const int* __restrict__ src, const int* __restrict__ dst,
    const int* __restrict__ blkhist, const int* __restrict__ btot,
    unsigned* __restrict__ part, int nEdges, int NB)
{
    __shared__ int sb[256];
    __shared__ int cur[256];
    int t = threadIdx.x;
    int v = (t < NB) ? btot[t] : 0;
    sb[t] = v;
    __syncthreads();
    for (int off = 1; off < 256; off <<= 1) {
        int xv = (t >= off) ? sb[t - off] : 0;
        __syncthreads();
        if (t >= off) sb[t] += xv;
        __syncthreads();
    }
    int bbase_t = sb[t] - v;
    cur[t] = (t < NB) ? (blkhist[t * NBLK + blockIdx.x] + bbase_t) : 0;
    __syncthreads();

    int per = (nEdges + gridDim.x - 1) / gridDim.x;
    int i0 = blockIdx.x * per;
    int i1 = min(nEdges, i0 + per);
    for (int i = i0 + t; i < i1; i += 256) {
        int d = dst[i];
        int b = d >> BSH;
        int p = atomicAdd(&cur[b], 1);
        part[p] = (unsigned)src[i] | ((unsigned)(d & (BNODES - 1)) << 17);
    }
}

// ===========================================================================
// P3: per-bucket CSR build. Bucket bases recomputed from btot in LDS.
// ===========================================================================
__global__ __launch_bounds__(256) void bucket_csr_kernel(
    const unsigned* __restrict__ part, const int* __restrict__ btot,
    int* __restrict__ rowptr, float* __restrict__ degf,
    int* __restrict__ csr_src, int nNodes, int NB, int nEdges)
{
    __shared__ int cnt[BNODES];
    __shared__ int excl[BNODES];
    __shared__ int cur[BNODES];
    __shared__ int s[256];
    __shared__ int sBB[2];

    int b = blockIdx.x;
    int t = threadIdx.x;

    int v = (t < NB) ? btot[t] : 0;
    s[t] = v;
    __syncthreads();
    for (int off = 1; off < 256; off <<= 1) {
        int xv = (t >= off) ? s[t - off] : 0;
        __syncthreads();
        if (t >= off) s[t] += xv;
        __syncthreads();
    }
    if (t == b) { sBB[0] = s[t] - v; sBB[1] = s[t]; }
    __syncthreads();
    int bb = sBB[0], be = sBB[1];

    cnt[t] = 0; cnt[t + 256] = 0;
    cur[t] = 0; cur[t + 256] = 0;
    __syncthreads();

    for (int i = bb + t; i < be; i += 256)
        atomicAdd(&cnt[part[i] >> 17], 1);
    __syncthreads();

    int a0 = cnt[2 * t], a1 = cnt[2 * t + 1];
    s[t] = a0 + a1;
    __syncthreads();
    for (int off = 1; off < 256; off <<= 1) {
        int xv = (t >= off) ? s[t - off] : 0;
        __syncthreads();
        if (t >= off) s[t] += xv;
        __syncthreads();
    }
    int pbase = (t > 0) ? s[t - 1] : 0;
    excl[2 * t]     = pbase;
    excl[2 * t + 1] = pbase + a0;
    __syncthreads();

    int node0 = b << BSH;
#pragma unroll
    for (int q = 0; q < 2; ++q) {
        int j = t + q * 256;
        int d = node0 + j;
        if (d < nNodes) {
            rowptr[d] = bb + excl[j];
            degf[d]   = (float)cnt[j];
        }
    }
    if (b == NB - 1 && t == 0) rowptr[nNodes] = nEdges;

    for (int i = bb + t; i < be; i += 256) {
        unsigned vv = part[i];
        int dloc = vv >> 17;
        int p = bb + excl[dloc] + atomicAdd(&cur[dloc], 1);
        csr_src[p] = (int)(vv & 0x1FFFFu);
    }
}

// ===========================================================================
// mid-tier CSR build (global atomics, windowed) — fallback if ws too small
// ===========================================================================
__global__ __launch_bounds__(256) void hist_win_kernel(
    const int* __restrict__ dst, int* __restrict__ count,
    int nEdges, int winSize)
{
    int pass    = blockIdx.x & 7;
    int slice   = blockIdx.x >> 3;
    int nSlices = gridDim.x >> 3;
    int lo = pass * winSize;
    int hi = lo + winSize;

    int stride = nSlices * blockDim.x;
    for (int i = slice * blockDim.x + threadIdx.x; i < nEdges; i += stride) {
        int d = dst[i];
        if (d >= lo && d < hi) atomicAdd(&count[d], 1);
    }
}

__global__ __launch_bounds__(256) void scan_block_kernel(
    const int* __restrict__ count, int* __restrict__ rowptr,
    int* __restrict__ blksums, int n)
{
    __shared__ int sums[256];
    int t = threadIdx.x;
    int base = blockIdx.x * 1024 + t * 4;
    int v[4];
    int s = 0;
#pragma unroll
    for (int j = 0; j < 4; ++j) { v[j] = (base + j < n) ? count[base + j] : 0; s += v[j]; }
    sums[t] = s;
    __syncthreads();
    for (int off = 1; off < 256; off <<= 1) {
        int xv = (t >= off) ? sums[t - off] : 0;
        __syncthreads();
        if (t >= off) sums[t] += xv;
        __syncthreads();
    }
    int run = (t > 0) ? sums[t - 1] : 0;
#pragma unroll
    for (int j = 0; j < 4; ++j) { if (base + j < n) rowptr[base + j] = run; run += v[j]; }
    if (t == 255) blksums[blockIdx.x] = sums[255];
}

__global__ __launch_bounds__(256) void scan_totals_kernel(
    int* __restrict__ blksums, int* __restrict__ rowptr,
    int numBlocks, int n, int E)
{
    __shared__ int s[256];
    int t = threadIdx.x;
    s[t] = (t < numBlocks) ? blksums[t] : 0;
    __syncthreads();
    for (int off = 1; off < 256; off <<= 1) {
        int xv = (t >= off) ? s[t - off] : 0;
        __syncthreads();
        if (t >= off) s[t] += xv;
        __syncthreads();
    }
    if (t < numBlocks) blksums[t] = (t > 0) ? s[t - 1] : 0;
    if (t == 0) rowptr[n] = E;
}

__global__ __launch_bounds__(256) void add_offsets_kernel(
    int* __restrict__ rowptr, const int* __restrict__ blksums, int n)
{
    int i = blockIdx.x * 256 + threadIdx.x;
    if (i < n) rowptr[i] += blksums[i >> 10];
}

__global__ __launch_bounds__(256) void fill_win_kernel(
    const int* __restrict__ src, const int* __restrict__ dst,
    const int* __restrict__ rowptr, int* __restrict__ count,
    int* __restrict__ csr_src, int nEdges, int winSize)
{
    int pass    = blockIdx.x & 7;
    int slice   = blockIdx.x >> 3;
    int nSlices = gridDim.x >> 3;
    int lo = pass * winSize;
    int hi = lo + winSize;

    int stride = nSlices * blockDim.x;
    for (int i = slice * blockDim.x + threadIdx.x; i < nEdges; i += stride) {
        int d = dst[i];
        if (d >= lo && d < hi) {
            int pos = rowptr[d] + atomicSub(&count[d], 1) - 1;
            csr_src[pos] = src[i];
        }
    }
}

__global__ __launch_bounds__(256) void deg_from_rowptr_kernel(
    const int* __restrict__ rowptr, float* __restrict__ degf, int n)
{
    int i = blockIdx.x * 256 + threadIdx.x;
    if (i < n) degf[i] = (float)(rowptr[i + 1] - rowptr[i]);
}

__global__ __launch_bounds__(256) void scale_kernel(
    const float* __restrict__ x, float* __restrict__ scale, int nNodes)
{
    int node = (blockIdx.x * 256 + threadIdx.x) >> 6;
    int lane = threadIdx.x & 63;
    if (node >= nNodes) return;
    float2 xv = *reinterpret_cast<const float2*>(x + (size_t)node * D + lane * 2);
    float ss = xv.x * xv.x + xv.y * xv.y;
    ss += __shfl_xor(ss, 1);
    ss += __shfl_xor(ss, 2);
    ss += __shfl_xor(ss, 4);
    ss += __shfl_xor(ss, 8);
    ss += __shfl_xor(ss, 16);
    ss += __shfl_xor(ss, 32);
    if (lane == 0) {
        float norm = sqrtf(ss);
        float ncl  = fminf(norm, 1.0f - 1e-7f);
        float at   = 0.5f * logf((1.0f + ncl) / (1.0f - ncl));
        scale[node] = at / fmaxf(norm, 1e-15f);
    }
}

// ===========================================================================
// gather fp8: msgb[n] = bf16( sum 64*th[src_e] ) (scale folded out in GEMM).
// 2 nodes/wave, 4 groups x 8 lanes per node; one float4/lane = one full
// 128B row per group-instruction -> 16 rows in flight/wave, 16 edges per
// node per main iteration (~avg degree). fp32 accumulate via HW fp8 cvt.
// ===========================================================================
__global__ __launch_bounds__(256) void gather8_kernel(
    const unsigned char* __restrict__ th8,
    const int* __restrict__ csr_src, const int* __restrict__ rowptr,
    short* __restrict__ msgb, int nNodes)
{
    int t    = threadIdx.x;
    int lane = t & 63;
    int wave = t >> 6;
    int np   = lane >> 5;          // node select 0/1
    int rem  = lane & 31;
    int g    = rem >> 3;           // group 0..3: edge slots g, g+4, ...
    int sl   = rem & 7;            // owns elements [16*sl, 16*sl+16)

    int n  = blockIdx.x * 8 + wave * 2 + np;
    int nn = n < nNodes ? n : nNodes - 1;
    int beg = rowptr[nn];
    int cnt = rowptr[nn + 1] - beg;

    float acc[16];
#pragma unroll
    for (int j = 0; j < 16; ++j) acc[j] = 0.0f;

    int k = g;
    for (; k + 12 < cnt; k += 16) {
        int s0 = csr_src[beg + k];
        int s1 = csr_src[beg + k + 4];
        int s2 = csr_src[beg + k + 8];
        int s3 = csr_src[beg + k + 12];
        float4 r0 = *reinterpret_cast<const float4*>(th8 + (size_t)s0 * D + sl * 16);
        float4 r1 = *reinterpret_cast<const float4*>(th8 + (size_t)s1 * D + sl * 16);
        float4 r2 = *reinterpret_cast<const float4*>(th8 + (size_t)s2 * D + sl * 16);
        float4 r3 = *reinterpret_cast<const float4*>(th8 + (size_t)s3 * D + sl * 16);
        const unsigned* u0 = reinterpret_cast<const unsigned*>(&r0);
        const unsigned* u1 = reinterpret_cast<const unsigned*>(&r1);
        const unsigned* u2 = reinterpret_cast<const unsigned*>(&r2);
        const unsigned* u3 = reinterpret_cast<const unsigned*>(&r3);
#pragma unroll
        for (int q = 0; q < 4; ++q) {
            f32x2 a0 = __builtin_amdgcn_cvt_pk_f32_fp8(u0[q], false);
            f32x2 b0 = __builtin_amdgcn_cvt_pk_f32_fp8(u0[q], true);
            f32x2 a1 = __builtin_amdgcn_cvt_pk_f32_fp8(u1[q], false);
            f32x2 b1 = __builtin_amdgcn_cvt_pk_f32_fp8(u1[q], true);
            f32x2 a2 = __builtin_amdgcn_cvt_pk_f32_fp8(u2[q], false);
            f32x2 b2 = __builtin_amdgcn_cvt_pk_f32_fp8(u2[q], true);
            f32x2 a3 = __builtin_amdgcn_cvt_pk_f32_fp8(u3[q], false);
            f32x2 b3 = __builtin_amdgcn_cvt_pk_f32_fp8(u3[q], true);
            acc[4 * q + 0] += (a0[0] + a1[0]) + (a2[0] + a3[0]);
            acc[4 * q + 1] += (a0[1] + a1[1]) + (a2[1] + a3[1]);
            acc[4 * q + 2] += (b0[0] + b1[0]) + (b2[0] + b3[0]);
            acc[4 * q + 3] += (b0[1] + b1[1]) + (b2[1] + b3[1]);
        }
    }
    for (; k < cnt; k += 4) {
        int s0 = csr_src[beg + k];
        float4 r0 = *reinterpret_cast<const float4*>(th8 + (size_t)s0 * D + sl * 16);
        const unsigned* u0 = reinterpret_cast<const unsigned*>(&r0);
#pragma unroll
        for (int q = 0; q < 4; ++q) {
            f32x2 a0 = __builtin_amdgcn_cvt_pk_f32_fp8(u0[q], false);
            f32x2 b0 = __builtin_amdgcn_cvt_pk_f32_fp8(u0[q], true);
            acc[4 * q + 0] += a0[0];
            acc[4 * q + 1] += a0[1];
            acc[4 * q + 2] += b0[0];
            acc[4 * q + 3] += b0[1];
        }
    }
    // combine the 4 groups of this node (lanes ^8, ^16 within the 32-half)
#pragma unroll
    for (int j = 0; j < 16; ++j) {
        acc[j] += __shfl_xor(acc[j], 8);
        acc[j] += __shfl_xor(acc[j], 16);
    }
    if (g == 0 && n < nNodes) {
        short s16[16];
#pragma unroll
        for (int j = 0; j < 16; ++j) s16[j] = f2bf(acc[j]);
        float4* o = reinterpret_cast<float4*>(msgb + (size_t)n * D + sl * 16);
        o[0] = reinterpret_cast<float4*>(s16)[0];
        o[1] = reinterpret_cast<float4*>(s16)[1];
    }
}

// gather fp16 -> fp32 msg (aliases d_out) — lo tier
__global__ __launch_bounds__(256) void gather_h16_kernel(
    const __half* __restrict__ th,
    const int* __restrict__ csr_src, const int* __restrict__ rowptr,
    float* __restrict__ msg, int nNodes)
{
    int n    = blockIdx.x * 4 + (threadIdx.x >> 6);
    int lane = threadIdx.x & 63;
    if (n >= nNodes) return;
    int grp = lane >> 4;
    int sl  = lane & 15;

    int beg = rowptr[n];
    int cnt = rowptr[n + 1] - beg;

    __half2 z = __float2half2_rn(0.0f);
    __half2 acc0[4] = {z, z, z, z};
    __half2 acc1[4] = {z, z, z, z};

    int k = grp;
    for (; k + 12 < cnt; k += 16) {
        int s0 = csr_src[beg + k];
        int s1 = csr_src[beg + k + 4];
        int s2 = csr_src[beg + k + 8];
        int s3 = csr_src[beg + k + 12];
        float4 r0 = *reinterpret_cast<const float4*>(th + (size_t)s0 * D + sl * 8);
        float4 r1 = *reinterpret_cast<const float4*>(th + (size_t)s1 * D + sl * 8);
        float4 r2 = *reinterpret_cast<const float4*>(th + (size_t)s2 * D + sl * 8);
        float4 r3 = *reinterpret_cast<const float4*>(th + (size_t)s3 * D + sl * 8);
        const __half2* h0 = reinterpret_cast<const __half2*>(&r0);
        const __half2* h1 = reinterpret_cast<const __half2*>(&r1);
        const __half2* h2 = reinterpret_cast<const __half2*>(&r2);
        const __half2* h3 = reinterpret_cast<const __half2*>(&r3);
#pragma unroll
        for (int j = 0; j < 4; ++j) {
            acc0[j] = __hadd2(acc0[j], h0[j]);
            acc1[j] = __hadd2(acc1[j], h1[j]);
            acc0[j] = __hadd2(acc0[j], h2[j]);
            acc1[j] = __hadd2(acc1[j], h3[j]);
        }
    }
    for (; k < cnt; k += 4) {
        int s0 = csr_src[beg + k];
        float4 r0 = *reinterpret_cast<const float4*>(th + (size_t)s0 * D + sl * 8);
        const __half2* h0 = reinterpret_cast<const __half2*>(&r0);
#pragma unroll
        for (int j = 0; j < 4; ++j) acc0[j] = __hadd2(acc0[j], h0[j]);
    }
#pragma unroll
    for (int j = 0; j < 4; ++j) {
        acc0[j] = __hadd2(acc0[j], acc1[j]);
        float f16 = __shfl_xor(__builtin_bit_cast(float, acc0[j]), 16);
        acc0[j] = __hadd2(acc0[j], __builtin_bit_cast(__half2, f16));
        float f32v = __shfl_xor(__builtin_bit_cast(float, acc0[j]), 32);
        acc0[j] = __hadd2(acc0[j], __builtin_bit_cast(__half2, f32v));
    }
    if (grp == 0) {
        float2 f0 = __half22float2(acc0[0]);
        float2 f1 = __half22float2(acc0[1]);
        float2 f2 = __half22float2(acc0[2]);
        float2 f3 = __half22float2(acc0[3]);
        float4 o0 = make_float4(f0.x, f0.y, f1.x, f1.y);
        float4 o1 = make_float4(f2.x, f2.y, f3.x, f3.y);
        *reinterpret_cast<float4*>(msg + (size_t)n * D + sl * 8)     = o0;
        *reinterpret_cast<float4*>(msg + (size_t)n * D + sl * 8 + 4) = o1;
    }
}

// gather (fp32 rows) — mid tier
__global__ __launch_bounds__(256) void gather_kernel(
    const float* __restrict__ x, const float* __restrict__ scale,
    const int* __restrict__ csr_src, const int* __restrict__ rowptr,
    float* __restrict__ msg, float* __restrict__ degf, int nNodes)
{
    int n    = blockIdx.x * 4 + (threadIdx.x >> 6);
    int lane = threadIdx.x & 63;
    if (n >= nNodes) return;

    int beg = rowptr[n], end = rowptr[n + 1];
    float2 acc0 = make_float2(0.0f, 0.0f);
    float2 acc1 = make_float2(0.0f, 0.0f);
    int e = beg;
    for (; e + 3 < end; e += 4) {
        int s0 = csr_src[e],     s1 = csr_src[e + 1];
        int s2 = csr_src[e + 2], s3 = csr_src[e + 3];
        float sc0 = scale[s0], sc1 = scale[s1];
        float sc2 = scale[s2], sc3 = scale[s3];
        float2 a = *reinterpret_cast<const float2*>(x + (size_t)s0 * D + lane * 2);
        float2 b = *reinterpret_cast<const float2*>(x + (size_t)s1 * D + lane * 2);
        float2 c = *reinterpret_cast<const float2*>(x + (size_t)s2 * D + lane * 2);
        float2 d = *reinterpret_cast<const float2*>(x + (size_t)s3 * D + lane * 2);
        acc0.x += sc0 * a.x;  acc0.y += sc0 * a.y;
        acc1.x += sc1 * b.x;  acc1.y += sc1 * b.y;
        acc0.x += sc2 * c.x;  acc0.y += sc2 * c.y;
        acc1.x += sc3 * d.x;  acc1.y += sc3 * d.y;
    }
    for (; e < end; ++e) {
        int s0 = csr_src[e];
        float sc0 = scale[s0];
        float2 a = *reinterpret_cast<const float2*>(x + (size_t)s0 * D + lane * 2);
        acc0.x += sc0 * a.x;  acc0.y += sc0 * a.y;
    }
    acc0.x += acc1.x;  acc0.y += acc1.y;
    *reinterpret_cast<float2*>(msg + (size_t)n * D + lane * 2) = acc0;
    if (lane == 0) degf[n] = (float)(end - beg);
}

// ===========================================================================
// Fallback edge scatter (fp32 hardware atomics) — last resort
// ===========================================================================
__global__ __launch_bounds__(256) void edge_scatter_kernel(
    const float* __restrict__ x,
    const int* __restrict__ src,
    const int* __restrict__ dst,
    float* __restrict__ msg,
    float* __restrict__ deg,
    int nEdges)
{
    long long t = (long long)blockIdx.x * blockDim.x + threadIdx.x;
    int edge = (int)(t >> 5);
    int lane = (int)(t & 31);
    if (edge >= nEdges) return;

    int s = src[edge];
    int d = dst[edge];

    const float4 xv = *reinterpret_cast<const float4*>(x + (size_t)s * D + lane * 4);
    float ss = xv.x * xv.x + xv.y * xv.y + xv.z * xv.z + xv.w * xv.w;
    ss += __shfl_xor(ss, 1);
    ss += __shfl_xor(ss, 2);
    ss += __shfl_xor(ss, 4);
    ss += __shfl_xor(ss, 8);
    ss += __shfl_xor(ss, 16);

    float norm = sqrtf(ss);
    float ncl  = fminf(norm, 1.0f - 1e-7f);
    float at   = 0.5f * logf((1.0f + ncl) / (1.0f - ncl));
    float scale = at / fmaxf(norm, 1e-15f);

    float* mrow = msg + (size_t)d * D + lane * 4;
    unsafeAtomicAdd(mrow + 0, xv.x * scale);
    unsafeAtomicAdd(mrow + 1, xv.y * scale);
    unsafeAtomicAdd(mrow + 2, xv.z * scale);
    unsafeAtomicAdd(mrow + 3, xv.w * scale);
    if (lane == 0) unsafeAtomicAdd(deg + d, 1.0f);
}

// ===========================================================================
// MFMA bf16 GEMM + expmap, bf16 A (x64-scaled): out = expmap0(
// (msgb@W^T)/(64*max(deg,1)) + b ), zeroed where deg==0.
// ===========================================================================
__global__ __launch_bounds__(256) void gemm_mfma_b_kernel(
    const short* __restrict__ msgb, const float* __restrict__ deg,
    const float* __restrict__ W, const float* __restrict__ bias,
    float* __restrict__ out, int nNodes)
{
    __shared__ short sW[128][136];

    const int t = threadIdx.x;

#pragma unroll
    for (int p = 0; p < 16; ++p) {
        int chunk = p * 256 + t;
        int row = chunk >> 5;
        int c4  = (chunk & 31) * 4;
        float4 v = *reinterpret_cast<const float4*>(W + row * 128 + c4);
        short4 s;
        s.x = f2bf(v.x); s.y = f2bf(v.y); s.z = f2bf(v.z); s.w = f2bf(v.w);
        *reinterpret_cast<short4*>(&sW[row][c4]) = s;
    }
    __syncthreads();

    const int wave = t >> 6;
    const int lane = t & 63;
    const int l15  = lane & 15;
    const int lhi  = lane >> 4;
    const int m0   = blockIdx.x * 64 + wave * 16;

    int arow = m0 + l15;
    if (arow >= nNodes) arow = nNodes - 1;
    const short* ap = msgb + (size_t)arow * D + lhi * 8;
    bf16x8 a[4];
#pragma unroll
    for (int kc = 0; kc < 4; ++kc)
        a[kc] = *reinterpret_cast<const bf16x8*>(ap + kc * 32);

    f32x4 acc[8];
#pragma unroll
    for (int ct = 0; ct < 8; ++ct) acc[ct] = (f32x4){0.f, 0.f, 0.f, 0.f};

#pragma unroll
    for (int ct = 0; ct < 8; ++ct) {
#pragma unroll
        for (int kc = 0; kc < 4; ++kc) {
            bf16x8 bfrag = *reinterpret_cast<const bf16x8*>(
                &sW[ct * 16 + l15][kc * 32 + lhi * 8]);
            acc[ct] = __builtin_amdgcn_mfma_f32_16x16x32_bf16(a[kc], bfrag, acc[ct], 0, 0, 0);
        }
    }

    float bv[8];
#pragma unroll
    for (int ct = 0; ct < 8; ++ct) bv[ct] = bias[ct * 16 + l15];

#pragma unroll
    for (int r = 0; r < 4; ++r) {
        int row = m0 + lhi * 4 + r;
        int rc  = row < nNodes ? row : nNodes - 1;
        float dg  = deg[rc];
        float inv = 1.0f / (64.0f * fmaxf(dg, 1.0f));   // fold fp8 x64 scale
        float v[8];
        float ss = 0.0f;
#pragma unroll
        for (int ct = 0; ct < 8; ++ct) {
            v[ct] = acc[ct][r] * inv + bv[ct];
            ss += v[ct] * v[ct];
        }
        ss += __shfl_xor(ss, 1);
        ss += __shfl_xor(ss, 2);
        ss += __shfl_xor(ss, 4);
        ss += __shfl_xor(ss, 8);
        float norm = sqrtf(ss);
        float sc = (dg > 0.0f) ? (tanhf(norm) / fmaxf(norm, 1e-15f)) : 0.0f;
        if (row < nNodes) {
#pragma unroll
            for (int ct = 0; ct < 8; ++ct)
                out[(size_t)row * D + ct * 16 + l15] = v[ct] * sc;
        }
    }
}

// fp32-A variant (msg may alias out; in-place safe — reads precede stores)
__global__ __launch_bounds__(256) void gemm_mfma_kernel(
    const float* msg, const float* __restrict__ deg,
    const float* __restrict__ W, const float* __restrict__ bias,
    float* out, int nNodes)
{
    __shared__ short sW[128][136];

    const int t = threadIdx.x;

#pragma unroll
    for (int p = 0; p < 16; ++p) {
        int chunk = p * 256 + t;
        int row = chunk >> 5;
        int c4  = (chunk & 31) * 4;
        float4 v = *reinterpret_cast<const float4*>(W + row * 128 + c4);
        short4 s;
        s.x = f2bf(v.x); s.y = f2bf(v.y); s.z = f2bf(v.z); s.w = f2bf(v.w);
        *reinterpret_cast<short4*>(&sW[row][c4]) = s;
    }
    __syncthreads();

    const int wave = t >> 6;
    const int lane = t & 63;
    const int l15  = lane & 15;
    const int lhi  = lane >> 4;
    const int m0   = blockIdx.x * 64 + wave * 16;

    int arow = m0 + l15;
    if (arow >= nNodes) arow = nNodes - 1;
    const float* ap = msg + (size_t)arow * D + lhi * 8;
    bf16x8 a[4];
#pragma unroll
    for (int kc = 0; kc < 4; ++kc) {
        float4 v0 = *reinterpret_cast<const float4*>(ap + kc * 32);
        float4 v1 = *reinterpret_cast<const float4*>(ap + kc * 32 + 4);
        bf16x8 f;
        f[0] = f2bf(v0.x); f[1] = f2bf(v0.y); f[2] = f2bf(v0.z); f[3] = f2bf(v0.w);
        f[4] = f2bf(v1.x); f[5] = f2bf(v1.y); f[6] = f2bf(v1.z); f[7] = f2bf(v1.w);
        a[kc] = f;
    }

    f32x4 acc[8];
#pragma unroll
    for (int ct = 0; ct < 8; ++ct) acc[ct] = (f32x4){0.f, 0.f, 0.f, 0.f};

#pragma unroll
    for (int ct = 0; ct < 8; ++ct) {
#pragma unroll
        for (int kc = 0; kc < 4; ++kc) {
            bf16x8 bfrag = *reinterpret_cast<const bf16x8*>(
                &sW[ct * 16 + l15][kc * 32 + lhi * 8]);
            acc[ct] = __builtin_amdgcn_mfma_f32_16x16x32_bf16(a[kc], bfrag, acc[ct], 0, 0, 0);
        }
    }

    float bv[8];
#pragma unroll
    for (int ct = 0; ct < 8; ++ct) bv[ct] = bias[ct * 16 + l15];

#pragma unroll
    for (int r = 0; r < 4; ++r) {
        int row = m0 + lhi * 4 + r;
        int rc  = row < nNodes ? row : nNodes - 1;
        float dg  = deg[rc];
        float inv = 1.0f / fmaxf(dg, 1.0f);
        float v[8];
        float ss = 0.0f;
#pragma unroll
        for (int ct = 0; ct < 8; ++ct) {
            v[ct] = acc[ct][r] * inv + bv[ct];
            ss += v[ct] * v[ct];
        }
        ss += __shfl_xor(ss, 1);
        ss += __shfl_xor(ss, 2);
        ss += __shfl_xor(ss, 4);
        ss += __shfl_xor(ss, 8);
        float norm = sqrtf(ss);
        float sc = (dg > 0.0f) ? (tanhf(norm) / fmaxf(norm, 1e-15f)) : 0.0f;
        if (row < nNodes) {
#pragma unroll
            for (int ct = 0; ct < 8; ++ct)
                out[(size_t)row * D + ct * 16 + l15] = v[ct] * sc;
        }
    }
}

static inline size_t align256(size_t o) { return (o + 255) & ~(size_t)255; }

extern "C" void kernel_launch(void* const* d_in, const int* in_sizes, int n_in,
                              void* d_out, int out_size, void* d_ws, size_t ws_size,
                              hipStream_t stream) {
    const float* x   = (const float*)d_in[0];
    const float* W   = (const float*)d_in[1];
    const float* b   = (const float*)d_in[2];
    const int*   src = (const int*)d_in[3];
    const int*   dst = (const int*)d_in[4];
    float* out = (float*)d_out;

    int nNodes = in_sizes[0] / D;
    int nEdges = in_sizes[3];
    int NB = (nNodes + BNODES - 1) >> BSH;

    // workspace layout (tiered)
    char* ws = (char*)d_ws;
    size_t off = 0;
    float* degf    = (float*)(ws + off); off = align256(off + sizeof(float) * nNodes);
    int*   count   = (int*)  (ws + off); off = align256(off + sizeof(int) * nNodes);
    int*   rowptr  = (int*)  (ws + off); off = align256(off + sizeof(int) * (nNodes + 1));
    float* scl     = (float*)(ws + off); off = align256(off + sizeof(float) * nNodes);
    int*   blksums = (int*)  (ws + off); off = align256(off + sizeof(int) * 256);
    int*   btot    = (int*)  (ws + off); off = align256(off + sizeof(int) * 256);
    int*   blkhist = (int*)  (ws + off); off = align256(off + sizeof(int) * NBLK * 256);
    int*   csr_src = (int*)  (ws + off); off = align256(off + sizeof(int) * nEdges);
    size_t need_mid = off;

    // region1: part (P2/P3) then msgb (gather onward) — part dead before
    // msgb is written. th lives beyond (written first, read last).
    size_t part_sz = sizeof(unsigned) * (size_t)nEdges;
    size_t msgb_sz = sizeof(short) * (size_t)nNodes * D;
    size_t th8_sz  = sizeof(unsigned char) * (size_t)nNodes * D;
    size_t th16_sz = sizeof(__half) * (size_t)nNodes * D;

    unsigned* part = (unsigned*)(ws + off);
    short*    msgb = (short*)   (ws + off);
    size_t off_lo = align256(off + part_sz);                                  // region1 = part only
    size_t off_hi = align256(off + (part_sz > msgb_sz ? part_sz : msgb_sz));  // region1 = max
    __half*        th_lo = (__half*)(ws + off_lo);
    unsigned char* th8   = (unsigned char*)(ws + off_hi);
    size_t need_lo = align256(off_lo + th16_sz);
    size_t need_hi = align256(off_hi + th8_sz);

    float* msg = out;  // fp32 msg staging (aliases out) for non-msgb tiers

    int numScanBlocks = (nNodes + 1023) / 1024;
    bool part_ok = (ws_size >= need_lo) && (nNodes <= 131072) && (NB <= 256);
    bool fp8msg  = (ws_size >= need_hi) && (nNodes <= 131072) && (NB <= 256);
    bool mid_ok  = (ws_size >= need_mid) && (numScanBlocks <= 256);

    if (part_ok || fp8msg) {
        if (fp8msg) {
            int TB = (nNodes + 7) / 8;
            hist_tangent8_kernel<<<NBLK + TB, 256, 0, stream>>>(
                dst, blkhist, nEdges, NB, x, th8, nNodes);
        } else {
            int TB = (nNodes + 3) / 4;
            hist_tangent_kernel<<<NBLK + TB, 256, 0, stream>>>(
                dst, blkhist, nEdges, NB, x, th_lo, nNodes);
        }
        part_scan1_kernel<<<NB, 256, 0, stream>>>(blkhist, btot);
        part_scatter_kernel<<<NBLK, 256, 0, stream>>>(src, dst, blkhist, btot, part, nEdges, NB);
        bucket_csr_kernel<<<NB, 256, 0, stream>>>(part, btot, rowptr, degf,
                                                  csr_src, nNodes, NB, nEdges);
        if (fp8msg) {
            gather8_kernel<<<(nNodes + 7) / 8, 256, 0, stream>>>(th8, csr_src, rowptr, msgb, nNodes);
            gemm_mfma_b_kernel<<<(nNodes + 63) / 64, 256, 0, stream>>>(msgb, degf, W, b, out, nNodes);
        } else {
            gather_h16_kernel<<<(nNodes + 3) / 4, 256, 0, stream>>>(th_lo, csr_src, rowptr, msg, nNodes);
            gemm_mfma_kernel<<<(nNodes + 63) / 64, 256, 0, stream>>>(msg, degf, W, b, out, nNodes);
        }
        return;
    }

    if (mid_ok) {
        hipMemsetAsync(count, 0, sizeof(int) * nNodes, stream);
        int winSize = (nNodes + 7) / 8;
        hist_win_kernel<<<4096, 256, 0, stream>>>(dst, count, nEdges, winSize);
        scan_block_kernel<<<numScanBlocks, 256, 0, stream>>>(count, rowptr, blksums, nNodes);
        scan_totals_kernel<<<1, 256, 0, stream>>>(blksums, rowptr, numScanBlocks, nNodes, nEdges);
        add_offsets_kernel<<<(nNodes + 255) / 256, 256, 0, stream>>>(rowptr, blksums, nNodes);
        fill_win_kernel<<<4096, 256, 0, stream>>>(src, dst, rowptr, count, csr_src, nEdges, winSize);
        deg_from_rowptr_kernel<<<(nNodes + 255) / 256, 256, 0, stream>>>(rowptr, degf, nNodes);

        scale_kernel<<<(nNodes + 3) / 4, 256, 0, stream>>>(x, scl, nNodes);
        gather_kernel<<<(nNodes + 3) / 4, 256, 0, stream>>>(x, scl, csr_src, rowptr, msg, degf, nNodes);
        gemm_mfma_kernel<<<(nNodes + 63) / 64, 256, 0, stream>>>(msg, degf, W, b, out, nNodes);
        return;
    }

    {
        float* deg = (float*)d_ws;
        hipMemsetAsync(msg, 0, (size_t)nNodes * D * sizeof(float), stream);
        hipMemsetAsync(deg, 0, (size_t)nNodes * sizeof(float), stream);
        long long threads = (long long)nEdges * 32;
        int blocks = (int)((threads + 255) / 256);
        edge_scatter_kernel<<<blocks, 256, 0, stream>>>(x, src, dst, msg, (float*)d_ws, nEdges);
        gemm_mfma_kernel<<<(nNodes + 63) / 64, 256, 0, stream>>>(msg, (float*)d_ws, W, b, out, nNodes);
    }
}